// Round 7
// baseline (482.365 us; speedup 1.0000x reference)
//
#include <hip/hip_runtime.h>

#define NN 10000
#define NE 160000
#define TT 2
#define SS 2
#define HH 64
#define ZZ 32
#define KK 4
#define NIN 4

typedef short bf16x8 __attribute__((ext_vector_type(8)));
typedef float f32x4 __attribute__((ext_vector_type(4)));

// fp32 -> bf16 (RNE)
__device__ __forceinline__ unsigned short f2b(float x) {
    unsigned u = __float_as_uint(x);
    u += 0x7fffu + ((u >> 16) & 1u);
    return (unsigned short)(u >> 16);
}
__device__ __forceinline__ float bf2f(unsigned short u) {
    return __uint_as_float(((unsigned)u) << 16);
}

// A0: M[k][i][j] = sum_h Ws[k,h,i] * Wd[k,h,j]   (grid 128 = K*Z, block 32)
__global__ void k_attnM(const float* __restrict__ Ws, const float* __restrict__ Wd,
                        float* __restrict__ M) {
    int k = blockIdx.x >> 5;
    int i = blockIdx.x & 31;
    int j = threadIdx.x;
    float acc = 0.0f;
    for (int h = 0; h < HH; ++h)
        acc += Ws[(k*HH + h)*ZZ + i] * Wd[(k*HH + h)*ZZ + j];
    M[(k*ZZ + i)*ZZ + j] = acc;
}

// A1: qd[n,s,k,i] (bf16) = sum_j M[k][i][j] * zG[n,s,j]   (dst-side projection)
__global__ void k_qd(const float* __restrict__ zG, const float* __restrict__ M,
                     unsigned short* __restrict__ qdb) {
    int t = blockIdx.x * blockDim.x + threadIdx.x;
    if (t >= NN*SS*KK*ZZ) return;
    int i  = t & 31;
    int k  = (t >> 5) & 3;
    int ns = t >> 7;
    const float* zg = zG + ns*ZZ;
    const float* m  = M + (k*ZZ + i)*ZZ;
    float acc = 0.0f;
#pragma unroll
    for (int j = 0; j < ZZ; ++j) acc += m[j] * zg[j];
    qdb[t] = f2b(acc);
}

// deg count
__global__ void k_deg(const int* __restrict__ dst, int* __restrict__ deg_i) {
    int e = blockIdx.x * blockDim.x + threadIdx.x;
    if (e < NE) atomicAdd(deg_i + dst[e], 1);
}

// C2: exclusive scan of deg_i -> offsets[0..NN], cursor copy (1 block, Hillis-Steele)
__global__ void k_scan(const int* __restrict__ deg_i, int* __restrict__ offsets,
                       int* __restrict__ cursor) {
    __shared__ int buf0[1024], buf1[1024];
    int tidx = threadIdx.x;
    const int CH = (NN + 1023) / 1024;   // 10
    int b0 = tidx * CH;
    int sum = 0;
    for (int i = 0; i < CH; ++i) { int idx = b0 + i; if (idx < NN) sum += deg_i[idx]; }
    buf0[tidx] = sum;
    __syncthreads();
    int* s = buf0; int* d = buf1;
    for (int off = 1; off < 1024; off <<= 1) {
        d[tidx] = s[tidx] + (tidx >= off ? s[tidx - off] : 0);
        __syncthreads();
        int* tmp = s; s = d; d = tmp;
    }
    int run = s[tidx] - sum;
    for (int i = 0; i < CH; ++i) {
        int idx = b0 + i;
        if (idx < NN) { offsets[idx] = run; cursor[idx] = run; run += deg_i[idx]; }
    }
    if (tidx == 0) offsets[NN] = NE;
}

// C3: scatter src/dst node ids into dst-sorted position order
__global__ void k_scatter(const int* __restrict__ src, const int* __restrict__ dst,
                          int* __restrict__ cursor, int* __restrict__ src_by_pos,
                          int* __restrict__ dst_by_pos) {
    int e = blockIdx.x * blockDim.x + threadIdx.x;
    if (e >= NE) return;
    int sn = src[e], dn = dst[e];
    int pos = atomicAdd(cursor + dn, 1);
    src_by_pos[pos] = sn;
    dst_by_pos[pos] = dn;
}

// A2 v4: CSR-order scores; per-edge random side is zGb[src] (64B, L2-resident);
// qd[dst] reads shared by consecutive threads (same dst) -> L1 broadcast.
__global__ __launch_bounds__(256) void k_edge_e(
    const unsigned short* __restrict__ qdb, const unsigned short* __restrict__ zGb,
    const int* __restrict__ src_by_pos, const int* __restrict__ dst_by_pos,
    float* __restrict__ e_csr) {
    int t = blockIdx.x * blockDim.x + threadIdx.x;
    if (t >= NE*SS) return;
    int s = t & 1;
    int idx = t >> 1;
    int sn = src_by_pos[idx], dn = dst_by_pos[idx];
    const unsigned* zp = (const unsigned*)(zGb + (sn*SS + s)*ZZ);
    float zf[32];
#pragma unroll
    for (int j = 0; j < 16; ++j) {
        unsigned u = zp[j];
        zf[2*j]   = __uint_as_float(u << 16);
        zf[2*j+1] = __uint_as_float(u & 0xffff0000u);
    }
    const unsigned* qp = (const unsigned*)(qdb + (dn*SS + s)*KK*ZZ);
    float ev[4];
#pragma unroll
    for (int k = 0; k < 4; ++k) {
        float a = 0.f;
#pragma unroll
        for (int j = 0; j < 16; ++j) {
            unsigned u = qp[k*16 + j];
            a += __uint_as_float(u << 16) * zf[2*j]
               + __uint_as_float(u & 0xffff0000u) * zf[2*j+1];
        }
        ev[k] = a > 0.f ? a : 0.01f*a;
    }
    *(float4*)(e_csr + t*4) = *(float4*)ev;
}

// A3+A4 fused: per-(n,s) softmax stats in-wave, alpha written directly.
// alpha = exp(e - m) / (denom * deg)
__global__ __launch_bounds__(64) void k_salpha(
    const float* __restrict__ e_csr, const int* __restrict__ offsets,
    float* __restrict__ alpha) {
    int item = blockIdx.x;
    int n = item >> 1, s = item & 1;
    int l = threadIdx.x;
    int i = l >> 2, k = l & 3;
    int r0 = offsets[n], r1 = offsets[n+1];
    float mx = -1e30f;
    for (int idx = r0 + i; idx < r1; idx += 16)
        mx = fmaxf(mx, e_csr[(idx*2 + s)*4 + k]);
#pragma unroll
    for (int off = 4; off < 64; off <<= 1) mx = fmaxf(mx, __shfl_xor(mx, off));
    float sum = 0.f;
    for (int idx = r0 + i; idx < r1; idx += 16)
        sum += __expf(e_csr[(idx*2 + s)*4 + k] - mx);
#pragma unroll
    for (int off = 4; off < 64; off <<= 1) sum += __shfl_xor(sum, off);
    int deg = r1 - r0;
    float dd = (float)(deg > 1 ? deg : 1);
    float inv = sum > 0.f ? 1.f/(sum*dd) : 0.f;
    for (int idx = r0 + i; idx < r1; idx += 16)
        alpha[(idx*2 + s)*4 + k] = __expf(e_csr[(idx*2 + s)*4 + k] - mx) * inv;
}

// W0: convert all step-phase constants to bf16 (weights + zA + zG)
__global__ void k_conv_all(const float* __restrict__ F2w1, const float* __restrict__ F2w2,
                           const float* __restrict__ F1w1, const float* __restrict__ F1w2,
                           const float* __restrict__ ow1, const float* __restrict__ ow2,
                           const float* __restrict__ zA, const float* __restrict__ zG,
                           unsigned short* __restrict__ W1b, unsigned short* __restrict__ W2b,
                           unsigned short* __restrict__ F1w1b, unsigned short* __restrict__ F1w2b,
                           unsigned short* __restrict__ ow1b, unsigned short* __restrict__ ow2b,
                           unsigned short* __restrict__ zAb, unsigned short* __restrict__ zGb) {
    int t = blockIdx.x * blockDim.x + threadIdx.x;
    if (t < NN*SS*ZZ) { zAb[t] = f2b(zA[t]); zGb[t] = f2b(zG[t]); }
    if (t < HH*2*HH)  W1b[t] = f2b(F2w1[t]);
    if (t < HH*HH)    { W2b[t] = f2b(F2w2[t]); F1w2b[t] = f2b(F1w2[t]); }
    if (t < HH*KK*HH) F1w1b[t] = f2b(F1w1[t]);
    if (t < HH*(HH+ZZ)) ow1b[t] = f2b(ow1[t]);
    if (t < 4*HH)     ow2b[t] = f2b(ow2[t]);
}

// B0: xt[n,s,i] = inputs[n, 0, i]
__global__ void k_xt0(const float* __restrict__ inputs, float* __restrict__ xt) {
    int t = blockIdx.x * blockDim.x + threadIdx.x;
    if (t >= NN*SS*NIN) return;
    int i = t & 3;
    int n = t >> 3;
    xt[t] = inputs[n*(TT*NIN) + i];
}

// B1: xt_enc (bf16) = xt @ xenc_w.T + b
__global__ void k_xenc(const float* __restrict__ xt, const float* __restrict__ w,
                       const float* __restrict__ b, unsigned short* __restrict__ xtb) {
    int t = blockIdx.x * blockDim.x + threadIdx.x;
    if (t >= NN*SS*HH) return;
    int h  = t & 63;
    int ns = t >> 6;
    const float* x = xt + ns*NIN;
    float acc = b[h];
#pragma unroll
    for (int i = 0; i < NIN; ++i) acc += x[i] * w[h*NIN + i];
    xtb[t] = f2b(acc);
}

// B2: edge MLP MFMA GEMM, barrier-free direct-gather, persistent + 2-stage pipeline.
__global__ __launch_bounds__(256) void k_edge_mfma(
    const unsigned short* __restrict__ xtb, const unsigned short* __restrict__ W1b,
    const unsigned short* __restrict__ W2b, const int* __restrict__ src_by_pos,
    const int* __restrict__ dst_by_pos, unsigned short* __restrict__ dA)
{
    __shared__ unsigned short hid_s[4][16*72];
    const int NT = NE*SS/64;   // 5000 tiles
    int tid = threadIdx.x;
    int w = tid >> 6, l = tid & 63, l15 = l & 15, qq = l >> 4;
    int s = l15 & 1;
    int eslot = w*8 + (l15 >> 1);

    bf16x8 b1[4][4], b2[2][4];
#pragma unroll
    for (int nb = 0; nb < 4; ++nb) {
        int n = nb*16 + l15;
#pragma unroll
        for (int kb = 0; kb < 4; ++kb)
            b1[kb][nb] = *(const bf16x8*)(W1b + n*128 + kb*32 + qq*8);
#pragma unroll
        for (int kb = 0; kb < 2; ++kb)
            b2[kb][nb] = *(const bf16x8*)(W2b + n*64 + kb*32 + qq*8);
    }

    int G = gridDim.x;
    int t = blockIdx.x;

    int p0 = t*32 + eslot;
    int sn0 = src_by_pos[p0], dn0 = dst_by_pos[p0];
    const unsigned short* ps = xtb + (sn0*SS + s)*HH + qq*8;
    const unsigned short* pd = xtb + (dn0*SS + s)*HH + qq*8;
    bf16x8 a0 = *(const bf16x8*)(ps);
    bf16x8 a1 = *(const bf16x8*)(ps + 32);
    bf16x8 a2 = *(const bf16x8*)(pd);
    bf16x8 a3 = *(const bf16x8*)(pd + 32);
    int t1 = t + G;
    int tc1 = t1 < NT ? t1 : 0;
    int sn1 = src_by_pos[tc1*32 + eslot], dn1 = dst_by_pos[tc1*32 + eslot];

    for (; t < NT; t += G) {
        const unsigned short* ps1 = xtb + (sn1*SS + s)*HH + qq*8;
        const unsigned short* pd1 = xtb + (dn1*SS + s)*HH + qq*8;
        bf16x8 n0 = *(const bf16x8*)(ps1);
        bf16x8 n1 = *(const bf16x8*)(ps1 + 32);
        bf16x8 n2 = *(const bf16x8*)(pd1);
        bf16x8 n3 = *(const bf16x8*)(pd1 + 32);
        int t2 = t + 2*G;
        int tc2 = t2 < NT ? t2 : 0;
        int sn2 = src_by_pos[tc2*32 + eslot], dn2 = dst_by_pos[tc2*32 + eslot];

        f32x4 acc[4];
#pragma unroll
        for (int nb = 0; nb < 4; ++nb) acc[nb] = (f32x4)(0.0f);
#pragma unroll
        for (int nb = 0; nb < 4; ++nb) {
            acc[nb] = __builtin_amdgcn_mfma_f32_16x16x32_bf16(a0, b1[0][nb], acc[nb], 0, 0, 0);
            acc[nb] = __builtin_amdgcn_mfma_f32_16x16x32_bf16(a1, b1[1][nb], acc[nb], 0, 0, 0);
            acc[nb] = __builtin_amdgcn_mfma_f32_16x16x32_bf16(a2, b1[2][nb], acc[nb], 0, 0, 0);
            acc[nb] = __builtin_amdgcn_mfma_f32_16x16x32_bf16(a3, b1[3][nb], acc[nb], 0, 0, 0);
        }
        unsigned short* hw = hid_s[w];
#pragma unroll
        for (int nb = 0; nb < 4; ++nb)
#pragma unroll
            for (int r = 0; r < 4; ++r) {
                float v = acc[nb][r];
                hw[(qq*4 + r)*72 + nb*16 + l15] = f2b(v > 0.0f ? v : 0.0f);
            }
        f32x4 acc2[4];
#pragma unroll
        for (int nb = 0; nb < 4; ++nb) acc2[nb] = (f32x4)(0.0f);
        const unsigned short* a2row = hw + l15*72 + qq*8;
#pragma unroll
        for (int kb = 0; kb < 2; ++kb) {
            bf16x8 af = *(const bf16x8*)(a2row + kb*32);
#pragma unroll
            for (int nb = 0; nb < 4; ++nb)
                acc2[nb] = __builtin_amdgcn_mfma_f32_16x16x32_bf16(af, b2[kb][nb], acc2[nb], 0, 0, 0);
        }
        unsigned short* drow = dA + (t*64 + w*16)*64;
#pragma unroll
        for (int nb = 0; nb < 4; ++nb)
#pragma unroll
            for (int r = 0; r < 4; ++r)
                drow[(qq*4 + r)*64 + nb*16 + l15] = f2b(acc2[nb][r]);

        a0 = n0; a1 = n1; a2 = n2; a3 = n3;
        sn1 = sn2; dn1 = dn2;
    }
}

// B3 v2: fused aggregation + node MLPs. 4 waves/block, 16 items/wave.
// Wave aggregates its items' CSR rows into a per-wave LDS tile (GEMM1 A-layout),
// then runs the 4 chained GEMMs. F1w1 B-fragments stream from global (L2-hot).
// LDS: res 4*8448 + hid 4*2304 + hcat 4*3328 = 56,320 B.
__global__ __launch_bounds__(256) void k_node_mfma(
    const unsigned short* __restrict__ dA, const int* __restrict__ offsets,
    const float* __restrict__ alpha, const unsigned short* __restrict__ zAb,
    const unsigned short* __restrict__ F1w1b, const unsigned short* __restrict__ F1w2b,
    const unsigned short* __restrict__ ow1b, const unsigned short* __restrict__ ow2b,
    const float* __restrict__ ob1, const float* __restrict__ ob2,
    float* __restrict__ xt, float* __restrict__ out, int tstep)
{
    __shared__ unsigned short res_s[4][16*264];
    __shared__ unsigned short hid_s[4][16*72];
    __shared__ unsigned short hcat_s[4][16*104];
    int tid = threadIdx.x;
    int w = tid >> 6, l = tid & 63, l15 = l & 15, qq = l >> 4;

    bf16x8 b2f[2][4], o1f[3][4], bo2[2];
#pragma unroll
    for (int nb = 0; nb < 4; ++nb) {
        int n = nb*16 + l15;
#pragma unroll
        for (int kb = 0; kb < 2; ++kb)
            b2f[kb][nb] = *(const bf16x8*)(F1w2b + n*64 + kb*32 + qq*8);
#pragma unroll
        for (int kb = 0; kb < 3; ++kb)
            o1f[kb][nb] = *(const bf16x8*)(ow1b + n*96 + kb*32 + qq*8);
    }
#pragma unroll
    for (int kb = 0; kb < 2; ++kb) {
        if (l15 < 4) bo2[kb] = *(const bf16x8*)(ow2b + l15*64 + kb*32 + qq*8);
        else {
            bf16x8 z;
#pragma unroll
            for (int j = 0; j < 8; ++j) z[j] = 0;
            bo2[kb] = z;
        }
    }
    float b1v[4];
#pragma unroll
    for (int nb = 0; nb < 4; ++nb) b1v[nb] = ob1[nb*16 + l15];
    float b2v = (l15 < 4) ? ob2[l15] : 0.0f;

    int itemBase = blockIdx.x*64 + w*16;

    // stage zA into hcat cols 64..95 (clamped for tail)
    int zi = itemBase + l15; if (zi >= NN*SS) zi = NN*SS - 1;
    *(uint4*)(&hcat_s[w][l15*104 + 64 + qq*8]) = *(const uint4*)(zAb + zi*ZZ + qq*8);

    // ---- aggregation: per item ii, lane l = column h of dA ----
    for (int ii = 0; ii < 16; ++ii) {
        int item = itemBase + ii;
        float a0 = 0.f, a1 = 0.f, a2 = 0.f, a3 = 0.f;
        if (item < NN*SS) {
            int n = item >> 1, s = item & 1;
            int r0 = offsets[n], r1 = offsets[n+1];
            for (int idx = r0; idx < r1; ++idx) {
                int row = idx*2 + s;
                const float4 w4 = *(const float4*)(alpha + row*4);
                float v = bf2f(dA[row*64 + l]);
                a0 += w4.x*v; a1 += w4.y*v; a2 += w4.z*v; a3 += w4.w*v;
            }
        }
        unsigned short* rr = &res_s[w][ii*264];
        rr[l]       = f2b(a0);
        rr[64 + l]  = f2b(a1);
        rr[128 + l] = f2b(a2);
        rr[192 + l] = f2b(a3);
    }

    // ---- GEMM1: res[16x256] @ F1w1^T[256x64], relu (B streamed from global) ----
    f32x4 acc[4];
#pragma unroll
    for (int nb = 0; nb < 4; ++nb) acc[nb] = (f32x4)(0.0f);
#pragma unroll
    for (int kb = 0; kb < 8; ++kb) {
        bf16x8 af = *(const bf16x8*)(&res_s[w][l15*264 + kb*32 + qq*8]);
#pragma unroll
        for (int nb = 0; nb < 4; ++nb) {
            bf16x8 bf = *(const bf16x8*)(F1w1b + (nb*16 + l15)*256 + kb*32 + qq*8);
            acc[nb] = __builtin_amdgcn_mfma_f32_16x16x32_bf16(af, bf, acc[nb], 0, 0, 0);
        }
    }
#pragma unroll
    for (int nb = 0; nb < 4; ++nb)
#pragma unroll
        for (int r = 0; r < 4; ++r) {
            float v = acc[nb][r];
            hid_s[w][(qq*4 + r)*72 + nb*16 + l15] = f2b(v > 0.0f ? v : 0.0f);
        }

    // ---- GEMM2: hid[16x64] @ F1w2^T[64x64] -> deltax -> hcat cols 0..63 ----
    f32x4 acc2[4];
#pragma unroll
    for (int nb = 0; nb < 4; ++nb) acc2[nb] = (f32x4)(0.0f);
#pragma unroll
    for (int kb = 0; kb < 2; ++kb) {
        bf16x8 af = *(const bf16x8*)(&hid_s[w][l15*72 + kb*32 + qq*8]);
#pragma unroll
        for (int nb = 0; nb < 4; ++nb)
            acc2[nb] = __builtin_amdgcn_mfma_f32_16x16x32_bf16(af, b2f[kb][nb], acc2[nb], 0, 0, 0);
    }
#pragma unroll
    for (int nb = 0; nb < 4; ++nb)
#pragma unroll
        for (int r = 0; r < 4; ++r)
            hcat_s[w][(qq*4 + r)*104 + nb*16 + l15] = f2b(acc2[nb][r]);

    // ---- GEMM3: hcat[16x96] @ ow1^T[96x64] + b1, relu -> hid_s ----
    f32x4 acc3[4];
#pragma unroll
    for (int nb = 0; nb < 4; ++nb) acc3[nb] = (f32x4)(0.0f);
#pragma unroll
    for (int kb = 0; kb < 3; ++kb) {
        bf16x8 af = *(const bf16x8*)(&hcat_s[w][l15*104 + kb*32 + qq*8]);
#pragma unroll
        for (int nb = 0; nb < 4; ++nb)
            acc3[nb] = __builtin_amdgcn_mfma_f32_16x16x32_bf16(af, o1f[kb][nb], acc3[nb], 0, 0, 0);
    }
#pragma unroll
    for (int nb = 0; nb < 4; ++nb)
#pragma unroll
        for (int r = 0; r < 4; ++r) {
            float v = acc3[nb][r] + b1v[nb];
            hid_s[w][(qq*4 + r)*72 + nb*16 + l15] = f2b(v > 0.0f ? v : 0.0f);
        }

    // ---- GEMM4: hid[16x64] @ ow2^T[64x4(pad16)] + b2 ----
    f32x4 acc4 = (f32x4)(0.0f);
#pragma unroll
    for (int kb = 0; kb < 2; ++kb) {
        bf16x8 af = *(const bf16x8*)(&hid_s[w][l15*72 + kb*32 + qq*8]);
        acc4 = __builtin_amdgcn_mfma_f32_16x16x32_bf16(af, bo2[kb], acc4, 0, 0, 0);
    }
    if (l15 < 4) {
#pragma unroll
        for (int r = 0; r < 4; ++r) {
            int item = itemBase + qq*4 + r;
            if (item < NN*SS) {
                float nx = xt[item*4 + l15] + acc4[r] + b2v;
                xt[item*4 + l15] = nx;
                int n = item >> 1, s = item & 1;
                out[((n*TT + tstep)*SS + s)*4 + l15] = nx;
            }
        }
    }
}

extern "C" void kernel_launch(void* const* d_in, const int* in_sizes, int n_in,
                              void* d_out, int out_size, void* d_ws, size_t ws_size,
                              hipStream_t stream) {
    const float* inputs = (const float*)d_in[0];
    const float* zA     = (const float*)d_in[1];
    const float* zG     = (const float*)d_in[2];
    const int*   src    = (const int*)d_in[3];
    const int*   dst    = (const int*)d_in[4];
    const float* Ws     = (const float*)d_in[5];
    const float* Wd     = (const float*)d_in[6];
    const float* F2w1   = (const float*)d_in[7];
    const float* F2w2   = (const float*)d_in[8];
    const float* F1w1   = (const float*)d_in[9];
    const float* F1w2   = (const float*)d_in[10];
    const float* xw     = (const float*)d_in[11];
    const float* xb     = (const float*)d_in[12];
    const float* ow1    = (const float*)d_in[13];
    const float* ob1    = (const float*)d_in[14];
    const float* ow2    = (const float*)d_in[15];
    const float* ob2    = (const float*)d_in[16];
    float* out = (float*)d_out;

    // ---- workspace carve (units: floats) ----
    float*          base        = (float*)d_ws;
    float*          M           = base;                              // 4,096
    float*          e_csr       = base + 4096;                       // 1,280,000
    float*          alpha       = base + 1284096;                    // 1,280,000
    int*            deg_i       = (int*)(base + 2564096);            // 10,000 (zeroed)
    int*            offsets     = (int*)(base + 2574096);            // 10,016
    int*            cursor      = (int*)(base + 2584112);            // 10,000
    int*            src_by_pos  = (int*)(base + 2594112);            // 160,000
    int*            dst_by_pos  = (int*)(base + 2754112);            // 160,000
    float*          xt          = base + 2914112;                    // 80,000
    unsigned short* xtb         = (unsigned short*)(base + 2994112); // 1,280,000 ush
    unsigned short* W1b         = (unsigned short*)(base + 3634112); // 8,192 ush
    unsigned short* W2b         = (unsigned short*)(base + 3638208); // 4,096 ush
    unsigned short* F1w1b       = (unsigned short*)(base + 3640256); // 16,384 ush
    unsigned short* F1w2b       = (unsigned short*)(base + 3648448); // 4,096 ush
    unsigned short* ow1b        = (unsigned short*)(base + 3650496); // 6,144 ush
    unsigned short* ow2b        = (unsigned short*)(base + 3653568); // 256 ush
    unsigned short* zAb         = (unsigned short*)(base + 3653696); // 640,000 ush
    unsigned short* zGb         = (unsigned short*)(base + 3973696); // 640,000 ush
    // phase union @ 4,293,696: qdb (2.56M ush, attention) / dA (20.48M ush, steps)
    unsigned short* qdb         = (unsigned short*)(base + 4293696);
    unsigned short* dA          = (unsigned short*)(base + 4293696);
    // total 14,533,696 floats = 58.1 MB

    hipMemsetAsync(deg_i, 0, 10000u * 4u, stream);

    // ---- attention phase (once) ----
    k_attnM<<<KK*ZZ, ZZ, 0, stream>>>(Ws, Wd, M);
    k_qd<<<(NN*SS*KK*ZZ + 255)/256, 256, 0, stream>>>(zG, M, qdb);
    k_conv_all<<<(NN*SS*ZZ + 255)/256, 256, 0, stream>>>(F2w1, F2w2, F1w1, F1w2, ow1, ow2,
                                                         zA, zG, W1b, W2b, F1w1b, F1w2b,
                                                         ow1b, ow2b, zAb, zGb);
    k_deg<<<(NE + 255)/256, 256, 0, stream>>>(dst, deg_i);
    k_scan<<<1, 1024, 0, stream>>>(deg_i, offsets, cursor);
    k_scatter<<<(NE + 255)/256, 256, 0, stream>>>(src, dst, cursor, src_by_pos, dst_by_pos);
    k_edge_e<<<(NE*SS + 255)/256, 256, 0, stream>>>(qdb, zGb, src_by_pos, dst_by_pos, e_csr);
    k_salpha<<<NN*SS, 64, 0, stream>>>(e_csr, offsets, alpha);

    // ---- time stepping ----
    k_xt0<<<(NN*SS*NIN + 255)/256, 256, 0, stream>>>(inputs, xt);
    for (int t = 0; t < 2; ++t) {
        k_xenc<<<(NN*SS*HH + 255)/256, 256, 0, stream>>>(xt, xw, xb, xtb);
        k_edge_mfma<<<1024, 256, 0, stream>>>(xtb, W1b, W2b, src_by_pos, dst_by_pos, dA);
        k_node_mfma<<<(NN*SS + 63)/64, 256, 0, stream>>>(dA, offsets, alpha, zAb,
                                                         F1w1b, F1w2b, ow1b, ow2b,
                                                         ob1, ob2, xt, out, t);
    }
}

// Round 8
// 361.265 us; speedup vs baseline: 1.3352x; 1.3352x over previous
//
#include <hip/hip_runtime.h>

#define NN 10000
#define NE 160000
#define TT 2
#define SS 2
#define HH 64
#define ZZ 32
#define KK 4
#define NIN 4

typedef short bf16x8 __attribute__((ext_vector_type(8)));
typedef float f32x4 __attribute__((ext_vector_type(4)));

// fp32 -> bf16 (RNE)
__device__ __forceinline__ unsigned short f2b(float x) {
    unsigned u = __float_as_uint(x);
    u += 0x7fffu + ((u >> 16) & 1u);
    return (unsigned short)(u >> 16);
}
__device__ __forceinline__ float bf2f(unsigned short u) {
    return __uint_as_float(((unsigned)u) << 16);
}

// A0: M[k][i][j] = sum_h Ws[k,h,i] * Wd[k,h,j]   (grid 128 = K*Z, block 32)
__global__ void k_attnM(const float* __restrict__ Ws, const float* __restrict__ Wd,
                        float* __restrict__ M) {
    int k = blockIdx.x >> 5;
    int i = blockIdx.x & 31;
    int j = threadIdx.x;
    float acc = 0.0f;
    for (int h = 0; h < HH; ++h)
        acc += Ws[(k*HH + h)*ZZ + i] * Wd[(k*HH + h)*ZZ + j];
    M[(k*ZZ + i)*ZZ + j] = acc;
}

// A1: qd[n,s,k,i] (bf16) = sum_j M[k][i][j] * zG[n,s,j]   (dst-side projection)
__global__ void k_qd(const float* __restrict__ zG, const float* __restrict__ M,
                     unsigned short* __restrict__ qdb) {
    int t = blockIdx.x * blockDim.x + threadIdx.x;
    if (t >= NN*SS*KK*ZZ) return;
    int i  = t & 31;
    int k  = (t >> 5) & 3;
    int ns = t >> 7;
    const float* zg = zG + ns*ZZ;
    const float* m  = M + (k*ZZ + i)*ZZ;
    float acc = 0.0f;
#pragma unroll
    for (int j = 0; j < ZZ; ++j) acc += m[j] * zg[j];
    qdb[t] = f2b(acc);
}

// deg count
__global__ void k_deg(const int* __restrict__ dst, int* __restrict__ deg_i) {
    int e = blockIdx.x * blockDim.x + threadIdx.x;
    if (e < NE) atomicAdd(deg_i + dst[e], 1);
}

// C2: exclusive scan of deg_i -> offsets[0..NN], cursor copy (1 block, Hillis-Steele)
__global__ void k_scan(const int* __restrict__ deg_i, int* __restrict__ offsets,
                       int* __restrict__ cursor) {
    __shared__ int buf0[1024], buf1[1024];
    int tidx = threadIdx.x;
    const int CH = (NN + 1023) / 1024;   // 10
    int b0 = tidx * CH;
    int sum = 0;
    for (int i = 0; i < CH; ++i) { int idx = b0 + i; if (idx < NN) sum += deg_i[idx]; }
    buf0[tidx] = sum;
    __syncthreads();
    int* s = buf0; int* d = buf1;
    for (int off = 1; off < 1024; off <<= 1) {
        d[tidx] = s[tidx] + (tidx >= off ? s[tidx - off] : 0);
        __syncthreads();
        int* tmp = s; s = d; d = tmp;
    }
    int run = s[tidx] - sum;
    for (int i = 0; i < CH; ++i) {
        int idx = b0 + i;
        if (idx < NN) { offsets[idx] = run; cursor[idx] = run; run += deg_i[idx]; }
    }
    if (tidx == 0) offsets[NN] = NE;
}

// C3: scatter src/dst node ids into dst-sorted position order
__global__ void k_scatter(const int* __restrict__ src, const int* __restrict__ dst,
                          int* __restrict__ cursor, int* __restrict__ src_by_pos,
                          int* __restrict__ dst_by_pos) {
    int e = blockIdx.x * blockDim.x + threadIdx.x;
    if (e >= NE) return;
    int sn = src[e], dn = dst[e];
    int pos = atomicAdd(cursor + dn, 1);
    src_by_pos[pos] = sn;
    dst_by_pos[pos] = dn;
}

// A2: CSR-order scores; per-edge random side is zGb[src] (64B, L2-resident);
// qd[dst] reads shared by consecutive threads (same dst) -> L1 broadcast.
__global__ __launch_bounds__(256) void k_edge_e(
    const unsigned short* __restrict__ qdb, const unsigned short* __restrict__ zGb,
    const int* __restrict__ src_by_pos, const int* __restrict__ dst_by_pos,
    float* __restrict__ e_csr) {
    int t = blockIdx.x * blockDim.x + threadIdx.x;
    if (t >= NE*SS) return;
    int s = t & 1;
    int idx = t >> 1;
    int sn = src_by_pos[idx], dn = dst_by_pos[idx];
    const unsigned* zp = (const unsigned*)(zGb + (sn*SS + s)*ZZ);
    float zf[32];
#pragma unroll
    for (int j = 0; j < 16; ++j) {
        unsigned u = zp[j];
        zf[2*j]   = __uint_as_float(u << 16);
        zf[2*j+1] = __uint_as_float(u & 0xffff0000u);
    }
    const unsigned* qp = (const unsigned*)(qdb + (dn*SS + s)*KK*ZZ);
    float ev[4];
#pragma unroll
    for (int k = 0; k < 4; ++k) {
        float a = 0.f;
#pragma unroll
        for (int j = 0; j < 16; ++j) {
            unsigned u = qp[k*16 + j];
            a += __uint_as_float(u << 16) * zf[2*j]
               + __uint_as_float(u & 0xffff0000u) * zf[2*j+1];
        }
        ev[k] = a > 0.f ? a : 0.01f*a;
    }
    *(float4*)(e_csr + t*4) = *(float4*)ev;
}

// A3+A4 fused: per-(n,s) softmax stats in-wave, alpha written directly.
// alpha = exp(e - m) / (denom * deg)
__global__ __launch_bounds__(64) void k_salpha(
    const float* __restrict__ e_csr, const int* __restrict__ offsets,
    float* __restrict__ alpha) {
    int item = blockIdx.x;
    int n = item >> 1, s = item & 1;
    int l = threadIdx.x;
    int i = l >> 2, k = l & 3;
    int r0 = offsets[n], r1 = offsets[n+1];
    float mx = -1e30f;
    for (int idx = r0 + i; idx < r1; idx += 16)
        mx = fmaxf(mx, e_csr[(idx*2 + s)*4 + k]);
#pragma unroll
    for (int off = 4; off < 64; off <<= 1) mx = fmaxf(mx, __shfl_xor(mx, off));
    float sum = 0.f;
    for (int idx = r0 + i; idx < r1; idx += 16)
        sum += __expf(e_csr[(idx*2 + s)*4 + k] - mx);
#pragma unroll
    for (int off = 4; off < 64; off <<= 1) sum += __shfl_xor(sum, off);
    int deg = r1 - r0;
    float dd = (float)(deg > 1 ? deg : 1);
    float inv = sum > 0.f ? 1.f/(sum*dd) : 0.f;
    for (int idx = r0 + i; idx < r1; idx += 16)
        alpha[(idx*2 + s)*4 + k] = __expf(e_csr[(idx*2 + s)*4 + k] - mx) * inv;
}

// W0: convert all step-phase constants to bf16 (weights + zA + zG)
__global__ void k_conv_all(const float* __restrict__ F2w1, const float* __restrict__ F2w2,
                           const float* __restrict__ F1w1, const float* __restrict__ F1w2,
                           const float* __restrict__ ow1, const float* __restrict__ ow2,
                           const float* __restrict__ zA, const float* __restrict__ zG,
                           unsigned short* __restrict__ W1b, unsigned short* __restrict__ W2b,
                           unsigned short* __restrict__ F1w1b, unsigned short* __restrict__ F1w2b,
                           unsigned short* __restrict__ ow1b, unsigned short* __restrict__ ow2b,
                           unsigned short* __restrict__ zAb, unsigned short* __restrict__ zGb) {
    int t = blockIdx.x * blockDim.x + threadIdx.x;
    if (t < NN*SS*ZZ) { zAb[t] = f2b(zA[t]); zGb[t] = f2b(zG[t]); }
    if (t < HH*2*HH)  W1b[t] = f2b(F2w1[t]);
    if (t < HH*HH)    { W2b[t] = f2b(F2w2[t]); F1w2b[t] = f2b(F1w2[t]); }
    if (t < HH*KK*HH) F1w1b[t] = f2b(F1w1[t]);
    if (t < HH*(HH+ZZ)) ow1b[t] = f2b(ow1[t]);
    if (t < 4*HH)     ow2b[t] = f2b(ow2[t]);
}

// B0: xt[n,s,i] = inputs[n, 0, i]
__global__ void k_xt0(const float* __restrict__ inputs, float* __restrict__ xt) {
    int t = blockIdx.x * blockDim.x + threadIdx.x;
    if (t >= NN*SS*NIN) return;
    int i = t & 3;
    int n = t >> 3;
    xt[t] = inputs[n*(TT*NIN) + i];
}

// B1: xt_enc (bf16) = xt @ xenc_w.T + b
__global__ void k_xenc(const float* __restrict__ xt, const float* __restrict__ w,
                       const float* __restrict__ b, unsigned short* __restrict__ xtb) {
    int t = blockIdx.x * blockDim.x + threadIdx.x;
    if (t >= NN*SS*HH) return;
    int h  = t & 63;
    int ns = t >> 6;
    const float* x = xt + ns*NIN;
    float acc = b[h];
#pragma unroll
    for (int i = 0; i < NIN; ++i) acc += x[i] * w[h*NIN + i];
    xtb[t] = f2b(acc);
}

// B2: edge MLP MFMA GEMM, barrier-free direct-gather, persistent + 2-stage pipeline.
__global__ __launch_bounds__(256) void k_edge_mfma(
    const unsigned short* __restrict__ xtb, const unsigned short* __restrict__ W1b,
    const unsigned short* __restrict__ W2b, const int* __restrict__ src_by_pos,
    const int* __restrict__ dst_by_pos, unsigned short* __restrict__ dA)
{
    __shared__ unsigned short hid_s[4][16*72];
    const int NT = NE*SS/64;   // 5000 tiles
    int tid = threadIdx.x;
    int w = tid >> 6, l = tid & 63, l15 = l & 15, qq = l >> 4;
    int s = l15 & 1;
    int eslot = w*8 + (l15 >> 1);

    bf16x8 b1[4][4], b2[2][4];
#pragma unroll
    for (int nb = 0; nb < 4; ++nb) {
        int n = nb*16 + l15;
#pragma unroll
        for (int kb = 0; kb < 4; ++kb)
            b1[kb][nb] = *(const bf16x8*)(W1b + n*128 + kb*32 + qq*8);
#pragma unroll
        for (int kb = 0; kb < 2; ++kb)
            b2[kb][nb] = *(const bf16x8*)(W2b + n*64 + kb*32 + qq*8);
    }

    int G = gridDim.x;
    int t = blockIdx.x;
    if (t >= NT) return;

    int p0 = t*32 + eslot;
    int sn0 = src_by_pos[p0], dn0 = dst_by_pos[p0];
    const unsigned short* ps = xtb + (sn0*SS + s)*HH + qq*8;
    const unsigned short* pd = xtb + (dn0*SS + s)*HH + qq*8;
    bf16x8 a0 = *(const bf16x8*)(ps);
    bf16x8 a1 = *(const bf16x8*)(ps + 32);
    bf16x8 a2 = *(const bf16x8*)(pd);
    bf16x8 a3 = *(const bf16x8*)(pd + 32);
    int t1 = t + G;
    int tc1 = t1 < NT ? t1 : 0;
    int sn1 = src_by_pos[tc1*32 + eslot], dn1 = dst_by_pos[tc1*32 + eslot];

    for (; t < NT; t += G) {
        const unsigned short* ps1 = xtb + (sn1*SS + s)*HH + qq*8;
        const unsigned short* pd1 = xtb + (dn1*SS + s)*HH + qq*8;
        bf16x8 n0 = *(const bf16x8*)(ps1);
        bf16x8 n1 = *(const bf16x8*)(ps1 + 32);
        bf16x8 n2 = *(const bf16x8*)(pd1);
        bf16x8 n3 = *(const bf16x8*)(pd1 + 32);
        int t2 = t + 2*G;
        int tc2 = t2 < NT ? t2 : 0;
        int sn2 = src_by_pos[tc2*32 + eslot], dn2 = dst_by_pos[tc2*32 + eslot];

        f32x4 acc[4];
#pragma unroll
        for (int nb = 0; nb < 4; ++nb) acc[nb] = (f32x4)(0.0f);
#pragma unroll
        for (int nb = 0; nb < 4; ++nb) {
            acc[nb] = __builtin_amdgcn_mfma_f32_16x16x32_bf16(a0, b1[0][nb], acc[nb], 0, 0, 0);
            acc[nb] = __builtin_amdgcn_mfma_f32_16x16x32_bf16(a1, b1[1][nb], acc[nb], 0, 0, 0);
            acc[nb] = __builtin_amdgcn_mfma_f32_16x16x32_bf16(a2, b1[2][nb], acc[nb], 0, 0, 0);
            acc[nb] = __builtin_amdgcn_mfma_f32_16x16x32_bf16(a3, b1[3][nb], acc[nb], 0, 0, 0);
        }
        unsigned short* hw = hid_s[w];
#pragma unroll
        for (int nb = 0; nb < 4; ++nb)
#pragma unroll
            for (int r = 0; r < 4; ++r) {
                float v = acc[nb][r];
                hw[(qq*4 + r)*72 + nb*16 + l15] = f2b(v > 0.0f ? v : 0.0f);
            }
        f32x4 acc2[4];
#pragma unroll
        for (int nb = 0; nb < 4; ++nb) acc2[nb] = (f32x4)(0.0f);
        const unsigned short* a2row = hw + l15*72 + qq*8;
#pragma unroll
        for (int kb = 0; kb < 2; ++kb) {
            bf16x8 af = *(const bf16x8*)(a2row + kb*32);
#pragma unroll
            for (int nb = 0; nb < 4; ++nb)
                acc2[nb] = __builtin_amdgcn_mfma_f32_16x16x32_bf16(af, b2[kb][nb], acc2[nb], 0, 0, 0);
        }
        unsigned short* drow = dA + (t*64 + w*16)*64;
#pragma unroll
        for (int nb = 0; nb < 4; ++nb)
#pragma unroll
            for (int r = 0; r < 4; ++r)
                drow[(qq*4 + r)*64 + nb*16 + l15] = f2b(acc2[nb][r]);

        a0 = n0; a1 = n1; a2 = n2; a3 = n3;
        sn1 = sn2; dn1 = dn2;
    }
}

// B2b: aggregation per (n,s): pure stream of alpha (broadcast) + dA rows
__global__ __launch_bounds__(64) void k_agg(
    const unsigned short* __restrict__ dA, const int* __restrict__ offsets,
    const float* __restrict__ alpha, unsigned short* __restrict__ res_b)
{
    int item = blockIdx.x;
    int n = item >> 1, s = item & 1;
    int h = threadIdx.x;
    int r0 = offsets[n], r1 = offsets[n+1];
    float a0 = 0.f, a1 = 0.f, a2 = 0.f, a3 = 0.f;
    for (int idx = r0; idx < r1; ++idx) {
        int row = idx*2 + s;
        const float4 w4 = *(const float4*)(alpha + row*4);
        unsigned short uv = dA[row*64 + h];
        float v = bf2f(uv);
        a0 += w4.x*v; a1 += w4.y*v; a2 += w4.z*v; a3 += w4.w*v;
    }
    res_b[item*256 +       h] = f2b(a0);
    res_b[item*256 + 64  + h] = f2b(a1);
    res_b[item*256 + 128 + h] = f2b(a2);
    res_b[item*256 + 192 + h] = f2b(a3);
}

// B3: node update as chained bf16 MFMA GEMMs. 4 waves/block, 16 items/wave.
// All weights stream from global (L2-hot). LDS = per-wave scratch only (22.5 KB),
// no __syncthreads -> higher occupancy than LDS-staged variant.
__global__ __launch_bounds__(256) void k_node_mfma(
    const unsigned short* __restrict__ res_b, const unsigned short* __restrict__ zAb,
    const unsigned short* __restrict__ F1w1b, const unsigned short* __restrict__ F1w2b,
    const unsigned short* __restrict__ ow1b, const unsigned short* __restrict__ ow2b,
    const float* __restrict__ ob1, const float* __restrict__ ob2,
    float* __restrict__ xt, float* __restrict__ out, int tstep)
{
    __shared__ unsigned short hid_s[4][16*72];
    __shared__ unsigned short hcat_s[4][16*104];
    int tid = threadIdx.x;
    int w = tid >> 6, l = tid & 63, l15 = l & 15, qq = l >> 4;

    bf16x8 b2f[2][4], o1f[3][4], bo2[2];
#pragma unroll
    for (int nb = 0; nb < 4; ++nb) {
        int n = nb*16 + l15;
#pragma unroll
        for (int kb = 0; kb < 2; ++kb)
            b2f[kb][nb] = *(const bf16x8*)(F1w2b + n*64 + kb*32 + qq*8);
#pragma unroll
        for (int kb = 0; kb < 3; ++kb)
            o1f[kb][nb] = *(const bf16x8*)(ow1b + n*96 + kb*32 + qq*8);
    }
#pragma unroll
    for (int kb = 0; kb < 2; ++kb) {
        if (l15 < 4) bo2[kb] = *(const bf16x8*)(ow2b + l15*64 + kb*32 + qq*8);
        else {
            bf16x8 z;
#pragma unroll
            for (int j = 0; j < 8; ++j) z[j] = 0;
            bo2[kb] = z;
        }
    }
    float b1v[4];
#pragma unroll
    for (int nb = 0; nb < 4; ++nb) b1v[nb] = ob1[nb*16 + l15];
    float b2v = (l15 < 4) ? ob2[l15] : 0.0f;

    int itemBase = blockIdx.x*64 + w*16;
    if (itemBase >= NN*SS) return;

    *(uint4*)(&hcat_s[w][l15*104 + 64 + qq*8]) =
        *(const uint4*)(zAb + (itemBase + l15)*ZZ + qq*8);

    // ---- GEMM1: res[16x256] @ F1w1^T[256x64], relu (B streamed from global) ----
    f32x4 acc[4];
#pragma unroll
    for (int nb = 0; nb < 4; ++nb) acc[nb] = (f32x4)(0.0f);
#pragma unroll
    for (int kb = 0; kb < 8; ++kb) {
        bf16x8 af = *(const bf16x8*)(res_b + (itemBase + l15)*256 + kb*32 + qq*8);
#pragma unroll
        for (int nb = 0; nb < 4; ++nb) {
            bf16x8 bf = *(const bf16x8*)(F1w1b + (nb*16 + l15)*256 + kb*32 + qq*8);
            acc[nb] = __builtin_amdgcn_mfma_f32_16x16x32_bf16(af, bf, acc[nb], 0, 0, 0);
        }
    }
#pragma unroll
    for (int nb = 0; nb < 4; ++nb)
#pragma unroll
        for (int r = 0; r < 4; ++r) {
            float v = acc[nb][r];
            hid_s[w][(qq*4 + r)*72 + nb*16 + l15] = f2b(v > 0.0f ? v : 0.0f);
        }

    // ---- GEMM2: hid[16x64] @ F1w2^T[64x64] -> deltax -> hcat cols 0..63 ----
    f32x4 acc2[4];
#pragma unroll
    for (int nb = 0; nb < 4; ++nb) acc2[nb] = (f32x4)(0.0f);
#pragma unroll
    for (int kb = 0; kb < 2; ++kb) {
        bf16x8 af = *(const bf16x8*)(&hid_s[w][l15*72 + kb*32 + qq*8]);
#pragma unroll
        for (int nb = 0; nb < 4; ++nb)
            acc2[nb] = __builtin_amdgcn_mfma_f32_16x16x32_bf16(af, b2f[kb][nb], acc2[nb], 0, 0, 0);
    }
#pragma unroll
    for (int nb = 0; nb < 4; ++nb)
#pragma unroll
        for (int r = 0; r < 4; ++r)
            hcat_s[w][(qq*4 + r)*104 + nb*16 + l15] = f2b(acc2[nb][r]);

    // ---- GEMM3: hcat[16x96] @ ow1^T[96x64] + b1, relu -> hid_s ----
    f32x4 acc3[4];
#pragma unroll
    for (int nb = 0; nb < 4; ++nb) acc3[nb] = (f32x4)(0.0f);
#pragma unroll
    for (int kb = 0; kb < 3; ++kb) {
        bf16x8 af = *(const bf16x8*)(&hcat_s[w][l15*104 + kb*32 + qq*8]);
#pragma unroll
        for (int nb = 0; nb < 4; ++nb)
            acc3[nb] = __builtin_amdgcn_mfma_f32_16x16x32_bf16(af, o1f[kb][nb], acc3[nb], 0, 0, 0);
    }
#pragma unroll
    for (int nb = 0; nb < 4; ++nb)
#pragma unroll
        for (int r = 0; r < 4; ++r) {
            float v = acc3[nb][r] + b1v[nb];
            hid_s[w][(qq*4 + r)*72 + nb*16 + l15] = f2b(v > 0.0f ? v : 0.0f);
        }

    // ---- GEMM4: hid[16x64] @ ow2^T[64x4(pad16)] + b2 ----
    f32x4 acc4 = (f32x4)(0.0f);
#pragma unroll
    for (int kb = 0; kb < 2; ++kb) {
        bf16x8 af = *(const bf16x8*)(&hid_s[w][l15*72 + kb*32 + qq*8]);
        acc4 = __builtin_amdgcn_mfma_f32_16x16x32_bf16(af, bo2[kb], acc4, 0, 0, 0);
    }
    if (l15 < 4) {
#pragma unroll
        for (int r = 0; r < 4; ++r) {
            int item = itemBase + qq*4 + r;
            float nx = xt[item*4 + l15] + acc4[r] + b2v;
            xt[item*4 + l15] = nx;
            int n = item >> 1, s = item & 1;
            out[((n*TT + tstep)*SS + s)*4 + l15] = nx;
        }
    }
}

extern "C" void kernel_launch(void* const* d_in, const int* in_sizes, int n_in,
                              void* d_out, int out_size, void* d_ws, size_t ws_size,
                              hipStream_t stream) {
    const float* inputs = (const float*)d_in[0];
    const float* zA     = (const float*)d_in[1];
    const float* zG     = (const float*)d_in[2];
    const int*   src    = (const int*)d_in[3];
    const int*   dst    = (const int*)d_in[4];
    const float* Ws     = (const float*)d_in[5];
    const float* Wd     = (const float*)d_in[6];
    const float* F2w1   = (const float*)d_in[7];
    const float* F2w2   = (const float*)d_in[8];
    const float* F1w1   = (const float*)d_in[9];
    const float* F1w2   = (const float*)d_in[10];
    const float* xw     = (const float*)d_in[11];
    const float* xb     = (const float*)d_in[12];
    const float* ow1    = (const float*)d_in[13];
    const float* ob1    = (const float*)d_in[14];
    const float* ow2    = (const float*)d_in[15];
    const float* ob2    = (const float*)d_in[16];
    float* out = (float*)d_out;

    // ---- workspace carve (units: floats) ----
    float*          base        = (float*)d_ws;
    float*          M           = base;                              // 4,096
    float*          e_csr       = base + 4096;                       // 1,280,000
    float*          alpha       = base + 1284096;                    // 1,280,000
    int*            deg_i       = (int*)(base + 2564096);            // 10,000 (zeroed)
    int*            offsets     = (int*)(base + 2574096);            // 10,016
    int*            cursor      = (int*)(base + 2584112);            // 10,000
    int*            src_by_pos  = (int*)(base + 2594112);            // 160,000
    int*            dst_by_pos  = (int*)(base + 2754112);            // 160,000
    float*          xt          = base + 2914112;                    // 80,000
    unsigned short* xtb         = (unsigned short*)(base + 2994112); // 1,280,000 ush
    unsigned short* W1b         = (unsigned short*)(base + 3634112); // 8,192 ush
    unsigned short* W2b         = (unsigned short*)(base + 3638208); // 4,096 ush
    unsigned short* F1w1b       = (unsigned short*)(base + 3640256); // 16,384 ush
    unsigned short* F1w2b       = (unsigned short*)(base + 3648448); // 4,096 ush
    unsigned short* ow1b        = (unsigned short*)(base + 3650496); // 6,144 ush
    unsigned short* ow2b        = (unsigned short*)(base + 3653568); // 256 ush
    unsigned short* zAb         = (unsigned short*)(base + 3653696); // 640,000 ush
    unsigned short* zGb         = (unsigned short*)(base + 3973696); // 640,000 ush
    unsigned short* res_b       = (unsigned short*)(base + 4293696); // 5,120,000 ush
    // phase union @ 6,853,696: qdb (2.56M ush, attention) / dA (20.48M ush, steps)
    unsigned short* qdb         = (unsigned short*)(base + 6853696);
    unsigned short* dA          = (unsigned short*)(base + 6853696);
    // total 17,093,696 floats = 68.4 MB

    hipMemsetAsync(deg_i, 0, 10000u * 4u, stream);

    // ---- attention phase (once) ----
    k_attnM<<<KK*ZZ, ZZ, 0, stream>>>(Ws, Wd, M);
    k_qd<<<(NN*SS*KK*ZZ + 255)/256, 256, 0, stream>>>(zG, M, qdb);
    k_conv_all<<<(NN*SS*ZZ + 255)/256, 256, 0, stream>>>(F2w1, F2w2, F1w1, F1w2, ow1, ow2,
                                                         zA, zG, W1b, W2b, F1w1b, F1w2b,
                                                         ow1b, ow2b, zAb, zGb);
    k_deg<<<(NE + 255)/256, 256, 0, stream>>>(dst, deg_i);
    k_scan<<<1, 1024, 0, stream>>>(deg_i, offsets, cursor);
    k_scatter<<<(NE + 255)/256, 256, 0, stream>>>(src, dst, cursor, src_by_pos, dst_by_pos);
    k_edge_e<<<(NE*SS + 255)/256, 256, 0, stream>>>(qdb, zGb, src_by_pos, dst_by_pos, e_csr);
    k_salpha<<<NN*SS, 64, 0, stream>>>(e_csr, offsets, alpha);

    // ---- time stepping ----
    k_xt0<<<(NN*SS*NIN + 255)/256, 256, 0, stream>>>(inputs, xt);
    for (int t = 0; t < 2; ++t) {
        k_xenc<<<(NN*SS*HH + 255)/256, 256, 0, stream>>>(xt, xw, xb, xtb);
        k_edge_mfma<<<2048, 256, 0, stream>>>(xtb, W1b, W2b, src_by_pos, dst_by_pos, dA);
        k_agg<<<NN*SS, 64, 0, stream>>>(dA, offsets, alpha, res_b);
        k_node_mfma<<<(NN*SS + 63)/64, 256, 0, stream>>>(res_b, zAb, F1w1b, F1w2b,
                                                         ow1b, ow2b, ob1, ob2, xt, out, t);
    }
}

// Round 9
// 342.529 us; speedup vs baseline: 1.4082x; 1.0547x over previous
//
#include <hip/hip_runtime.h>

#define NN 10000
#define NE 160000
#define TT 2
#define SS 2
#define HH 64
#define ZZ 32
#define KK 4
#define NIN 4

typedef short bf16x8 __attribute__((ext_vector_type(8)));
typedef float f32x4 __attribute__((ext_vector_type(4)));

// fp32 -> bf16 (RNE)
__device__ __forceinline__ unsigned short f2b(float x) {
    unsigned u = __float_as_uint(x);
    u += 0x7fffu + ((u >> 16) & 1u);
    return (unsigned short)(u >> 16);
}
__device__ __forceinline__ float bf2f(unsigned short u) {
    return __uint_as_float(((unsigned)u) << 16);
}

// A0: MT[k][j][i] = sum_h Ws[k,h,i] * Wd[k,h,j]   (TRANSPOSED store for k_qd coalescing)
__global__ void k_attnM(const float* __restrict__ Ws, const float* __restrict__ Wd,
                        float* __restrict__ MT) {
    int k = blockIdx.x >> 5;
    int i = blockIdx.x & 31;
    int j = threadIdx.x;
    float acc = 0.0f;
    for (int h = 0; h < HH; ++h)
        acc += Ws[(k*HH + h)*ZZ + i] * Wd[(k*HH + h)*ZZ + j];
    MT[(k*ZZ + j)*ZZ + i] = acc;
}

// A1: qd[n,s,k,i] (bf16) = sum_j MT[k][j][i] * zG[n,s,j]
// lane = i -> MT reads coalesced (consecutive i), zG reads lane-uniform.
__global__ void k_qd(const float* __restrict__ zG, const float* __restrict__ MT,
                     unsigned short* __restrict__ qdb) {
    int t = blockIdx.x * blockDim.x + threadIdx.x;
    if (t >= NN*SS*KK*ZZ) return;
    int i  = t & 31;
    int k  = (t >> 5) & 3;
    int ns = t >> 7;
    const float* zg = zG + ns*ZZ;
    const float* mt = MT + k*ZZ*ZZ;
    float acc = 0.0f;
#pragma unroll
    for (int j = 0; j < ZZ; ++j) acc += mt[j*ZZ + i] * zg[j];
    qdb[t] = f2b(acc);
}

// deg count
__global__ void k_deg(const int* __restrict__ dst, int* __restrict__ deg_i) {
    int e = blockIdx.x * blockDim.x + threadIdx.x;
    if (e < NE) atomicAdd(deg_i + dst[e], 1);
}

// C2: exclusive scan of deg_i -> offsets[0..NN], cursor copy (1 block, Hillis-Steele)
__global__ void k_scan(const int* __restrict__ deg_i, int* __restrict__ offsets,
                       int* __restrict__ cursor) {
    __shared__ int buf0[1024], buf1[1024];
    int tidx = threadIdx.x;
    const int CH = (NN + 1023) / 1024;   // 10
    int b0 = tidx * CH;
    int sum = 0;
    for (int i = 0; i < CH; ++i) { int idx = b0 + i; if (idx < NN) sum += deg_i[idx]; }
    buf0[tidx] = sum;
    __syncthreads();
    int* s = buf0; int* d = buf1;
    for (int off = 1; off < 1024; off <<= 1) {
        d[tidx] = s[tidx] + (tidx >= off ? s[tidx - off] : 0);
        __syncthreads();
        int* tmp = s; s = d; d = tmp;
    }
    int run = s[tidx] - sum;
    for (int i = 0; i < CH; ++i) {
        int idx = b0 + i;
        if (idx < NN) { offsets[idx] = run; cursor[idx] = run; run += deg_i[idx]; }
    }
    if (tidx == 0) offsets[NN] = NE;
}

// C3: scatter src/dst node ids into dst-sorted position order
__global__ void k_scatter(const int* __restrict__ src, const int* __restrict__ dst,
                          int* __restrict__ cursor, int* __restrict__ src_by_pos,
                          int* __restrict__ dst_by_pos) {
    int e = blockIdx.x * blockDim.x + threadIdx.x;
    if (e >= NE) return;
    int sn = src[e], dn = dst[e];
    int pos = atomicAdd(cursor + dn, 1);
    src_by_pos[pos] = sn;
    dst_by_pos[pos] = dn;
}

// A2: CSR-order scores; per-edge random side is zGb[src] (64B, L2-resident);
// qd[dst] reads shared by consecutive threads (same dst) -> L1 broadcast.
__global__ __launch_bounds__(256) void k_edge_e(
    const unsigned short* __restrict__ qdb, const unsigned short* __restrict__ zGb,
    const int* __restrict__ src_by_pos, const int* __restrict__ dst_by_pos,
    float* __restrict__ e_csr) {
    int t = blockIdx.x * blockDim.x + threadIdx.x;
    if (t >= NE*SS) return;
    int s = t & 1;
    int idx = t >> 1;
    int sn = src_by_pos[idx], dn = dst_by_pos[idx];
    const unsigned* zp = (const unsigned*)(zGb + (sn*SS + s)*ZZ);
    float zf[32];
#pragma unroll
    for (int j = 0; j < 16; ++j) {
        unsigned u = zp[j];
        zf[2*j]   = __uint_as_float(u << 16);
        zf[2*j+1] = __uint_as_float(u & 0xffff0000u);
    }
    const unsigned* qp = (const unsigned*)(qdb + (dn*SS + s)*KK*ZZ);
    float ev[4];
#pragma unroll
    for (int k = 0; k < 4; ++k) {
        float a = 0.f;
#pragma unroll
        for (int j = 0; j < 16; ++j) {
            unsigned u = qp[k*16 + j];
            a += __uint_as_float(u << 16) * zf[2*j]
               + __uint_as_float(u & 0xffff0000u) * zf[2*j+1];
        }
        ev[k] = a > 0.f ? a : 0.01f*a;
    }
    *(float4*)(e_csr + t*4) = *(float4*)ev;
}

// A3+A4 fused: per-(n,s) softmax stats in-wave, alpha written directly.
// alpha = exp(e - m) / (denom * deg)
__global__ __launch_bounds__(64) void k_salpha(
    const float* __restrict__ e_csr, const int* __restrict__ offsets,
    float* __restrict__ alpha) {
    int item = blockIdx.x;
    int n = item >> 1, s = item & 1;
    int l = threadIdx.x;
    int i = l >> 2, k = l & 3;
    int r0 = offsets[n], r1 = offsets[n+1];
    float mx = -1e30f;
    for (int idx = r0 + i; idx < r1; idx += 16)
        mx = fmaxf(mx, e_csr[(idx*2 + s)*4 + k]);
#pragma unroll
    for (int off = 4; off < 64; off <<= 1) mx = fmaxf(mx, __shfl_xor(mx, off));
    float sum = 0.f;
    for (int idx = r0 + i; idx < r1; idx += 16)
        sum += __expf(e_csr[(idx*2 + s)*4 + k] - mx);
#pragma unroll
    for (int off = 4; off < 64; off <<= 1) sum += __shfl_xor(sum, off);
    int deg = r1 - r0;
    float dd = (float)(deg > 1 ? deg : 1);
    float inv = sum > 0.f ? 1.f/(sum*dd) : 0.f;
    for (int idx = r0 + i; idx < r1; idx += 16)
        alpha[(idx*2 + s)*4 + k] = __expf(e_csr[(idx*2 + s)*4 + k] - mx) * inv;
}

// W0: convert all step-phase constants to bf16 (weights + zA + zG)
__global__ void k_conv_all(const float* __restrict__ F2w1, const float* __restrict__ F2w2,
                           const float* __restrict__ F1w1, const float* __restrict__ F1w2,
                           const float* __restrict__ ow1, const float* __restrict__ ow2,
                           const float* __restrict__ zA, const float* __restrict__ zG,
                           unsigned short* __restrict__ W1b, unsigned short* __restrict__ W2b,
                           unsigned short* __restrict__ F1w1b, unsigned short* __restrict__ F1w2b,
                           unsigned short* __restrict__ ow1b, unsigned short* __restrict__ ow2b,
                           unsigned short* __restrict__ zAb, unsigned short* __restrict__ zGb) {
    int t = blockIdx.x * blockDim.x + threadIdx.x;
    if (t < NN*SS*ZZ) { zAb[t] = f2b(zA[t]); zGb[t] = f2b(zG[t]); }
    if (t < HH*2*HH)  W1b[t] = f2b(F2w1[t]);
    if (t < HH*HH)    { W2b[t] = f2b(F2w2[t]); F1w2b[t] = f2b(F1w2[t]); }
    if (t < HH*KK*HH) F1w1b[t] = f2b(F1w1[t]);
    if (t < HH*(HH+ZZ)) ow1b[t] = f2b(ow1[t]);
    if (t < 4*HH)     ow2b[t] = f2b(ow2[t]);
}

// B0: xt[n,s,i] = inputs[n, 0, i]
__global__ void k_xt0(const float* __restrict__ inputs, float* __restrict__ xt) {
    int t = blockIdx.x * blockDim.x + threadIdx.x;
    if (t >= NN*SS*NIN) return;
    int i = t & 3;
    int n = t >> 3;
    xt[t] = inputs[n*(TT*NIN) + i];
}

// B1: xt_enc (bf16) = xt @ xenc_w.T + b
__global__ void k_xenc(const float* __restrict__ xt, const float* __restrict__ w,
                       const float* __restrict__ b, unsigned short* __restrict__ xtb) {
    int t = blockIdx.x * blockDim.x + threadIdx.x;
    if (t >= NN*SS*HH) return;
    int h  = t & 63;
    int ns = t >> 6;
    const float* x = xt + ns*NIN;
    float acc = b[h];
#pragma unroll
    for (int i = 0; i < NIN; ++i) acc += x[i] * w[h*NIN + i];
    xtb[t] = f2b(acc);
}

// B2: edge MLP MFMA GEMM, barrier-free direct-gather, persistent + 2-stage pipeline.
__global__ __launch_bounds__(256) void k_edge_mfma(
    const unsigned short* __restrict__ xtb, const unsigned short* __restrict__ W1b,
    const unsigned short* __restrict__ W2b, const int* __restrict__ src_by_pos,
    const int* __restrict__ dst_by_pos, unsigned short* __restrict__ dA)
{
    __shared__ unsigned short hid_s[4][16*72];
    const int NT = NE*SS/64;   // 5000 tiles
    int tid = threadIdx.x;
    int w = tid >> 6, l = tid & 63, l15 = l & 15, qq = l >> 4;
    int s = l15 & 1;
    int eslot = w*8 + (l15 >> 1);

    bf16x8 b1[4][4], b2[2][4];
#pragma unroll
    for (int nb = 0; nb < 4; ++nb) {
        int n = nb*16 + l15;
#pragma unroll
        for (int kb = 0; kb < 4; ++kb)
            b1[kb][nb] = *(const bf16x8*)(W1b + n*128 + kb*32 + qq*8);
#pragma unroll
        for (int kb = 0; kb < 2; ++kb)
            b2[kb][nb] = *(const bf16x8*)(W2b + n*64 + kb*32 + qq*8);
    }

    int G = gridDim.x;
    int t = blockIdx.x;
    if (t >= NT) return;

    int p0 = t*32 + eslot;
    int sn0 = src_by_pos[p0], dn0 = dst_by_pos[p0];
    const unsigned short* ps = xtb + (sn0*SS + s)*HH + qq*8;
    const unsigned short* pd = xtb + (dn0*SS + s)*HH + qq*8;
    bf16x8 a0 = *(const bf16x8*)(ps);
    bf16x8 a1 = *(const bf16x8*)(ps + 32);
    bf16x8 a2 = *(const bf16x8*)(pd);
    bf16x8 a3 = *(const bf16x8*)(pd + 32);
    int t1 = t + G;
    int tc1 = t1 < NT ? t1 : 0;
    int sn1 = src_by_pos[tc1*32 + eslot], dn1 = dst_by_pos[tc1*32 + eslot];

    for (; t < NT; t += G) {
        const unsigned short* ps1 = xtb + (sn1*SS + s)*HH + qq*8;
        const unsigned short* pd1 = xtb + (dn1*SS + s)*HH + qq*8;
        bf16x8 n0 = *(const bf16x8*)(ps1);
        bf16x8 n1 = *(const bf16x8*)(ps1 + 32);
        bf16x8 n2 = *(const bf16x8*)(pd1);
        bf16x8 n3 = *(const bf16x8*)(pd1 + 32);
        int t2 = t + 2*G;
        int tc2 = t2 < NT ? t2 : 0;
        int sn2 = src_by_pos[tc2*32 + eslot], dn2 = dst_by_pos[tc2*32 + eslot];

        f32x4 acc[4];
#pragma unroll
        for (int nb = 0; nb < 4; ++nb) acc[nb] = (f32x4)(0.0f);
#pragma unroll
        for (int nb = 0; nb < 4; ++nb) {
            acc[nb] = __builtin_amdgcn_mfma_f32_16x16x32_bf16(a0, b1[0][nb], acc[nb], 0, 0, 0);
            acc[nb] = __builtin_amdgcn_mfma_f32_16x16x32_bf16(a1, b1[1][nb], acc[nb], 0, 0, 0);
            acc[nb] = __builtin_amdgcn_mfma_f32_16x16x32_bf16(a2, b1[2][nb], acc[nb], 0, 0, 0);
            acc[nb] = __builtin_amdgcn_mfma_f32_16x16x32_bf16(a3, b1[3][nb], acc[nb], 0, 0, 0);
        }
        unsigned short* hw = hid_s[w];
#pragma unroll
        for (int nb = 0; nb < 4; ++nb)
#pragma unroll
            for (int r = 0; r < 4; ++r) {
                float v = acc[nb][r];
                hw[(qq*4 + r)*72 + nb*16 + l15] = f2b(v > 0.0f ? v : 0.0f);
            }
        f32x4 acc2[4];
#pragma unroll
        for (int nb = 0; nb < 4; ++nb) acc2[nb] = (f32x4)(0.0f);
        const unsigned short* a2row = hw + l15*72 + qq*8;
#pragma unroll
        for (int kb = 0; kb < 2; ++kb) {
            bf16x8 af = *(const bf16x8*)(a2row + kb*32);
#pragma unroll
            for (int nb = 0; nb < 4; ++nb)
                acc2[nb] = __builtin_amdgcn_mfma_f32_16x16x32_bf16(af, b2[kb][nb], acc2[nb], 0, 0, 0);
        }
        unsigned short* drow = dA + (t*64 + w*16)*64;
#pragma unroll
        for (int nb = 0; nb < 4; ++nb)
#pragma unroll
            for (int r = 0; r < 4; ++r)
                drow[(qq*4 + r)*64 + nb*16 + l15] = f2b(acc2[nb][r]);

        a0 = n0; a1 = n1; a2 = n2; a3 = n3;
        sn1 = sn2; dn1 = dn2;
    }
}

// B2b: aggregation per (n,s): pure stream of alpha (broadcast) + dA rows
__global__ __launch_bounds__(64) void k_agg(
    const unsigned short* __restrict__ dA, const int* __restrict__ offsets,
    const float* __restrict__ alpha, unsigned short* __restrict__ res_b)
{
    int item = blockIdx.x;
    int n = item >> 1, s = item & 1;
    int h = threadIdx.x;
    int r0 = offsets[n], r1 = offsets[n+1];
    float a0 = 0.f, a1 = 0.f, a2 = 0.f, a3 = 0.f;
    for (int idx = r0; idx < r1; ++idx) {
        int row = idx*2 + s;
        const float4 w4 = *(const float4*)(alpha + row*4);
        unsigned short uv = dA[row*64 + h];
        float v = bf2f(uv);
        a0 += w4.x*v; a1 += w4.y*v; a2 += w4.z*v; a3 += w4.w*v;
    }
    res_b[item*256 +       h] = f2b(a0);
    res_b[item*256 + 64  + h] = f2b(a1);
    res_b[item*256 + 128 + h] = f2b(a2);
    res_b[item*256 + 192 + h] = f2b(a3);
}

// B3: node update as chained bf16 MFMA GEMMs. 4 waves/block, 16 items/wave.
// All weights stream from global (L2-hot). LDS = per-wave scratch only (22.5 KB),
// no __syncthreads -> higher occupancy than LDS-staged variant.
__global__ __launch_bounds__(256) void k_node_mfma(
    const unsigned short* __restrict__ res_b, const unsigned short* __restrict__ zAb,
    const unsigned short* __restrict__ F1w1b, const unsigned short* __restrict__ F1w2b,
    const unsigned short* __restrict__ ow1b, const unsigned short* __restrict__ ow2b,
    const float* __restrict__ ob1, const float* __restrict__ ob2,
    float* __restrict__ xt, float* __restrict__ out, int tstep)
{
    __shared__ unsigned short hid_s[4][16*72];
    __shared__ unsigned short hcat_s[4][16*104];
    int tid = threadIdx.x;
    int w = tid >> 6, l = tid & 63, l15 = l & 15, qq = l >> 4;

    bf16x8 b2f[2][4], o1f[3][4], bo2[2];
#pragma unroll
    for (int nb = 0; nb < 4; ++nb) {
        int n = nb*16 + l15;
#pragma unroll
        for (int kb = 0; kb < 2; ++kb)
            b2f[kb][nb] = *(const bf16x8*)(F1w2b + n*64 + kb*32 + qq*8);
#pragma unroll
        for (int kb = 0; kb < 3; ++kb)
            o1f[kb][nb] = *(const bf16x8*)(ow1b + n*96 + kb*32 + qq*8);
    }
#pragma unroll
    for (int kb = 0; kb < 2; ++kb) {
        if (l15 < 4) bo2[kb] = *(const bf16x8*)(ow2b + l15*64 + kb*32 + qq*8);
        else {
            bf16x8 z;
#pragma unroll
            for (int j = 0; j < 8; ++j) z[j] = 0;
            bo2[kb] = z;
        }
    }
    float b1v[4];
#pragma unroll
    for (int nb = 0; nb < 4; ++nb) b1v[nb] = ob1[nb*16 + l15];
    float b2v = (l15 < 4) ? ob2[l15] : 0.0f;

    int itemBase = blockIdx.x*64 + w*16;
    if (itemBase >= NN*SS) return;

    *(uint4*)(&hcat_s[w][l15*104 + 64 + qq*8]) =
        *(const uint4*)(zAb + (itemBase + l15)*ZZ + qq*8);

    // ---- GEMM1: res[16x256] @ F1w1^T[256x64], relu (B streamed from global) ----
    f32x4 acc[4];
#pragma unroll
    for (int nb = 0; nb < 4; ++nb) acc[nb] = (f32x4)(0.0f);
#pragma unroll
    for (int kb = 0; kb < 8; ++kb) {
        bf16x8 af = *(const bf16x8*)(res_b + (itemBase + l15)*256 + kb*32 + qq*8);
#pragma unroll
        for (int nb = 0; nb < 4; ++nb) {
            bf16x8 bf = *(const bf16x8*)(F1w1b + (nb*16 + l15)*256 + kb*32 + qq*8);
            acc[nb] = __builtin_amdgcn_mfma_f32_16x16x32_bf16(af, bf, acc[nb], 0, 0, 0);
        }
    }
#pragma unroll
    for (int nb = 0; nb < 4; ++nb)
#pragma unroll
        for (int r = 0; r < 4; ++r) {
            float v = acc[nb][r];
            hid_s[w][(qq*4 + r)*72 + nb*16 + l15] = f2b(v > 0.0f ? v : 0.0f);
        }

    // ---- GEMM2: hid[16x64] @ F1w2^T[64x64] -> deltax -> hcat cols 0..63 ----
    f32x4 acc2[4];
#pragma unroll
    for (int nb = 0; nb < 4; ++nb) acc2[nb] = (f32x4)(0.0f);
#pragma unroll
    for (int kb = 0; kb < 2; ++kb) {
        bf16x8 af = *(const bf16x8*)(&hid_s[w][l15*72 + kb*32 + qq*8]);
#pragma unroll
        for (int nb = 0; nb < 4; ++nb)
            acc2[nb] = __builtin_amdgcn_mfma_f32_16x16x32_bf16(af, b2f[kb][nb], acc2[nb], 0, 0, 0);
    }
#pragma unroll
    for (int nb = 0; nb < 4; ++nb)
#pragma unroll
        for (int r = 0; r < 4; ++r)
            hcat_s[w][(qq*4 + r)*104 + nb*16 + l15] = f2b(acc2[nb][r]);

    // ---- GEMM3: hcat[16x96] @ ow1^T[96x64] + b1, relu -> hid_s ----
    f32x4 acc3[4];
#pragma unroll
    for (int nb = 0; nb < 4; ++nb) acc3[nb] = (f32x4)(0.0f);
#pragma unroll
    for (int kb = 0; kb < 3; ++kb) {
        bf16x8 af = *(const bf16x8*)(&hcat_s[w][l15*104 + kb*32 + qq*8]);
#pragma unroll
        for (int nb = 0; nb < 4; ++nb)
            acc3[nb] = __builtin_amdgcn_mfma_f32_16x16x32_bf16(af, o1f[kb][nb], acc3[nb], 0, 0, 0);
    }
#pragma unroll
    for (int nb = 0; nb < 4; ++nb)
#pragma unroll
        for (int r = 0; r < 4; ++r) {
            float v = acc3[nb][r] + b1v[nb];
            hid_s[w][(qq*4 + r)*72 + nb*16 + l15] = f2b(v > 0.0f ? v : 0.0f);
        }

    // ---- GEMM4: hid[16x64] @ ow2^T[64x4(pad16)] + b2 ----
    f32x4 acc4 = (f32x4)(0.0f);
#pragma unroll
    for (int kb = 0; kb < 2; ++kb) {
        bf16x8 af = *(const bf16x8*)(&hid_s[w][l15*72 + kb*32 + qq*8]);
        acc4 = __builtin_amdgcn_mfma_f32_16x16x32_bf16(af, bo2[kb], acc4, 0, 0, 0);
    }
    if (l15 < 4) {
#pragma unroll
        for (int r = 0; r < 4; ++r) {
            int item = itemBase + qq*4 + r;
            float nx = xt[item*4 + l15] + acc4[r] + b2v;
            xt[item*4 + l15] = nx;
            int n = item >> 1, s = item & 1;
            out[((n*TT + tstep)*SS + s)*4 + l15] = nx;
        }
    }
}

extern "C" void kernel_launch(void* const* d_in, const int* in_sizes, int n_in,
                              void* d_out, int out_size, void* d_ws, size_t ws_size,
                              hipStream_t stream) {
    const float* inputs = (const float*)d_in[0];
    const float* zA     = (const float*)d_in[1];
    const float* zG     = (const float*)d_in[2];
    const int*   src    = (const int*)d_in[3];
    const int*   dst    = (const int*)d_in[4];
    const float* Ws     = (const float*)d_in[5];
    const float* Wd     = (const float*)d_in[6];
    const float* F2w1   = (const float*)d_in[7];
    const float* F2w2   = (const float*)d_in[8];
    const float* F1w1   = (const float*)d_in[9];
    const float* F1w2   = (const float*)d_in[10];
    const float* xw     = (const float*)d_in[11];
    const float* xb     = (const float*)d_in[12];
    const float* ow1    = (const float*)d_in[13];
    const float* ob1    = (const float*)d_in[14];
    const float* ow2    = (const float*)d_in[15];
    const float* ob2    = (const float*)d_in[16];
    float* out = (float*)d_out;

    // ---- workspace carve (units: floats) ----
    float*          base        = (float*)d_ws;
    float*          MT          = base;                              // 4,096
    float*          e_csr       = base + 4096;                       // 1,280,000
    float*          alpha       = base + 1284096;                    // 1,280,000
    int*            deg_i       = (int*)(base + 2564096);            // 10,000 (zeroed)
    int*            offsets     = (int*)(base + 2574096);            // 10,016
    int*            cursor      = (int*)(base + 2584112);            // 10,000
    int*            src_by_pos  = (int*)(base + 2594112);            // 160,000
    int*            dst_by_pos  = (int*)(base + 2754112);            // 160,000
    float*          xt          = base + 2914112;                    // 80,000
    unsigned short* xtb         = (unsigned short*)(base + 2994112); // 1,280,000 ush
    unsigned short* W1b         = (unsigned short*)(base + 3634112); // 8,192 ush
    unsigned short* W2b         = (unsigned short*)(base + 3638208); // 4,096 ush
    unsigned short* F1w1b       = (unsigned short*)(base + 3640256); // 16,384 ush
    unsigned short* F1w2b       = (unsigned short*)(base + 3648448); // 4,096 ush
    unsigned short* ow1b        = (unsigned short*)(base + 3650496); // 6,144 ush
    unsigned short* ow2b        = (unsigned short*)(base + 3653568); // 256 ush
    unsigned short* zAb         = (unsigned short*)(base + 3653696); // 640,000 ush
    unsigned short* zGb         = (unsigned short*)(base + 3973696); // 640,000 ush
    unsigned short* res_b       = (unsigned short*)(base + 4293696); // 5,120,000 ush
    // phase union @ 6,853,696: qdb (2.56M ush, attention) / dA (20.48M ush, steps)
    unsigned short* qdb         = (unsigned short*)(base + 6853696);
    unsigned short* dA          = (unsigned short*)(base + 6853696);
    // total 17,093,696 floats = 68.4 MB

    hipMemsetAsync(deg_i, 0, 10000u * 4u, stream);

    // ---- attention phase (once) ----
    k_attnM<<<KK*ZZ, ZZ, 0, stream>>>(Ws, Wd, MT);
    k_qd<<<(NN*SS*KK*ZZ + 255)/256, 256, 0, stream>>>(zG, MT, qdb);
    k_conv_all<<<(NN*SS*ZZ + 255)/256, 256, 0, stream>>>(F2w1, F2w2, F1w1, F1w2, ow1, ow2,
                                                         zA, zG, W1b, W2b, F1w1b, F1w2b,
                                                         ow1b, ow2b, zAb, zGb);
    k_deg<<<(NE + 255)/256, 256, 0, stream>>>(dst, deg_i);
    k_scan<<<1, 1024, 0, stream>>>(deg_i, offsets, cursor);
    k_scatter<<<(NE + 255)/256, 256, 0, stream>>>(src, dst, cursor, src_by_pos, dst_by_pos);
    k_edge_e<<<(NE*SS + 255)/256, 256, 0, stream>>>(qdb, zGb, src_by_pos, dst_by_pos, e_csr);
    k_salpha<<<NN*SS, 64, 0, stream>>>(e_csr, offsets, alpha);

    // ---- time stepping ----
    k_xt0<<<(NN*SS*NIN + 255)/256, 256, 0, stream>>>(inputs, xt);
    for (int t = 0; t < 2; ++t) {
        k_xenc<<<(NN*SS*HH + 255)/256, 256, 0, stream>>>(xt, xw, xb, xtb);
        k_edge_mfma<<<2048, 256, 0, stream>>>(xtb, W1b, W2b, src_by_pos, dst_by_pos, dA);
        k_agg<<<NN*SS, 64, 0, stream>>>(dA, offsets, alpha, res_b);
        k_node_mfma<<<(NN*SS + 63)/64, 256, 0, stream>>>(res_b, zAb, F1w1b, F1w2b,
                                                         ow1b, ow2b, ob1, ob2, xt, out, t);
    }
}

// Round 10
// 311.452 us; speedup vs baseline: 1.5488x; 1.0998x over previous
//
#include <hip/hip_runtime.h>

#define NN 10000
#define NE 160000
#define TT 2
#define SS 2
#define HH 64
#define ZZ 32
#define KK 4
#define NIN 4

typedef short bf16x8 __attribute__((ext_vector_type(8)));
typedef float f32x4 __attribute__((ext_vector_type(4)));

// fp32 -> bf16 (RNE)
__device__ __forceinline__ unsigned short f2b(float x) {
    unsigned u = __float_as_uint(x);
    u += 0x7fffu + ((u >> 16) & 1u);
    return (unsigned short)(u >> 16);
}
__device__ __forceinline__ float bf2f(unsigned short u) {
    return __uint_as_float(((unsigned)u) << 16);
}
// elementwise relu(a+b) on bf16x8
__device__ __forceinline__ bf16x8 addrelu8(bf16x8 a, bf16x8 b) {
    bf16x8 r;
#pragma unroll
    for (int j = 0; j < 8; ++j) {
        float v = bf2f((unsigned short)a[j]) + bf2f((unsigned short)b[j]);
        r[j] = (short)f2b(v > 0.0f ? v : 0.0f);
    }
    return r;
}

// A0: MT[k][j][i] = sum_h Ws[k,h,i] * Wd[k,h,j]   (TRANSPOSED store for k_qd coalescing)
__global__ void k_attnM(const float* __restrict__ Ws, const float* __restrict__ Wd,
                        float* __restrict__ MT) {
    int k = blockIdx.x >> 5;
    int i = blockIdx.x & 31;
    int j = threadIdx.x;
    float acc = 0.0f;
    for (int h = 0; h < HH; ++h)
        acc += Ws[(k*HH + h)*ZZ + i] * Wd[(k*HH + h)*ZZ + j];
    MT[(k*ZZ + j)*ZZ + i] = acc;
}

// A1: qd[n,s,k,i] (bf16) = sum_j MT[k][j][i] * zG[n,s,j]  (coalesced over i)
__global__ void k_qd(const float* __restrict__ zG, const float* __restrict__ MT,
                     unsigned short* __restrict__ qdb) {
    int t = blockIdx.x * blockDim.x + threadIdx.x;
    if (t >= NN*SS*KK*ZZ) return;
    int i  = t & 31;
    int k  = (t >> 5) & 3;
    int ns = t >> 7;
    const float* zg = zG + ns*ZZ;
    const float* mt = MT + k*ZZ*ZZ;
    float acc = 0.0f;
#pragma unroll
    for (int j = 0; j < ZZ; ++j) acc += mt[j*ZZ + i] * zg[j];
    qdb[t] = f2b(acc);
}

// Fold xenc into F2w1 halves: G1 = W1a@xw, G2 = W1b@xw, c1 = W1a@xb, c2 = W1b@xb
// (1 block x 256)
__global__ void k_fold(const float* __restrict__ F2w1, const float* __restrict__ xw,
                       const float* __restrict__ xb,
                       float* __restrict__ G1, float* __restrict__ G2,
                       float* __restrict__ c1, float* __restrict__ c2) {
    int t = threadIdx.x;
    int h = t >> 2, i = t & 3;
    float a1 = 0.f, a2 = 0.f;
    for (int j = 0; j < HH; ++j) {
        float x = xw[j*NIN + i];
        a1 += F2w1[h*128 + j] * x;
        a2 += F2w1[h*128 + 64 + j] * x;
    }
    G1[h*4 + i] = a1;
    G2[h*4 + i] = a2;
    if (i == 0) {
        float b1 = 0.f, b2 = 0.f;
        for (int j = 0; j < HH; ++j) {
            float bb = xb[j];
            b1 += F2w1[h*128 + j] * bb;
            b2 += F2w1[h*128 + 64 + j] * bb;
        }
        c1[h] = b1; c2[h] = b2;
    }
}

// deg count
__global__ void k_deg(const int* __restrict__ dst, int* __restrict__ deg_i) {
    int e = blockIdx.x * blockDim.x + threadIdx.x;
    if (e < NE) atomicAdd(deg_i + dst[e], 1);
}

// C2: exclusive scan of deg_i -> offsets[0..NN], cursor copy (1 block, Hillis-Steele)
__global__ void k_scan(const int* __restrict__ deg_i, int* __restrict__ offsets,
                       int* __restrict__ cursor) {
    __shared__ int buf0[1024], buf1[1024];
    int tidx = threadIdx.x;
    const int CH = (NN + 1023) / 1024;   // 10
    int b0 = tidx * CH;
    int sum = 0;
    for (int i = 0; i < CH; ++i) { int idx = b0 + i; if (idx < NN) sum += deg_i[idx]; }
    buf0[tidx] = sum;
    __syncthreads();
    int* s = buf0; int* d = buf1;
    for (int off = 1; off < 1024; off <<= 1) {
        d[tidx] = s[tidx] + (tidx >= off ? s[tidx - off] : 0);
        __syncthreads();
        int* tmp = s; s = d; d = tmp;
    }
    int run = s[tidx] - sum;
    for (int i = 0; i < CH; ++i) {
        int idx = b0 + i;
        if (idx < NN) { offsets[idx] = run; cursor[idx] = run; run += deg_i[idx]; }
    }
    if (tidx == 0) offsets[NN] = NE;
}

// C3: scatter src/dst node ids into dst-sorted position order
__global__ void k_scatter(const int* __restrict__ src, const int* __restrict__ dst,
                          int* __restrict__ cursor, int* __restrict__ src_by_pos,
                          int* __restrict__ dst_by_pos) {
    int e = blockIdx.x * blockDim.x + threadIdx.x;
    if (e >= NE) return;
    int sn = src[e], dn = dst[e];
    int pos = atomicAdd(cursor + dn, 1);
    src_by_pos[pos] = sn;
    dst_by_pos[pos] = dn;
}

// A2: CSR-order scores; per-edge random side is zGb[src] (64B, L2-resident)
__global__ __launch_bounds__(256) void k_edge_e(
    const unsigned short* __restrict__ qdb, const unsigned short* __restrict__ zGb,
    const int* __restrict__ src_by_pos, const int* __restrict__ dst_by_pos,
    float* __restrict__ e_csr) {
    int t = blockIdx.x * blockDim.x + threadIdx.x;
    if (t >= NE*SS) return;
    int s = t & 1;
    int idx = t >> 1;
    int sn = src_by_pos[idx], dn = dst_by_pos[idx];
    const unsigned* zp = (const unsigned*)(zGb + (sn*SS + s)*ZZ);
    float zf[32];
#pragma unroll
    for (int j = 0; j < 16; ++j) {
        unsigned u = zp[j];
        zf[2*j]   = __uint_as_float(u << 16);
        zf[2*j+1] = __uint_as_float(u & 0xffff0000u);
    }
    const unsigned* qp = (const unsigned*)(qdb + (dn*SS + s)*KK*ZZ);
    float ev[4];
#pragma unroll
    for (int k = 0; k < 4; ++k) {
        float a = 0.f;
#pragma unroll
        for (int j = 0; j < 16; ++j) {
            unsigned u = qp[k*16 + j];
            a += __uint_as_float(u << 16) * zf[2*j]
               + __uint_as_float(u & 0xffff0000u) * zf[2*j+1];
        }
        ev[k] = a > 0.f ? a : 0.01f*a;
    }
    *(float4*)(e_csr + t*4) = *(float4*)ev;
}

// A3+A4 fused: per-(n,s) softmax stats in-wave, alpha written directly.
__global__ __launch_bounds__(64) void k_salpha(
    const float* __restrict__ e_csr, const int* __restrict__ offsets,
    float* __restrict__ alpha) {
    int item = blockIdx.x;
    int n = item >> 1, s = item & 1;
    int l = threadIdx.x;
    int i = l >> 2, k = l & 3;
    int r0 = offsets[n], r1 = offsets[n+1];
    float mx = -1e30f;
    for (int idx = r0 + i; idx < r1; idx += 16)
        mx = fmaxf(mx, e_csr[(idx*2 + s)*4 + k]);
#pragma unroll
    for (int off = 4; off < 64; off <<= 1) mx = fmaxf(mx, __shfl_xor(mx, off));
    float sum = 0.f;
    for (int idx = r0 + i; idx < r1; idx += 16)
        sum += __expf(e_csr[(idx*2 + s)*4 + k] - mx);
#pragma unroll
    for (int off = 4; off < 64; off <<= 1) sum += __shfl_xor(sum, off);
    int deg = r1 - r0;
    float dd = (float)(deg > 1 ? deg : 1);
    float inv = sum > 0.f ? 1.f/(sum*dd) : 0.f;
    for (int idx = r0 + i; idx < r1; idx += 16)
        alpha[(idx*2 + s)*4 + k] = __expf(e_csr[(idx*2 + s)*4 + k] - mx) * inv;
}

// W0: convert step-phase constants to bf16 (weights + zA + zG); W1 no longer needed
__global__ void k_conv_all(const float* __restrict__ F2w2,
                           const float* __restrict__ F1w1, const float* __restrict__ F1w2,
                           const float* __restrict__ ow1, const float* __restrict__ ow2,
                           const float* __restrict__ zA, const float* __restrict__ zG,
                           unsigned short* __restrict__ W2b,
                           unsigned short* __restrict__ F1w1b, unsigned short* __restrict__ F1w2b,
                           unsigned short* __restrict__ ow1b, unsigned short* __restrict__ ow2b,
                           unsigned short* __restrict__ zAb, unsigned short* __restrict__ zGb) {
    int t = blockIdx.x * blockDim.x + threadIdx.x;
    if (t < NN*SS*ZZ) { zAb[t] = f2b(zA[t]); zGb[t] = f2b(zG[t]); }
    if (t < HH*HH)    { W2b[t] = f2b(F2w2[t]); F1w2b[t] = f2b(F1w2[t]); }
    if (t < HH*KK*HH) F1w1b[t] = f2b(F1w1[t]);
    if (t < HH*(HH+ZZ)) ow1b[t] = f2b(ow1[t]);
    if (t < 4*HH)     ow2b[t] = f2b(ow2[t]);
}

// B0: xt[n,s,i] = inputs[n, 0, i]
__global__ void k_xt0(const float* __restrict__ inputs, float* __restrict__ xt) {
    int t = blockIdx.x * blockDim.x + threadIdx.x;
    if (t >= NN*SS*NIN) return;
    int i = t & 3;
    int n = t >> 3;
    xt[t] = inputs[n*(TT*NIN) + i];
}

// B1 v2: P1[ns,h] = xt[ns]@G1^T + c1, P2 = xt@G2^T + c2  (xenc folded into W1 halves)
__global__ void k_xenc2(const float* __restrict__ xt, const float* __restrict__ G1,
                        const float* __restrict__ G2, const float* __restrict__ c1,
                        const float* __restrict__ c2,
                        unsigned short* __restrict__ P1b, unsigned short* __restrict__ P2b) {
    int t = blockIdx.x * blockDim.x + threadIdx.x;
    if (t >= NN*SS*HH) return;
    int h  = t & 63;
    int ns = t >> 6;
    const float* x = xt + ns*NIN;
    float p1 = c1[h], p2 = c2[h];
#pragma unroll
    for (int i = 0; i < NIN; ++i) {
        p1 += x[i] * G1[h*NIN + i];
        p2 += x[i] * G2[h*NIN + i];
    }
    P1b[t] = f2b(p1);
    P2b[t] = f2b(p2);
}

// B2 v3: edge MLP second layer only. hidden = relu(P1[src]+P2[dst]) gathered
// directly in A-layout; GEMM2 [16x64]@[64x64]; no LDS at all.
__global__ __launch_bounds__(256) void k_edge_mfma(
    const unsigned short* __restrict__ P1b, const unsigned short* __restrict__ P2b,
    const unsigned short* __restrict__ W2b, const int* __restrict__ src_by_pos,
    const int* __restrict__ dst_by_pos, unsigned short* __restrict__ dA)
{
    const int NT = NE*SS/64;   // 5000 tiles
    int tid = threadIdx.x;
    int w = tid >> 6, l = tid & 63, l15 = l & 15, qq = l >> 4;
    int s = l15 & 1;
    int eslot = w*8 + (l15 >> 1);

    // W2 B-fragments, loaded once per block
    bf16x8 b2[2][4];
#pragma unroll
    for (int nb = 0; nb < 4; ++nb) {
        int n = nb*16 + l15;
#pragma unroll
        for (int kb = 0; kb < 2; ++kb)
            b2[kb][nb] = *(const bf16x8*)(W2b + n*64 + kb*32 + qq*8);
    }

    int G = gridDim.x;
    int t = blockIdx.x;
    if (t >= NT) return;

    // prologue: ids(t) -> raw frags(t); ids(t+G)
    int p0 = t*32 + eslot;
    int sn0 = src_by_pos[p0], dn0 = dst_by_pos[p0];
    const unsigned short* ps = P1b + (sn0*SS + s)*HH + qq*8;
    const unsigned short* pd = P2b + (dn0*SS + s)*HH + qq*8;
    bf16x8 r0 = *(const bf16x8*)(ps);
    bf16x8 r1 = *(const bf16x8*)(ps + 32);
    bf16x8 r2 = *(const bf16x8*)(pd);
    bf16x8 r3 = *(const bf16x8*)(pd + 32);
    int t1 = t + G;
    int tc1 = t1 < NT ? t1 : 0;
    int sn1 = src_by_pos[tc1*32 + eslot], dn1 = dst_by_pos[tc1*32 + eslot];

    for (; t < NT; t += G) {
        // issue next tile's raw gathers
        const unsigned short* ps1 = P1b + (sn1*SS + s)*HH + qq*8;
        const unsigned short* pd1 = P2b + (dn1*SS + s)*HH + qq*8;
        bf16x8 n0 = *(const bf16x8*)(ps1);
        bf16x8 n1 = *(const bf16x8*)(ps1 + 32);
        bf16x8 n2 = *(const bf16x8*)(pd1);
        bf16x8 n3 = *(const bf16x8*)(pd1 + 32);
        // ids for t+2G
        int t2 = t + 2*G;
        int tc2 = t2 < NT ? t2 : 0;
        int sn2 = src_by_pos[tc2*32 + eslot], dn2 = dst_by_pos[tc2*32 + eslot];

        // hidden A-frags: relu(P1[src]+P2[dst])
        bf16x8 af0 = addrelu8(r0, r2);   // k = 0..31 chunk (qq*8)
        bf16x8 af1 = addrelu8(r1, r3);   // k = 32..63 chunk

        // GEMM2: [16x64] @ [64x64]
        f32x4 acc[4];
#pragma unroll
        for (int nb = 0; nb < 4; ++nb) acc[nb] = (f32x4)(0.0f);
#pragma unroll
        for (int nb = 0; nb < 4; ++nb) {
            acc[nb] = __builtin_amdgcn_mfma_f32_16x16x32_bf16(af0, b2[0][nb], acc[nb], 0, 0, 0);
            acc[nb] = __builtin_amdgcn_mfma_f32_16x16x32_bf16(af1, b2[1][nb], acc[nb], 0, 0, 0);
        }

        // write dA (C-layout rows)
        unsigned short* drow = dA + (t*64 + w*16)*64;
#pragma unroll
        for (int nb = 0; nb < 4; ++nb)
#pragma unroll
            for (int r = 0; r < 4; ++r)
                drow[(qq*4 + r)*64 + nb*16 + l15] = f2b(acc[nb][r]);

        // pipeline shift
        r0 = n0; r1 = n1; r2 = n2; r3 = n3;
        sn1 = sn2; dn1 = dn2;
    }
}

// B2b: aggregation per (n,s): pure stream of alpha (broadcast) + dA rows
__global__ __launch_bounds__(64) void k_agg(
    const unsigned short* __restrict__ dA, const int* __restrict__ offsets,
    const float* __restrict__ alpha, unsigned short* __restrict__ res_b)
{
    int item = blockIdx.x;
    int n = item >> 1, s = item & 1;
    int h = threadIdx.x;
    int r0 = offsets[n], r1 = offsets[n+1];
    float a0 = 0.f, a1 = 0.f, a2 = 0.f, a3 = 0.f;
    for (int idx = r0; idx < r1; ++idx) {
        int row = idx*2 + s;
        const float4 w4 = *(const float4*)(alpha + row*4);
        float v = bf2f(dA[row*64 + h]);
        a0 += w4.x*v; a1 += w4.y*v; a2 += w4.z*v; a3 += w4.w*v;
    }
    res_b[item*256 +       h] = f2b(a0);
    res_b[item*256 + 64  + h] = f2b(a1);
    res_b[item*256 + 128 + h] = f2b(a2);
    res_b[item*256 + 192 + h] = f2b(a3);
}

// B3: node update as chained bf16 MFMA GEMMs. 4 waves/block, 16 items/wave.
__global__ __launch_bounds__(256) void k_node_mfma(
    const unsigned short* __restrict__ res_b, const unsigned short* __restrict__ zAb,
    const unsigned short* __restrict__ F1w1b, const unsigned short* __restrict__ F1w2b,
    const unsigned short* __restrict__ ow1b, const unsigned short* __restrict__ ow2b,
    const float* __restrict__ ob1, const float* __restrict__ ob2,
    float* __restrict__ xt, float* __restrict__ out, int tstep)
{
    __shared__ unsigned short hid_s[4][16*72];
    __shared__ unsigned short hcat_s[4][16*104];
    int tid = threadIdx.x;
    int w = tid >> 6, l = tid & 63, l15 = l & 15, qq = l >> 4;

    bf16x8 b2f[2][4], o1f[3][4], bo2[2];
#pragma unroll
    for (int nb = 0; nb < 4; ++nb) {
        int n = nb*16 + l15;
#pragma unroll
        for (int kb = 0; kb < 2; ++kb)
            b2f[kb][nb] = *(const bf16x8*)(F1w2b + n*64 + kb*32 + qq*8);
#pragma unroll
        for (int kb = 0; kb < 3; ++kb)
            o1f[kb][nb] = *(const bf16x8*)(ow1b + n*96 + kb*32 + qq*8);
    }
#pragma unroll
    for (int kb = 0; kb < 2; ++kb) {
        if (l15 < 4) bo2[kb] = *(const bf16x8*)(ow2b + l15*64 + kb*32 + qq*8);
        else {
            bf16x8 z;
#pragma unroll
            for (int j = 0; j < 8; ++j) z[j] = 0;
            bo2[kb] = z;
        }
    }
    float b1v[4];
#pragma unroll
    for (int nb = 0; nb < 4; ++nb) b1v[nb] = ob1[nb*16 + l15];
    float b2v = (l15 < 4) ? ob2[l15] : 0.0f;

    int itemBase = blockIdx.x*64 + w*16;
    if (itemBase >= NN*SS) return;

    *(uint4*)(&hcat_s[w][l15*104 + 64 + qq*8]) =
        *(const uint4*)(zAb + (itemBase + l15)*ZZ + qq*8);

    // GEMM1: res[16x256] @ F1w1^T[256x64], relu (B streamed from global)
    f32x4 acc[4];
#pragma unroll
    for (int nb = 0; nb < 4; ++nb) acc[nb] = (f32x4)(0.0f);
#pragma unroll
    for (int kb = 0; kb < 8; ++kb) {
        bf16x8 af = *(const bf16x8*)(res_b + (itemBase + l15)*256 + kb*32 + qq*8);
#pragma unroll
        for (int nb = 0; nb < 4; ++nb) {
            bf16x8 bf = *(const bf16x8*)(F1w1b + (nb*16 + l15)*256 + kb*32 + qq*8);
            acc[nb] = __builtin_amdgcn_mfma_f32_16x16x32_bf16(af, bf, acc[nb], 0, 0, 0);
        }
    }
#pragma unroll
    for (int nb = 0; nb < 4; ++nb)
#pragma unroll
        for (int r = 0; r < 4; ++r) {
            float v = acc[nb][r];
            hid_s[w][(qq*4 + r)*72 + nb*16 + l15] = f2b(v > 0.0f ? v : 0.0f);
        }

    // GEMM2: hid[16x64] @ F1w2^T[64x64] -> deltax -> hcat cols 0..63
    f32x4 acc2[4];
#pragma unroll
    for (int nb = 0; nb < 4; ++nb) acc2[nb] = (f32x4)(0.0f);
#pragma unroll
    for (int kb = 0; kb < 2; ++kb) {
        bf16x8 af = *(const bf16x8*)(&hid_s[w][l15*72 + kb*32 + qq*8]);
#pragma unroll
        for (int nb = 0; nb < 4; ++nb)
            acc2[nb] = __builtin_amdgcn_mfma_f32_16x16x32_bf16(af, b2f[kb][nb], acc2[nb], 0, 0, 0);
    }
#pragma unroll
    for (int nb = 0; nb < 4; ++nb)
#pragma unroll
        for (int r = 0; r < 4; ++r)
            hcat_s[w][(qq*4 + r)*104 + nb*16 + l15] = f2b(acc2[nb][r]);

    // GEMM3: hcat[16x96] @ ow1^T[96x64] + b1, relu -> hid_s
    f32x4 acc3[4];
#pragma unroll
    for (int nb = 0; nb < 4; ++nb) acc3[nb] = (f32x4)(0.0f);
#pragma unroll
    for (int kb = 0; kb < 3; ++kb) {
        bf16x8 af = *(const bf16x8*)(&hcat_s[w][l15*104 + kb*32 + qq*8]);
#pragma unroll
        for (int nb = 0; nb < 4; ++nb)
            acc3[nb] = __builtin_amdgcn_mfma_f32_16x16x32_bf16(af, o1f[kb][nb], acc3[nb], 0, 0, 0);
    }
#pragma unroll
    for (int nb = 0; nb < 4; ++nb)
#pragma unroll
        for (int r = 0; r < 4; ++r) {
            float v = acc3[nb][r] + b1v[nb];
            hid_s[w][(qq*4 + r)*72 + nb*16 + l15] = f2b(v > 0.0f ? v : 0.0f);
        }

    // GEMM4: hid[16x64] @ ow2^T[64x4(pad16)] + b2
    f32x4 acc4 = (f32x4)(0.0f);
#pragma unroll
    for (int kb = 0; kb < 2; ++kb) {
        bf16x8 af = *(const bf16x8*)(&hid_s[w][l15*72 + kb*32 + qq*8]);
        acc4 = __builtin_amdgcn_mfma_f32_16x16x32_bf16(af, bo2[kb], acc4, 0, 0, 0);
    }
    if (l15 < 4) {
#pragma unroll
        for (int r = 0; r < 4; ++r) {
            int item = itemBase + qq*4 + r;
            float nx = xt[item*4 + l15] + acc4[r] + b2v;
            xt[item*4 + l15] = nx;
            int n = item >> 1, s = item & 1;
            out[((n*TT + tstep)*SS + s)*4 + l15] = nx;
        }
    }
}

extern "C" void kernel_launch(void* const* d_in, const int* in_sizes, int n_in,
                              void* d_out, int out_size, void* d_ws, size_t ws_size,
                              hipStream_t stream) {
    const float* inputs = (const float*)d_in[0];
    const float* zA     = (const float*)d_in[1];
    const float* zG     = (const float*)d_in[2];
    const int*   src    = (const int*)d_in[3];
    const int*   dst    = (const int*)d_in[4];
    const float* Ws     = (const float*)d_in[5];
    const float* Wd     = (const float*)d_in[6];
    const float* F2w1   = (const float*)d_in[7];
    const float* F2w2   = (const float*)d_in[8];
    const float* F1w1   = (const float*)d_in[9];
    const float* F1w2   = (const float*)d_in[10];
    const float* xw     = (const float*)d_in[11];
    const float* xb     = (const float*)d_in[12];
    const float* ow1    = (const float*)d_in[13];
    const float* ob1    = (const float*)d_in[14];
    const float* ow2    = (const float*)d_in[15];
    const float* ob2    = (const float*)d_in[16];
    float* out = (float*)d_out;

    // ---- workspace carve (units: floats) ----
    float*          base        = (float*)d_ws;
    float*          MT          = base;                              // 4,096
    float*          e_csr       = base + 4096;                       // 1,280,000
    float*          alpha       = base + 1284096;                    // 1,280,000
    int*            deg_i       = (int*)(base + 2564096);            // 10,000 (zeroed)
    int*            offsets     = (int*)(base + 2574096);            // 10,016
    int*            cursor      = (int*)(base + 2584112);            // 10,000
    int*            src_by_pos  = (int*)(base + 2594112);            // 160,000
    int*            dst_by_pos  = (int*)(base + 2754112);            // 160,000
    float*          xt          = base + 2914112;                    // 80,000
    float*          G1f         = base + 2994112;                    // 256
    float*          G2f         = base + 2994368;                    // 256
    float*          c1f         = base + 2994624;                    // 64
    float*          c2f         = base + 2994688;                    // 64 (ends 2,994,752; pad to 2,994,816)
    unsigned short* P1b         = (unsigned short*)(base + 2994816); // 1,280,000 ush
    unsigned short* P2b         = (unsigned short*)(base + 3634816); // 1,280,000 ush
    unsigned short* W2b         = (unsigned short*)(base + 4274816); // 4,096 ush
    unsigned short* F1w1b       = (unsigned short*)(base + 4276864); // 16,384 ush
    unsigned short* F1w2b       = (unsigned short*)(base + 4285056); // 4,096 ush
    unsigned short* ow1b        = (unsigned short*)(base + 4287104); // 6,144 ush
    unsigned short* ow2b        = (unsigned short*)(base + 4290176); // 256 ush
    unsigned short* zAb         = (unsigned short*)(base + 4290304); // 640,000 ush
    unsigned short* zGb         = (unsigned short*)(base + 4610304); // 640,000 ush
    unsigned short* res_b       = (unsigned short*)(base + 4930304); // 5,120,000 ush
    // phase union @ 7,490,304: qdb (2.56M ush, attention) / dA (20.48M ush, steps)
    unsigned short* qdb         = (unsigned short*)(base + 7490304);
    unsigned short* dA          = (unsigned short*)(base + 7490304);
    // total 17,730,304 floats = 70.9 MB

    hipMemsetAsync(deg_i, 0, 10000u * 4u, stream);

    // ---- attention phase (once) ----
    k_attnM<<<KK*ZZ, ZZ, 0, stream>>>(Ws, Wd, MT);
    k_qd<<<(NN*SS*KK*ZZ + 255)/256, 256, 0, stream>>>(zG, MT, qdb);
    k_fold<<<1, 256, 0, stream>>>(F2w1, xw, xb, G1f, G2f, c1f, c2f);
    k_conv_all<<<(NN*SS*ZZ + 255)/256, 256, 0, stream>>>(F2w2, F1w1, F1w2, ow1, ow2,
                                                         zA, zG, W2b, F1w1b, F1w2b,
                                                         ow1b, ow2b, zAb, zGb);
    k_deg<<<(NE + 255)/256, 256, 0, stream>>>(dst, deg_i);
    k_scan<<<1, 1024, 0, stream>>>(deg_i, offsets, cursor);
    k_scatter<<<(NE + 255)/256, 256, 0, stream>>>(src, dst, cursor, src_by_pos, dst_by_pos);
    k_edge_e<<<(NE*SS + 255)/256, 256, 0, stream>>>(qdb, zGb, src_by_pos, dst_by_pos, e_csr);
    k_salpha<<<NN*SS, 64, 0, stream>>>(e_csr, offsets, alpha);

    // ---- time stepping ----
    k_xt0<<<(NN*SS*NIN + 255)/256, 256, 0, stream>>>(inputs, xt);
    for (int t = 0; t < 2; ++t) {
        k_xenc2<<<(NN*SS*HH + 255)/256, 256, 0, stream>>>(xt, G1f, G2f, c1f, c2f, P1b, P2b);
        k_edge_mfma<<<1024, 256, 0, stream>>>(P1b, P2b, W2b, src_by_pos, dst_by_pos, dA);
        k_agg<<<NN*SS, 64, 0, stream>>>(dA, offsets, alpha, res_b);
        k_node_mfma<<<(NN*SS + 63)/64, 256, 0, stream>>>(res_b, zAb, F1w1b, F1w2b,
                                                         ow1b, ow2b, ob1, ob2, xt, out, t);
    }
}

// Round 11
// 276.421 us; speedup vs baseline: 1.7450x; 1.1267x over previous
//
#include <hip/hip_runtime.h>

#define NN 10000
#define NE 160000
#define TT 2
#define SS 2
#define HH 64
#define ZZ 32
#define KK 4
#define NIN 4

typedef short bf16x8 __attribute__((ext_vector_type(8)));
typedef float f32x4 __attribute__((ext_vector_type(4)));

// fp32 -> bf16 (RNE)
__device__ __forceinline__ unsigned short f2b(float x) {
    unsigned u = __float_as_uint(x);
    u += 0x7fffu + ((u >> 16) & 1u);
    return (unsigned short)(u >> 16);
}
__device__ __forceinline__ float bf2f(unsigned short u) {
    return __uint_as_float(((unsigned)u) << 16);
}

// A0: MT[k][j][i] = sum_h Ws[k,h,i] * Wd[k,h,j]   (TRANSPOSED store for k_qd coalescing)
__global__ void k_attnM(const float* __restrict__ Ws, const float* __restrict__ Wd,
                        float* __restrict__ MT) {
    int k = blockIdx.x >> 5;
    int i = blockIdx.x & 31;
    int j = threadIdx.x;
    float acc = 0.0f;
    for (int h = 0; h < HH; ++h)
        acc += Ws[(k*HH + h)*ZZ + i] * Wd[(k*HH + h)*ZZ + j];
    MT[(k*ZZ + j)*ZZ + i] = acc;
}

// A1: qd[n,s,k,i] (bf16) = sum_j MT[k][j][i] * zG[n,s,j]  (coalesced over i)
__global__ void k_qd(const float* __restrict__ zG, const float* __restrict__ MT,
                     unsigned short* __restrict__ qdb) {
    int t = blockIdx.x * blockDim.x + threadIdx.x;
    if (t >= NN*SS*KK*ZZ) return;
    int i  = t & 31;
    int k  = (t >> 5) & 3;
    int ns = t >> 7;
    const float* zg = zG + ns*ZZ;
    const float* mt = MT + k*ZZ*ZZ;
    float acc = 0.0f;
#pragma unroll
    for (int j = 0; j < ZZ; ++j) acc += mt[j*ZZ + i] * zg[j];
    qdb[t] = f2b(acc);
}

// Fold xenc into F2w1 halves: G1 = W1a@xw, G2 = W1b@xw, c1 = W1a@xb, c2 = W1b@xb
__global__ void k_fold(const float* __restrict__ F2w1, const float* __restrict__ xw,
                       const float* __restrict__ xb,
                       float* __restrict__ G1, float* __restrict__ G2,
                       float* __restrict__ c1, float* __restrict__ c2) {
    int t = threadIdx.x;
    int h = t >> 2, i = t & 3;
    float a1 = 0.f, a2 = 0.f;
    for (int j = 0; j < HH; ++j) {
        float x = xw[j*NIN + i];
        a1 += F2w1[h*128 + j] * x;
        a2 += F2w1[h*128 + 64 + j] * x;
    }
    G1[h*4 + i] = a1;
    G2[h*4 + i] = a2;
    if (i == 0) {
        float b1 = 0.f, b2 = 0.f;
        for (int j = 0; j < HH; ++j) {
            float bb = xb[j];
            b1 += F2w1[h*128 + j] * bb;
            b2 += F2w1[h*128 + 64 + j] * bb;
        }
        c1[h] = b1; c2[h] = b2;
    }
}

// deg count
__global__ void k_deg(const int* __restrict__ dst, int* __restrict__ deg_i) {
    int e = blockIdx.x * blockDim.x + threadIdx.x;
    if (e < NE) atomicAdd(deg_i + dst[e], 1);
}

// C2: exclusive scan of deg_i -> offsets[0..NN], cursor copy (1 block, Hillis-Steele)
__global__ void k_scan(const int* __restrict__ deg_i, int* __restrict__ offsets,
                       int* __restrict__ cursor) {
    __shared__ int buf0[1024], buf1[1024];
    int tidx = threadIdx.x;
    const int CH = (NN + 1023) / 1024;   // 10
    int b0 = tidx * CH;
    int sum = 0;
    for (int i = 0; i < CH; ++i) { int idx = b0 + i; if (idx < NN) sum += deg_i[idx]; }
    buf0[tidx] = sum;
    __syncthreads();
    int* s = buf0; int* d = buf1;
    for (int off = 1; off < 1024; off <<= 1) {
        d[tidx] = s[tidx] + (tidx >= off ? s[tidx - off] : 0);
        __syncthreads();
        int* tmp = s; s = d; d = tmp;
    }
    int run = s[tidx] - sum;
    for (int i = 0; i < CH; ++i) {
        int idx = b0 + i;
        if (idx < NN) { offsets[idx] = run; cursor[idx] = run; run += deg_i[idx]; }
    }
    if (tidx == 0) offsets[NN] = NE;
}

// C3: scatter src/dst node ids into dst-sorted position order
__global__ void k_scatter(const int* __restrict__ src, const int* __restrict__ dst,
                          int* __restrict__ cursor, int* __restrict__ src_by_pos,
                          int* __restrict__ dst_by_pos) {
    int e = blockIdx.x * blockDim.x + threadIdx.x;
    if (e >= NE) return;
    int sn = src[e], dn = dst[e];
    int pos = atomicAdd(cursor + dn, 1);
    src_by_pos[pos] = sn;
    dst_by_pos[pos] = dn;
}

// A2: CSR-order scores; per-edge random side is zGb[src] (64B, L2-resident)
__global__ __launch_bounds__(256) void k_edge_e(
    const unsigned short* __restrict__ qdb, const unsigned short* __restrict__ zGb,
    const int* __restrict__ src_by_pos, const int* __restrict__ dst_by_pos,
    float* __restrict__ e_csr) {
    int t = blockIdx.x * blockDim.x + threadIdx.x;
    if (t >= NE*SS) return;
    int s = t & 1;
    int idx = t >> 1;
    int sn = src_by_pos[idx], dn = dst_by_pos[idx];
    const unsigned* zp = (const unsigned*)(zGb + (sn*SS + s)*ZZ);
    float zf[32];
#pragma unroll
    for (int j = 0; j < 16; ++j) {
        unsigned u = zp[j];
        zf[2*j]   = __uint_as_float(u << 16);
        zf[2*j+1] = __uint_as_float(u & 0xffff0000u);
    }
    const unsigned* qp = (const unsigned*)(qdb + (dn*SS + s)*KK*ZZ);
    float ev[4];
#pragma unroll
    for (int k = 0; k < 4; ++k) {
        float a = 0.f;
#pragma unroll
        for (int j = 0; j < 16; ++j) {
            unsigned u = qp[k*16 + j];
            a += __uint_as_float(u << 16) * zf[2*j]
               + __uint_as_float(u & 0xffff0000u) * zf[2*j+1];
        }
        ev[k] = a > 0.f ? a : 0.01f*a;
    }
    *(float4*)(e_csr + t*4) = *(float4*)ev;
}

// A3+A4 fused: per-(n,s) softmax stats in-wave, alpha written directly.
__global__ __launch_bounds__(64) void k_salpha(
    const float* __restrict__ e_csr, const int* __restrict__ offsets,
    float* __restrict__ alpha) {
    int item = blockIdx.x;
    int n = item >> 1, s = item & 1;
    int l = threadIdx.x;
    int i = l >> 2, k = l & 3;
    int r0 = offsets[n], r1 = offsets[n+1];
    float mx = -1e30f;
    for (int idx = r0 + i; idx < r1; idx += 16)
        mx = fmaxf(mx, e_csr[(idx*2 + s)*4 + k]);
#pragma unroll
    for (int off = 4; off < 64; off <<= 1) mx = fmaxf(mx, __shfl_xor(mx, off));
    float sum = 0.f;
    for (int idx = r0 + i; idx < r1; idx += 16)
        sum += __expf(e_csr[(idx*2 + s)*4 + k] - mx);
#pragma unroll
    for (int off = 4; off < 64; off <<= 1) sum += __shfl_xor(sum, off);
    int deg = r1 - r0;
    float dd = (float)(deg > 1 ? deg : 1);
    float inv = sum > 0.f ? 1.f/(sum*dd) : 0.f;
    for (int idx = r0 + i; idx < r1; idx += 16)
        alpha[(idx*2 + s)*4 + k] = __expf(e_csr[(idx*2 + s)*4 + k] - mx) * inv;
}

// W0: convert step-phase constants to bf16
__global__ void k_conv_all(const float* __restrict__ F2w2,
                           const float* __restrict__ F1w1, const float* __restrict__ F1w2,
                           const float* __restrict__ ow1, const float* __restrict__ ow2,
                           const float* __restrict__ zA, const float* __restrict__ zG,
                           unsigned short* __restrict__ W2b,
                           unsigned short* __restrict__ F1w1b, unsigned short* __restrict__ F1w2b,
                           unsigned short* __restrict__ ow1b, unsigned short* __restrict__ ow2b,
                           unsigned short* __restrict__ zAb, unsigned short* __restrict__ zGb) {
    int t = blockIdx.x * blockDim.x + threadIdx.x;
    if (t < NN*SS*ZZ) { zAb[t] = f2b(zA[t]); zGb[t] = f2b(zG[t]); }
    if (t < HH*HH)    { W2b[t] = f2b(F2w2[t]); F1w2b[t] = f2b(F1w2[t]); }
    if (t < HH*KK*HH) F1w1b[t] = f2b(F1w1[t]);
    if (t < HH*(HH+ZZ)) ow1b[t] = f2b(ow1[t]);
    if (t < 4*HH)     ow2b[t] = f2b(ow2[t]);
}

// B0: xt[n,s,i] = inputs[n, 0, i]
__global__ void k_xt0(const float* __restrict__ inputs, float* __restrict__ xt) {
    int t = blockIdx.x * blockDim.x + threadIdx.x;
    if (t >= NN*SS*NIN) return;
    int i = t & 3;
    int n = t >> 3;
    xt[t] = inputs[n*(TT*NIN) + i];
}

// B1: P1[ns,h] = xt[ns]@G1^T + c1, P2 = xt@G2^T + c2  (xenc folded into W1 halves)
__global__ void k_xenc2(const float* __restrict__ xt, const float* __restrict__ G1,
                        const float* __restrict__ G2, const float* __restrict__ c1,
                        const float* __restrict__ c2,
                        unsigned short* __restrict__ P1b, unsigned short* __restrict__ P2b) {
    int t = blockIdx.x * blockDim.x + threadIdx.x;
    if (t >= NN*SS*HH) return;
    int h  = t & 63;
    int ns = t >> 6;
    const float* x = xt + ns*NIN;
    float p1 = c1[h], p2 = c2[h];
#pragma unroll
    for (int i = 0; i < NIN; ++i) {
        p1 += x[i] * G1[h*NIN + i];
        p2 += x[i] * G2[h*NIN + i];
    }
    P1b[t] = f2b(p1);
    P2b[t] = f2b(p2);
}

// B2 v4: fused edge layer-1 + aggregation (W2 commuted out to node kernel).
// Per (n,s): p2 loaded once (dst fixed); per edge one coalesced 128B P1[src] row;
// hid = relu(p1+p2); agg_k += alpha_k * hid (fp32).
__global__ __launch_bounds__(64) void k_agg2(
    const unsigned short* __restrict__ P1b, const unsigned short* __restrict__ P2b,
    const int* __restrict__ src_by_pos, const int* __restrict__ offsets,
    const float* __restrict__ alpha, unsigned short* __restrict__ agg_b)
{
    int item = blockIdx.x;
    int n = item >> 1, s = item & 1;
    int h = threadIdx.x;
    int r0 = offsets[n], r1 = offsets[n+1];
    float p2 = bf2f(P2b[item*HH + h]);   // item == n*SS+s
    float a0 = 0.f, a1 = 0.f, a2 = 0.f, a3 = 0.f;
    for (int idx = r0; idx < r1; ++idx) {
        int sn = src_by_pos[idx];
        float p1 = bf2f(P1b[(sn*SS + s)*HH + h]);
        float hid = p1 + p2;
        hid = hid > 0.f ? hid : 0.f;
        const float4 w4 = *(const float4*)(alpha + (idx*2 + s)*4);
        a0 += w4.x*hid; a1 += w4.y*hid; a2 += w4.z*hid; a3 += w4.w*hid;
    }
    agg_b[item*256 +       h] = f2b(a0);
    agg_b[item*256 + 64  + h] = f2b(a1);
    agg_b[item*256 + 128 + h] = f2b(a2);
    agg_b[item*256 + 192 + h] = f2b(a3);
}

// B3 v3: GEMM0 (agg@W2^T block-diag per head) + chained node GEMMs.
// 4 waves/block, 16 items/wave. Per-wave LDS only, no barrier.
__global__ __launch_bounds__(256) void k_node_mfma(
    const unsigned short* __restrict__ agg_b, const unsigned short* __restrict__ zAb,
    const unsigned short* __restrict__ W2b,
    const unsigned short* __restrict__ F1w1b, const unsigned short* __restrict__ F1w2b,
    const unsigned short* __restrict__ ow1b, const unsigned short* __restrict__ ow2b,
    const float* __restrict__ ob1, const float* __restrict__ ob2,
    float* __restrict__ xt, float* __restrict__ out, int tstep)
{
    __shared__ unsigned short res_s[4][16*264];
    __shared__ unsigned short hid_s[4][16*72];
    __shared__ unsigned short hcat_s[4][16*104];
    int tid = threadIdx.x;
    int w = tid >> 6, l = tid & 63, l15 = l & 15, qq = l >> 4;

    bf16x8 w2f[2][4], b2f[2][4], o1f[3][4], bo2[2];
#pragma unroll
    for (int nb = 0; nb < 4; ++nb) {
        int n = nb*16 + l15;
#pragma unroll
        for (int kb = 0; kb < 2; ++kb) {
            w2f[kb][nb] = *(const bf16x8*)(W2b  + n*64 + kb*32 + qq*8);
            b2f[kb][nb] = *(const bf16x8*)(F1w2b + n*64 + kb*32 + qq*8);
        }
#pragma unroll
        for (int kb = 0; kb < 3; ++kb)
            o1f[kb][nb] = *(const bf16x8*)(ow1b + n*96 + kb*32 + qq*8);
    }
#pragma unroll
    for (int kb = 0; kb < 2; ++kb) {
        if (l15 < 4) bo2[kb] = *(const bf16x8*)(ow2b + l15*64 + kb*32 + qq*8);
        else {
            bf16x8 z;
#pragma unroll
            for (int j = 0; j < 8; ++j) z[j] = 0;
            bo2[kb] = z;
        }
    }
    float b1v[4];
#pragma unroll
    for (int nb = 0; nb < 4; ++nb) b1v[nb] = ob1[nb*16 + l15];
    float b2v = (l15 < 4) ? ob2[l15] : 0.0f;

    int itemBase = blockIdx.x*64 + w*16;
    if (itemBase >= NN*SS) return;

    *(uint4*)(&hcat_s[w][l15*104 + 64 + qq*8]) =
        *(const uint4*)(zAb + (itemBase + l15)*ZZ + qq*8);

    // GEMM0: res[item, k*64+h'] = sum_h agg[item,k*64+h] * W2[h'][h]  (per-head block-diag)
#pragma unroll
    for (int k = 0; k < 4; ++k) {
        f32x4 acc0[4];
#pragma unroll
        for (int nb = 0; nb < 4; ++nb) acc0[nb] = (f32x4)(0.0f);
#pragma unroll
        for (int kb = 0; kb < 2; ++kb) {
            bf16x8 af = *(const bf16x8*)(agg_b + (itemBase + l15)*256 + k*64 + kb*32 + qq*8);
#pragma unroll
            for (int nb = 0; nb < 4; ++nb)
                acc0[nb] = __builtin_amdgcn_mfma_f32_16x16x32_bf16(af, w2f[kb][nb], acc0[nb], 0, 0, 0);
        }
#pragma unroll
        for (int nb = 0; nb < 4; ++nb)
#pragma unroll
            for (int r = 0; r < 4; ++r)
                res_s[w][(qq*4 + r)*264 + k*64 + nb*16 + l15] = f2b(acc0[nb][r]);
    }

    // GEMM1: res[16x256] @ F1w1^T[256x64], relu (A from per-wave LDS, B from global)
    f32x4 acc[4];
#pragma unroll
    for (int nb = 0; nb < 4; ++nb) acc[nb] = (f32x4)(0.0f);
#pragma unroll
    for (int kb = 0; kb < 8; ++kb) {
        bf16x8 af = *(const bf16x8*)(&res_s[w][l15*264 + kb*32 + qq*8]);
#pragma unroll
        for (int nb = 0; nb < 4; ++nb) {
            bf16x8 bf = *(const bf16x8*)(F1w1b + (nb*16 + l15)*256 + kb*32 + qq*8);
            acc[nb] = __builtin_amdgcn_mfma_f32_16x16x32_bf16(af, bf, acc[nb], 0, 0, 0);
        }
    }
#pragma unroll
    for (int nb = 0; nb < 4; ++nb)
#pragma unroll
        for (int r = 0; r < 4; ++r) {
            float v = acc[nb][r];
            hid_s[w][(qq*4 + r)*72 + nb*16 + l15] = f2b(v > 0.0f ? v : 0.0f);
        }

    // GEMM2: hid[16x64] @ F1w2^T[64x64] -> deltax -> hcat cols 0..63
    f32x4 acc2[4];
#pragma unroll
    for (int nb = 0; nb < 4; ++nb) acc2[nb] = (f32x4)(0.0f);
#pragma unroll
    for (int kb = 0; kb < 2; ++kb) {
        bf16x8 af = *(const bf16x8*)(&hid_s[w][l15*72 + kb*32 + qq*8]);
#pragma unroll
        for (int nb = 0; nb < 4; ++nb)
            acc2[nb] = __builtin_amdgcn_mfma_f32_16x16x32_bf16(af, b2f[kb][nb], acc2[nb], 0, 0, 0);
    }
#pragma unroll
    for (int nb = 0; nb < 4; ++nb)
#pragma unroll
        for (int r = 0; r < 4; ++r)
            hcat_s[w][(qq*4 + r)*104 + nb*16 + l15] = f2b(acc2[nb][r]);

    // GEMM3: hcat[16x96] @ ow1^T[96x64] + b1, relu -> hid_s
    f32x4 acc3[4];
#pragma unroll
    for (int nb = 0; nb < 4; ++nb) acc3[nb] = (f32x4)(0.0f);
#pragma unroll
    for (int kb = 0; kb < 3; ++kb) {
        bf16x8 af = *(const bf16x8*)(&hcat_s[w][l15*104 + kb*32 + qq*8]);
#pragma unroll
        for (int nb = 0; nb < 4; ++nb)
            acc3[nb] = __builtin_amdgcn_mfma_f32_16x16x32_bf16(af, o1f[kb][nb], acc3[nb], 0, 0, 0);
    }
#pragma unroll
    for (int nb = 0; nb < 4; ++nb)
#pragma unroll
        for (int r = 0; r < 4; ++r) {
            float v = acc3[nb][r] + b1v[nb];
            hid_s[w][(qq*4 + r)*72 + nb*16 + l15] = f2b(v > 0.0f ? v : 0.0f);
        }

    // GEMM4: hid[16x64] @ ow2^T[64x4(pad16)] + b2
    f32x4 acc4 = (f32x4)(0.0f);
#pragma unroll
    for (int kb = 0; kb < 2; ++kb) {
        bf16x8 af = *(const bf16x8*)(&hid_s[w][l15*72 + kb*32 + qq*8]);
        acc4 = __builtin_amdgcn_mfma_f32_16x16x32_bf16(af, bo2[kb], acc4, 0, 0, 0);
    }
    if (l15 < 4) {
#pragma unroll
        for (int r = 0; r < 4; ++r) {
            int item = itemBase + qq*4 + r;
            float nx = xt[item*4 + l15] + acc4[r] + b2v;
            xt[item*4 + l15] = nx;
            int n = item >> 1, s = item & 1;
            out[((n*TT + tstep)*SS + s)*4 + l15] = nx;
        }
    }
}

extern "C" void kernel_launch(void* const* d_in, const int* in_sizes, int n_in,
                              void* d_out, int out_size, void* d_ws, size_t ws_size,
                              hipStream_t stream) {
    const float* inputs = (const float*)d_in[0];
    const float* zA     = (const float*)d_in[1];
    const float* zG     = (const float*)d_in[2];
    const int*   src    = (const int*)d_in[3];
    const int*   dst    = (const int*)d_in[4];
    const float* Ws     = (const float*)d_in[5];
    const float* Wd     = (const float*)d_in[6];
    const float* F2w1   = (const float*)d_in[7];
    const float* F2w2   = (const float*)d_in[8];
    const float* F1w1   = (const float*)d_in[9];
    const float* F1w2   = (const float*)d_in[10];
    const float* xw     = (const float*)d_in[11];
    const float* xb     = (const float*)d_in[12];
    const float* ow1    = (const float*)d_in[13];
    const float* ob1    = (const float*)d_in[14];
    const float* ow2    = (const float*)d_in[15];
    const float* ob2    = (const float*)d_in[16];
    float* out = (float*)d_out;

    // ---- workspace carve (units: floats) ----
    float*          base        = (float*)d_ws;
    float*          MT          = base;                              // 4,096
    float*          e_csr       = base + 4096;                       // 1,280,000
    float*          alpha       = base + 1284096;                    // 1,280,000
    int*            deg_i       = (int*)(base + 2564096);            // 10,000 (zeroed)
    int*            offsets     = (int*)(base + 2574096);            // 10,016
    int*            cursor      = (int*)(base + 2584112);            // 10,000
    int*            src_by_pos  = (int*)(base + 2594112);            // 160,000
    int*            dst_by_pos  = (int*)(base + 2754112);            // 160,000
    float*          xt          = base + 2914112;                    // 80,000
    float*          G1f         = base + 2994112;                    // 256
    float*          G2f         = base + 2994368;                    // 256
    float*          c1f         = base + 2994624;                    // 64
    float*          c2f         = base + 2994688;                    // 64 (pad to 2,994,816)
    unsigned short* P1b         = (unsigned short*)(base + 2994816); // 1,280,000 ush
    unsigned short* P2b         = (unsigned short*)(base + 3634816); // 1,280,000 ush
    unsigned short* W2b         = (unsigned short*)(base + 4274816); // 4,096 ush
    unsigned short* F1w1b       = (unsigned short*)(base + 4276864); // 16,384 ush
    unsigned short* F1w2b       = (unsigned short*)(base + 4285056); // 4,096 ush
    unsigned short* ow1b        = (unsigned short*)(base + 4287104); // 6,144 ush
    unsigned short* ow2b        = (unsigned short*)(base + 4290176); // 256 ush
    unsigned short* zAb         = (unsigned short*)(base + 4290304); // 640,000 ush
    unsigned short* zGb         = (unsigned short*)(base + 4610304); // 640,000 ush
    unsigned short* agg_b       = (unsigned short*)(base + 4930304); // 5,120,000 ush
    unsigned short* qdb         = (unsigned short*)(base + 7490304); // 2,560,000 ush (attention only)
    // total 8,770,304 floats = 35.1 MB

    hipMemsetAsync(deg_i, 0, 10000u * 4u, stream);

    // ---- attention phase (once) ----
    k_attnM<<<KK*ZZ, ZZ, 0, stream>>>(Ws, Wd, MT);
    k_qd<<<(NN*SS*KK*ZZ + 255)/256, 256, 0, stream>>>(zG, MT, qdb);
    k_fold<<<1, 256, 0, stream>>>(F2w1, xw, xb, G1f, G2f, c1f, c2f);
    k_conv_all<<<(NN*SS*ZZ + 255)/256, 256, 0, stream>>>(F2w2, F1w1, F1w2, ow1, ow2,
                                                         zA, zG, W2b, F1w1b, F1w2b,
                                                         ow1b, ow2b, zAb, zGb);
    k_deg<<<(NE + 255)/256, 256, 0, stream>>>(dst, deg_i);
    k_scan<<<1, 1024, 0, stream>>>(deg_i, offsets, cursor);
    k_scatter<<<(NE + 255)/256, 256, 0, stream>>>(src, dst, cursor, src_by_pos, dst_by_pos);
    k_edge_e<<<(NE*SS + 255)/256, 256, 0, stream>>>(qdb, zGb, src_by_pos, dst_by_pos, e_csr);
    k_salpha<<<NN*SS, 64, 0, stream>>>(e_csr, offsets, alpha);

    // ---- time stepping ----
    k_xt0<<<(NN*SS*NIN + 255)/256, 256, 0, stream>>>(inputs, xt);
    for (int t = 0; t < 2; ++t) {
        k_xenc2<<<(NN*SS*HH + 255)/256, 256, 0, stream>>>(xt, G1f, G2f, c1f, c2f, P1b, P2b);
        k_agg2<<<NN*SS, 64, 0, stream>>>(P1b, P2b, src_by_pos, offsets, alpha, agg_b);
        k_node_mfma<<<(NN*SS + 63)/64, 256, 0, stream>>>(agg_b, zAb, W2b, F1w1b, F1w2b,
                                                         ow1b, ow2b, ob1, ob2, xt, out, t);
    }
}

// Round 12
// 266.120 us; speedup vs baseline: 1.8126x; 1.0387x over previous
//
#include <hip/hip_runtime.h>

#define NN 10000
#define NE 160000
#define TT 2
#define SS 2
#define HH 64
#define ZZ 32
#define KK 4
#define NIN 4

typedef short bf16x8 __attribute__((ext_vector_type(8)));
typedef float f32x4 __attribute__((ext_vector_type(4)));

// fp32 -> bf16 (RNE)
__device__ __forceinline__ unsigned short f2b(float x) {
    unsigned u = __float_as_uint(x);
    u += 0x7fffu + ((u >> 16) & 1u);
    return (unsigned short)(u >> 16);
}
__device__ __forceinline__ float bf2f(unsigned short u) {
    return __uint_as_float(((unsigned)u) << 16);
}

// A0: MT[k][j][i] = sum_h Ws[k,h,i] * Wd[k,h,j]   (TRANSPOSED store for k_qd coalescing)
__global__ void k_attnM(const float* __restrict__ Ws, const float* __restrict__ Wd,
                        float* __restrict__ MT) {
    int k = blockIdx.x >> 5;
    int i = blockIdx.x & 31;
    int j = threadIdx.x;
    float acc = 0.0f;
    for (int h = 0; h < HH; ++h)
        acc += Ws[(k*HH + h)*ZZ + i] * Wd[(k*HH + h)*ZZ + j];
    MT[(k*ZZ + j)*ZZ + i] = acc;
}

// A1: qd[n,s,k,i] (bf16) = sum_j MT[k][j][i] * zG[n,s,j]  (coalesced over i)
__global__ void k_qd(const float* __restrict__ zG, const float* __restrict__ MT,
                     unsigned short* __restrict__ qdb) {
    int t = blockIdx.x * blockDim.x + threadIdx.x;
    if (t >= NN*SS*KK*ZZ) return;
    int i  = t & 31;
    int k  = (t >> 5) & 3;
    int ns = t >> 7;
    const float* zg = zG + ns*ZZ;
    const float* mt = MT + k*ZZ*ZZ;
    float acc = 0.0f;
#pragma unroll
    for (int j = 0; j < ZZ; ++j) acc += mt[j*ZZ + i] * zg[j];
    qdb[t] = f2b(acc);
}

// Fold xenc into F2w1 halves: G1 = W1a@xw, G2 = W1b@xw, c1 = W1a@xb, c2 = W1b@xb
__global__ void k_fold(const float* __restrict__ F2w1, const float* __restrict__ xw,
                       const float* __restrict__ xb,
                       float* __restrict__ G1, float* __restrict__ G2,
                       float* __restrict__ c1, float* __restrict__ c2) {
    int t = threadIdx.x;
    int h = t >> 2, i = t & 3;
    float a1 = 0.f, a2 = 0.f;
    for (int j = 0; j < HH; ++j) {
        float x = xw[j*NIN + i];
        a1 += F2w1[h*128 + j] * x;
        a2 += F2w1[h*128 + 64 + j] * x;
    }
    G1[h*4 + i] = a1;
    G2[h*4 + i] = a2;
    if (i == 0) {
        float b1 = 0.f, b2 = 0.f;
        for (int j = 0; j < HH; ++j) {
            float bb = xb[j];
            b1 += F2w1[h*128 + j] * bb;
            b2 += F2w1[h*128 + 64 + j] * bb;
        }
        c1[h] = b1; c2[h] = b2;
    }
}

// init: deg count + xt[n,s,i] = inputs[n,0,i]  (merged)
__global__ void k_init(const float* __restrict__ inputs, float* __restrict__ xt,
                       const int* __restrict__ dst, int* __restrict__ deg_i) {
    int t = blockIdx.x * blockDim.x + threadIdx.x;
    if (t < NE) atomicAdd(deg_i + dst[t], 1);
    if (t < NN*SS*NIN) {
        int i = t & 3;
        int n = t >> 3;
        xt[t] = inputs[n*(TT*NIN) + i];
    }
}

// C2: exclusive scan of deg_i -> offsets[0..NN], cursor copy (1 block, Hillis-Steele)
__global__ void k_scan(const int* __restrict__ deg_i, int* __restrict__ offsets,
                       int* __restrict__ cursor) {
    __shared__ int buf0[1024], buf1[1024];
    int tidx = threadIdx.x;
    const int CH = (NN + 1023) / 1024;   // 10
    int b0 = tidx * CH;
    int sum = 0;
    for (int i = 0; i < CH; ++i) { int idx = b0 + i; if (idx < NN) sum += deg_i[idx]; }
    buf0[tidx] = sum;
    __syncthreads();
    int* s = buf0; int* d = buf1;
    for (int off = 1; off < 1024; off <<= 1) {
        d[tidx] = s[tidx] + (tidx >= off ? s[tidx - off] : 0);
        __syncthreads();
        int* tmp = s; s = d; d = tmp;
    }
    int run = s[tidx] - sum;
    for (int i = 0; i < CH; ++i) {
        int idx = b0 + i;
        if (idx < NN) { offsets[idx] = run; cursor[idx] = run; run += deg_i[idx]; }
    }
    if (tidx == 0) offsets[NN] = NE;
}

// C3: scatter src/dst node ids into dst-sorted position order
__global__ void k_scatter(const int* __restrict__ src, const int* __restrict__ dst,
                          int* __restrict__ cursor, int* __restrict__ src_by_pos,
                          int* __restrict__ dst_by_pos) {
    int e = blockIdx.x * blockDim.x + threadIdx.x;
    if (e >= NE) return;
    int sn = src[e], dn = dst[e];
    int pos = atomicAdd(cursor + dn, 1);
    src_by_pos[pos] = sn;
    dst_by_pos[pos] = dn;
}

// A2: CSR-order scores; per-edge random side is zGb[src] (64B, L2-resident)
__global__ __launch_bounds__(256) void k_edge_e(
    const unsigned short* __restrict__ qdb, const unsigned short* __restrict__ zGb,
    const int* __restrict__ src_by_pos, const int* __restrict__ dst_by_pos,
    float* __restrict__ e_csr) {
    int t = blockIdx.x * blockDim.x + threadIdx.x;
    if (t >= NE*SS) return;
    int s = t & 1;
    int idx = t >> 1;
    int sn = src_by_pos[idx], dn = dst_by_pos[idx];
    const unsigned* zp = (const unsigned*)(zGb + (sn*SS + s)*ZZ);
    float zf[32];
#pragma unroll
    for (int j = 0; j < 16; ++j) {
        unsigned u = zp[j];
        zf[2*j]   = __uint_as_float(u << 16);
        zf[2*j+1] = __uint_as_float(u & 0xffff0000u);
    }
    const unsigned* qp = (const unsigned*)(qdb + (dn*SS + s)*KK*ZZ);
    float ev[4];
#pragma unroll
    for (int k = 0; k < 4; ++k) {
        float a = 0.f;
#pragma unroll
        for (int j = 0; j < 16; ++j) {
            unsigned u = qp[k*16 + j];
            a += __uint_as_float(u << 16) * zf[2*j]
               + __uint_as_float(u & 0xffff0000u) * zf[2*j+1];
        }
        ev[k] = a > 0.f ? a : 0.01f*a;
    }
    *(float4*)(e_csr + t*4) = *(float4*)ev;
}

// A3+A4 fused: per-(n,s) softmax stats in-wave, alpha written directly.
__global__ __launch_bounds__(64) void k_salpha(
    const float* __restrict__ e_csr, const int* __restrict__ offsets,
    float* __restrict__ alpha) {
    int item = blockIdx.x;
    int n = item >> 1, s = item & 1;
    int l = threadIdx.x;
    int i = l >> 2, k = l & 3;
    int r0 = offsets[n], r1 = offsets[n+1];
    float mx = -1e30f;
    for (int idx = r0 + i; idx < r1; idx += 16)
        mx = fmaxf(mx, e_csr[(idx*2 + s)*4 + k]);
#pragma unroll
    for (int off = 4; off < 64; off <<= 1) mx = fmaxf(mx, __shfl_xor(mx, off));
    float sum = 0.f;
    for (int idx = r0 + i; idx < r1; idx += 16)
        sum += __expf(e_csr[(idx*2 + s)*4 + k] - mx);
#pragma unroll
    for (int off = 4; off < 64; off <<= 1) sum += __shfl_xor(sum, off);
    int deg = r1 - r0;
    float dd = (float)(deg > 1 ? deg : 1);
    float inv = sum > 0.f ? 1.f/(sum*dd) : 0.f;
    for (int idx = r0 + i; idx < r1; idx += 16)
        alpha[(idx*2 + s)*4 + k] = __expf(e_csr[(idx*2 + s)*4 + k] - mx) * inv;
}

// W0: convert step-phase constants to bf16
__global__ void k_conv_all(const float* __restrict__ F2w2,
                           const float* __restrict__ F1w1, const float* __restrict__ F1w2,
                           const float* __restrict__ ow1, const float* __restrict__ ow2,
                           const float* __restrict__ zA, const float* __restrict__ zG,
                           unsigned short* __restrict__ W2b,
                           unsigned short* __restrict__ F1w1b, unsigned short* __restrict__ F1w2b,
                           unsigned short* __restrict__ ow1b, unsigned short* __restrict__ ow2b,
                           unsigned short* __restrict__ zAb, unsigned short* __restrict__ zGb) {
    int t = blockIdx.x * blockDim.x + threadIdx.x;
    if (t < NN*SS*ZZ) { zAb[t] = f2b(zA[t]); zGb[t] = f2b(zG[t]); }
    if (t < HH*HH)    { W2b[t] = f2b(F2w2[t]); F1w2b[t] = f2b(F1w2[t]); }
    if (t < HH*KK*HH) F1w1b[t] = f2b(F1w1[t]);
    if (t < HH*(HH+ZZ)) ow1b[t] = f2b(ow1[t]);
    if (t < 4*HH)     ow2b[t] = f2b(ow2[t]);
}

// B2 v5: fused xenc + edge layer-1 + aggregation. Per (n,s): p2 computed once
// from xt[item] (fp32); per edge one 16B wave-uniform xt[src] load + 4 FMAs.
// Edge loop unrolled x4 to keep 4 loads in flight.
__global__ __launch_bounds__(64) void k_agg2(
    const float* __restrict__ xt, const float* __restrict__ G1,
    const float* __restrict__ G2, const float* __restrict__ c1,
    const float* __restrict__ c2, const int* __restrict__ src_by_pos,
    const int* __restrict__ offsets, const float* __restrict__ alpha,
    unsigned short* __restrict__ agg_b)
{
    int item = blockIdx.x;
    int n = item >> 1, s = item & 1;
    int h = threadIdx.x;
    int r0 = offsets[n], r1 = offsets[n+1];
    const float4 g1 = *(const float4*)(G1 + h*4);
    const float4 g2 = *(const float4*)(G2 + h*4);
    const float4 xd = *(const float4*)(xt + item*4);
    float p2 = c2[h] + xd.x*g2.x + xd.y*g2.y + xd.z*g2.z + xd.w*g2.w;
    float c1h = c1[h];
    float a0 = 0.f, a1 = 0.f, a2 = 0.f, a3 = 0.f;
    int idx = r0;
    for (; idx + 4 <= r1; idx += 4) {
        int sn0 = src_by_pos[idx];
        int sn1 = src_by_pos[idx+1];
        int sn2 = src_by_pos[idx+2];
        int sn3 = src_by_pos[idx+3];
        float4 x0 = *(const float4*)(xt + (sn0*SS + s)*NIN);
        float4 x1 = *(const float4*)(xt + (sn1*SS + s)*NIN);
        float4 x2 = *(const float4*)(xt + (sn2*SS + s)*NIN);
        float4 x3 = *(const float4*)(xt + (sn3*SS + s)*NIN);
        float4 w0 = *(const float4*)(alpha + ((idx+0)*2 + s)*4);
        float4 w1 = *(const float4*)(alpha + ((idx+1)*2 + s)*4);
        float4 w2 = *(const float4*)(alpha + ((idx+2)*2 + s)*4);
        float4 w3 = *(const float4*)(alpha + ((idx+3)*2 + s)*4);
        float p, hd;
        p = c1h + x0.x*g1.x + x0.y*g1.y + x0.z*g1.z + x0.w*g1.w;
        hd = p + p2; hd = hd > 0.f ? hd : 0.f;
        a0 += w0.x*hd; a1 += w0.y*hd; a2 += w0.z*hd; a3 += w0.w*hd;
        p = c1h + x1.x*g1.x + x1.y*g1.y + x1.z*g1.z + x1.w*g1.w;
        hd = p + p2; hd = hd > 0.f ? hd : 0.f;
        a0 += w1.x*hd; a1 += w1.y*hd; a2 += w1.z*hd; a3 += w1.w*hd;
        p = c1h + x2.x*g1.x + x2.y*g1.y + x2.z*g1.z + x2.w*g1.w;
        hd = p + p2; hd = hd > 0.f ? hd : 0.f;
        a0 += w2.x*hd; a1 += w2.y*hd; a2 += w2.z*hd; a3 += w2.w*hd;
        p = c1h + x3.x*g1.x + x3.y*g1.y + x3.z*g1.z + x3.w*g1.w;
        hd = p + p2; hd = hd > 0.f ? hd : 0.f;
        a0 += w3.x*hd; a1 += w3.y*hd; a2 += w3.z*hd; a3 += w3.w*hd;
    }
    for (; idx < r1; ++idx) {
        int sn = src_by_pos[idx];
        float4 x0 = *(const float4*)(xt + (sn*SS + s)*NIN);
        float4 w0 = *(const float4*)(alpha + (idx*2 + s)*4);
        float p = c1h + x0.x*g1.x + x0.y*g1.y + x0.z*g1.z + x0.w*g1.w;
        float hd = p + p2; hd = hd > 0.f ? hd : 0.f;
        a0 += w0.x*hd; a1 += w0.y*hd; a2 += w0.z*hd; a3 += w0.w*hd;
    }
    agg_b[item*256 +       h] = f2b(a0);
    agg_b[item*256 + 64  + h] = f2b(a1);
    agg_b[item*256 + 128 + h] = f2b(a2);
    agg_b[item*256 + 192 + h] = f2b(a3);
}

// B3: GEMM0 (agg@W2^T block-diag per head) + chained node GEMMs.
// 4 waves/block, 16 items/wave. Per-wave LDS only, no barrier.
__global__ __launch_bounds__(256) void k_node_mfma(
    const unsigned short* __restrict__ agg_b, const unsigned short* __restrict__ zAb,
    const unsigned short* __restrict__ W2b,
    const unsigned short* __restrict__ F1w1b, const unsigned short* __restrict__ F1w2b,
    const unsigned short* __restrict__ ow1b, const unsigned short* __restrict__ ow2b,
    const float* __restrict__ ob1, const float* __restrict__ ob2,
    float* __restrict__ xt, float* __restrict__ out, int tstep)
{
    __shared__ unsigned short res_s[4][16*264];
    __shared__ unsigned short hid_s[4][16*72];
    __shared__ unsigned short hcat_s[4][16*104];
    int tid = threadIdx.x;
    int w = tid >> 6, l = tid & 63, l15 = l & 15, qq = l >> 4;

    bf16x8 w2f[2][4], b2f[2][4], o1f[3][4], bo2[2];
#pragma unroll
    for (int nb = 0; nb < 4; ++nb) {
        int n = nb*16 + l15;
#pragma unroll
        for (int kb = 0; kb < 2; ++kb) {
            w2f[kb][nb] = *(const bf16x8*)(W2b  + n*64 + kb*32 + qq*8);
            b2f[kb][nb] = *(const bf16x8*)(F1w2b + n*64 + kb*32 + qq*8);
        }
#pragma unroll
        for (int kb = 0; kb < 3; ++kb)
            o1f[kb][nb] = *(const bf16x8*)(ow1b + n*96 + kb*32 + qq*8);
    }
#pragma unroll
    for (int kb = 0; kb < 2; ++kb) {
        if (l15 < 4) bo2[kb] = *(const bf16x8*)(ow2b + l15*64 + kb*32 + qq*8);
        else {
            bf16x8 z;
#pragma unroll
            for (int j = 0; j < 8; ++j) z[j] = 0;
            bo2[kb] = z;
        }
    }
    float b1v[4];
#pragma unroll
    for (int nb = 0; nb < 4; ++nb) b1v[nb] = ob1[nb*16 + l15];
    float b2v = (l15 < 4) ? ob2[l15] : 0.0f;

    int itemBase = blockIdx.x*64 + w*16;
    if (itemBase >= NN*SS) return;

    *(uint4*)(&hcat_s[w][l15*104 + 64 + qq*8]) =
        *(const uint4*)(zAb + (itemBase + l15)*ZZ + qq*8);

    // GEMM0: res[item, k*64+h'] = sum_h agg[item,k*64+h] * W2[h'][h]
#pragma unroll
    for (int k = 0; k < 4; ++k) {
        f32x4 acc0[4];
#pragma unroll
        for (int nb = 0; nb < 4; ++nb) acc0[nb] = (f32x4)(0.0f);
#pragma unroll
        for (int kb = 0; kb < 2; ++kb) {
            bf16x8 af = *(const bf16x8*)(agg_b + (itemBase + l15)*256 + k*64 + kb*32 + qq*8);
#pragma unroll
            for (int nb = 0; nb < 4; ++nb)
                acc0[nb] = __builtin_amdgcn_mfma_f32_16x16x32_bf16(af, w2f[kb][nb], acc0[nb], 0, 0, 0);
        }
#pragma unroll
        for (int nb = 0; nb < 4; ++nb)
#pragma unroll
            for (int r = 0; r < 4; ++r)
                res_s[w][(qq*4 + r)*264 + k*64 + nb*16 + l15] = f2b(acc0[nb][r]);
    }

    // GEMM1: res[16x256] @ F1w1^T[256x64], relu
    f32x4 acc[4];
#pragma unroll
    for (int nb = 0; nb < 4; ++nb) acc[nb] = (f32x4)(0.0f);
#pragma unroll
    for (int kb = 0; kb < 8; ++kb) {
        bf16x8 af = *(const bf16x8*)(&res_s[w][l15*264 + kb*32 + qq*8]);
#pragma unroll
        for (int nb = 0; nb < 4; ++nb) {
            bf16x8 bf = *(const bf16x8*)(F1w1b + (nb*16 + l15)*256 + kb*32 + qq*8);
            acc[nb] = __builtin_amdgcn_mfma_f32_16x16x32_bf16(af, bf, acc[nb], 0, 0, 0);
        }
    }
#pragma unroll
    for (int nb = 0; nb < 4; ++nb)
#pragma unroll
        for (int r = 0; r < 4; ++r) {
            float v = acc[nb][r];
            hid_s[w][(qq*4 + r)*72 + nb*16 + l15] = f2b(v > 0.0f ? v : 0.0f);
        }

    // GEMM2: hid[16x64] @ F1w2^T[64x64] -> deltax -> hcat cols 0..63
    f32x4 acc2[4];
#pragma unroll
    for (int nb = 0; nb < 4; ++nb) acc2[nb] = (f32x4)(0.0f);
#pragma unroll
    for (int kb = 0; kb < 2; ++kb) {
        bf16x8 af = *(const bf16x8*)(&hid_s[w][l15*72 + kb*32 + qq*8]);
#pragma unroll
        for (int nb = 0; nb < 4; ++nb)
            acc2[nb] = __builtin_amdgcn_mfma_f32_16x16x32_bf16(af, b2f[kb][nb], acc2[nb], 0, 0, 0);
    }
#pragma unroll
    for (int nb = 0; nb < 4; ++nb)
#pragma unroll
        for (int r = 0; r < 4; ++r)
            hcat_s[w][(qq*4 + r)*104 + nb*16 + l15] = f2b(acc2[nb][r]);

    // GEMM3: hcat[16x96] @ ow1^T[96x64] + b1, relu -> hid_s
    f32x4 acc3[4];
#pragma unroll
    for (int nb = 0; nb < 4; ++nb) acc3[nb] = (f32x4)(0.0f);
#pragma unroll
    for (int kb = 0; kb < 3; ++kb) {
        bf16x8 af = *(const bf16x8*)(&hcat_s[w][l15*104 + kb*32 + qq*8]);
#pragma unroll
        for (int nb = 0; nb < 4; ++nb)
            acc3[nb] = __builtin_amdgcn_mfma_f32_16x16x32_bf16(af, o1f[kb][nb], acc3[nb], 0, 0, 0);
    }
#pragma unroll
    for (int nb = 0; nb < 4; ++nb)
#pragma unroll
        for (int r = 0; r < 4; ++r) {
            float v = acc3[nb][r] + b1v[nb];
            hid_s[w][(qq*4 + r)*72 + nb*16 + l15] = f2b(v > 0.0f ? v : 0.0f);
        }

    // GEMM4: hid[16x64] @ ow2^T[64x4(pad16)] + b2
    f32x4 acc4 = (f32x4)(0.0f);
#pragma unroll
    for (int kb = 0; kb < 2; ++kb) {
        bf16x8 af = *(const bf16x8*)(&hid_s[w][l15*72 + kb*32 + qq*8]);
        acc4 = __builtin_amdgcn_mfma_f32_16x16x32_bf16(af, bo2[kb], acc4, 0, 0, 0);
    }
    if (l15 < 4) {
#pragma unroll
        for (int r = 0; r < 4; ++r) {
            int item = itemBase + qq*4 + r;
            float nx = xt[item*4 + l15] + acc4[r] + b2v;
            xt[item*4 + l15] = nx;
            int n = item >> 1, s = item & 1;
            out[((n*TT + tstep)*SS + s)*4 + l15] = nx;
        }
    }
}

extern "C" void kernel_launch(void* const* d_in, const int* in_sizes, int n_in,
                              void* d_out, int out_size, void* d_ws, size_t ws_size,
                              hipStream_t stream) {
    const float* inputs = (const float*)d_in[0];
    const float* zA     = (const float*)d_in[1];
    const float* zG     = (const float*)d_in[2];
    const int*   src    = (const int*)d_in[3];
    const int*   dst    = (const int*)d_in[4];
    const float* Ws     = (const float*)d_in[5];
    const float* Wd     = (const float*)d_in[6];
    const float* F2w1   = (const float*)d_in[7];
    const float* F2w2   = (const float*)d_in[8];
    const float* F1w1   = (const float*)d_in[9];
    const float* F1w2   = (const float*)d_in[10];
    const float* xw     = (const float*)d_in[11];
    const float* xb     = (const float*)d_in[12];
    const float* ow1    = (const float*)d_in[13];
    const float* ob1    = (const float*)d_in[14];
    const float* ow2    = (const float*)d_in[15];
    const float* ob2    = (const float*)d_in[16];
    float* out = (float*)d_out;

    // ---- workspace carve (units: floats) ----
    float*          base        = (float*)d_ws;
    float*          MT          = base;                              // 4,096
    float*          e_csr       = base + 4096;                       // 1,280,000
    float*          alpha       = base + 1284096;                    // 1,280,000
    int*            deg_i       = (int*)(base + 2564096);            // 10,000 (zeroed)
    int*            offsets     = (int*)(base + 2574096);            // 10,016
    int*            cursor      = (int*)(base + 2584112);            // 10,000
    int*            src_by_pos  = (int*)(base + 2594112);            // 160,000
    int*            dst_by_pos  = (int*)(base + 2754112);            // 160,000
    float*          xt          = base + 2914112;                    // 80,000
    float*          G1f         = base + 2994112;                    // 256
    float*          G2f         = base + 2994368;                    // 256
    float*          c1f         = base + 2994624;                    // 64
    float*          c2f         = base + 2994688;                    // 64 (pad to 2,994,816)
    unsigned short* W2b         = (unsigned short*)(base + 2994816); // 4,096 ush
    unsigned short* F1w1b       = (unsigned short*)(base + 2996864); // 16,384 ush
    unsigned short* F1w2b       = (unsigned short*)(base + 3005056); // 4,096 ush
    unsigned short* ow1b        = (unsigned short*)(base + 3007104); // 6,144 ush
    unsigned short* ow2b        = (unsigned short*)(base + 3010176); // 256 ush
    unsigned short* zAb         = (unsigned short*)(base + 3010304); // 640,000 ush
    unsigned short* zGb         = (unsigned short*)(base + 3330304); // 640,000 ush
    unsigned short* agg_b       = (unsigned short*)(base + 3650304); // 5,120,000 ush
    unsigned short* qdb         = (unsigned short*)(base + 6210304); // 2,560,000 ush (attention only)
    // total 7,490,304 floats = 30.0 MB

    hipMemsetAsync(deg_i, 0, 10000u * 4u, stream);

    // ---- attention phase (once) ----
    k_attnM<<<KK*ZZ, ZZ, 0, stream>>>(Ws, Wd, MT);
    k_qd<<<(NN*SS*KK*ZZ + 255)/256, 256, 0, stream>>>(zG, MT, qdb);
    k_fold<<<1, 256, 0, stream>>>(F2w1, xw, xb, G1f, G2f, c1f, c2f);
    k_conv_all<<<(NN*SS*ZZ + 255)/256, 256, 0, stream>>>(F2w2, F1w1, F1w2, ow1, ow2,
                                                         zA, zG, W2b, F1w1b, F1w2b,
                                                         ow1b, ow2b, zAb, zGb);
    k_init<<<(NE + 255)/256, 256, 0, stream>>>(inputs, xt, dst, deg_i);
    k_scan<<<1, 1024, 0, stream>>>(deg_i, offsets, cursor);
    k_scatter<<<(NE + 255)/256, 256, 0, stream>>>(src, dst, cursor, src_by_pos, dst_by_pos);
    k_edge_e<<<(NE*SS + 255)/256, 256, 0, stream>>>(qdb, zGb, src_by_pos, dst_by_pos, e_csr);
    k_salpha<<<NN*SS, 64, 0, stream>>>(e_csr, offsets, alpha);

    // ---- time stepping ----
    for (int t = 0; t < 2; ++t) {
        k_agg2<<<NN*SS, 64, 0, stream>>>(xt, G1f, G2f, c1f, c2f,
                                         src_by_pos, offsets, alpha, agg_b);
        k_node_mfma<<<(NN*SS + 63)/64, 256, 0, stream>>>(agg_b, zAb, W2b, F1w1b, F1w2b,
                                                         ow1b, ow2b, ob1, ob2, xt, out, t);
    }
}

// Round 13
// 251.122 us; speedup vs baseline: 1.9208x; 1.0597x over previous
//
#include <hip/hip_runtime.h>

#define NN 10000
#define NE 160000
#define TT 2
#define SS 2
#define HH 64
#define ZZ 32
#define KK 4
#define NIN 4

typedef short bf16x8 __attribute__((ext_vector_type(8)));
typedef float f32x4 __attribute__((ext_vector_type(4)));

// fp32 -> bf16 (RNE)
__device__ __forceinline__ unsigned short f2b(float x) {
    unsigned u = __float_as_uint(x);
    u += 0x7fffu + ((u >> 16) & 1u);
    return (unsigned short)(u >> 16);
}
__device__ __forceinline__ float bf2f(unsigned short u) {
    return __uint_as_float(((unsigned)u) << 16);
}

// leaky(dot(zG_row(bf16 pairs), qf[32]))
__device__ __forceinline__ float edge_score(const unsigned* __restrict__ zp,
                                            const float* __restrict__ qf) {
    float a = 0.f;
#pragma unroll
    for (int j = 0; j < 16; ++j) {
        unsigned u = zp[j];
        a += __uint_as_float(u << 16) * qf[2*j]
           + __uint_as_float(u & 0xffff0000u) * qf[2*j+1];
    }
    return a > 0.f ? a : 0.01f*a;
}

// P0: merged prep. blocks 0..15: attnM (MT[k][j][i], transposed). block 16: fold.
// blocks 17+: bf16 conversions + xt init + deg count.
__global__ __launch_bounds__(256) void k_prep(
    const float* __restrict__ Ws, const float* __restrict__ Wd,
    const float* __restrict__ F2w1, const float* __restrict__ xw,
    const float* __restrict__ xb, const float* __restrict__ F2w2,
    const float* __restrict__ F1w1, const float* __restrict__ F1w2,
    const float* __restrict__ ow1, const float* __restrict__ ow2,
    const float* __restrict__ zA, const float* __restrict__ zG,
    const float* __restrict__ inputs, const int* __restrict__ dst,
    float* __restrict__ MT, float* __restrict__ G1, float* __restrict__ G2,
    float* __restrict__ c1, float* __restrict__ c2,
    unsigned short* __restrict__ W2b, unsigned short* __restrict__ F1w1b,
    unsigned short* __restrict__ F1w2b, unsigned short* __restrict__ ow1b,
    unsigned short* __restrict__ ow2b, unsigned short* __restrict__ zAb,
    unsigned short* __restrict__ zGb, float* __restrict__ xt,
    int* __restrict__ deg_i)
{
    int b = blockIdx.x;
    int tid = threadIdx.x;
    if (b < 16) {
        int o = b*256 + tid;              // 4096 outputs
        int j = o & 31, i = (o >> 5) & 31, k = o >> 10;
        float acc = 0.0f;
        for (int h = 0; h < HH; ++h)
            acc += Ws[(k*HH + h)*ZZ + i] * Wd[(k*HH + h)*ZZ + j];
        MT[(k*ZZ + j)*ZZ + i] = acc;
    } else if (b == 16) {
        int h = tid >> 2, i = tid & 3;
        float a1 = 0.f, a2 = 0.f;
        for (int j = 0; j < HH; ++j) {
            float x = xw[j*NIN + i];
            a1 += F2w1[h*128 + j] * x;
            a2 += F2w1[h*128 + 64 + j] * x;
        }
        G1[h*4 + i] = a1;
        G2[h*4 + i] = a2;
        if (i == 0) {
            float b1 = 0.f, b2 = 0.f;
            for (int j = 0; j < HH; ++j) {
                float bb = xb[j];
                b1 += F2w1[h*128 + j] * bb;
                b2 += F2w1[h*128 + 64 + j] * bb;
            }
            c1[h] = b1; c2[h] = b2;
        }
    } else {
        int t = (b - 17)*256 + tid;
        if (t < NN*SS*ZZ) { zAb[t] = f2b(zA[t]); zGb[t] = f2b(zG[t]); }
        if (t < HH*HH)    { W2b[t] = f2b(F2w2[t]); F1w2b[t] = f2b(F1w2[t]); }
        if (t < HH*KK*HH) F1w1b[t] = f2b(F1w1[t]);
        if (t < HH*(HH+ZZ)) ow1b[t] = f2b(ow1[t]);
        if (t < 4*HH)     ow2b[t] = f2b(ow2[t]);
        if (t < NN*SS*NIN) {
            int i = t & 3;
            int n = t >> 3;
            xt[t] = inputs[n*(TT*NIN) + i];
        }
        if (t < NE) atomicAdd(deg_i + dst[t], 1);
    }
}

// A1: qd[n,s,k,i] (bf16) = sum_j MT[k][j][i] * zG[n,s,j]  (coalesced over i)
__global__ void k_qd(const float* __restrict__ zG, const float* __restrict__ MT,
                     unsigned short* __restrict__ qdb) {
    int t = blockIdx.x * blockDim.x + threadIdx.x;
    if (t >= NN*SS*KK*ZZ) return;
    int i  = t & 31;
    int k  = (t >> 5) & 3;
    int ns = t >> 7;
    const float* zg = zG + ns*ZZ;
    const float* mt = MT + k*ZZ*ZZ;
    float acc = 0.0f;
#pragma unroll
    for (int j = 0; j < ZZ; ++j) acc += mt[j*ZZ + i] * zg[j];
    qdb[t] = f2b(acc);
}

// C2: exclusive scan of deg_i -> offsets[0..NN], cursor copy (1 block, Hillis-Steele)
__global__ void k_scan(const int* __restrict__ deg_i, int* __restrict__ offsets,
                       int* __restrict__ cursor) {
    __shared__ int buf0[1024], buf1[1024];
    int tidx = threadIdx.x;
    const int CH = (NN + 1023) / 1024;   // 10
    int b0 = tidx * CH;
    int sum = 0;
    for (int i = 0; i < CH; ++i) { int idx = b0 + i; if (idx < NN) sum += deg_i[idx]; }
    buf0[tidx] = sum;
    __syncthreads();
    int* s = buf0; int* d = buf1;
    for (int off = 1; off < 1024; off <<= 1) {
        d[tidx] = s[tidx] + (tidx >= off ? s[tidx - off] : 0);
        __syncthreads();
        int* tmp = s; s = d; d = tmp;
    }
    int run = s[tidx] - sum;
    for (int i = 0; i < CH; ++i) {
        int idx = b0 + i;
        if (idx < NN) { offsets[idx] = run; cursor[idx] = run; run += deg_i[idx]; }
    }
    if (tidx == 0) offsets[NN] = NE;
}

// C3: scatter src node ids into dst-sorted position order
__global__ void k_scatter(const int* __restrict__ src, const int* __restrict__ dst,
                          int* __restrict__ cursor, int* __restrict__ src_by_pos) {
    int e = blockIdx.x * blockDim.x + threadIdx.x;
    if (e >= NE) return;
    int pos = atomicAdd(cursor + dst[e], 1);
    src_by_pos[pos] = src[e];
}

// A2+A3+A4 fused: per (n,s) block computes scores on the fly, softmax stats
// in-wave (E[8] register cache, recompute fallback), writes alpha directly.
// alpha = exp(e - m) / (denom * deg)
__global__ __launch_bounds__(64) void k_attn_alpha(
    const unsigned short* __restrict__ qdb, const unsigned short* __restrict__ zGb,
    const int* __restrict__ src_by_pos, const int* __restrict__ offsets,
    float* __restrict__ alpha)
{
    int item = blockIdx.x;
    int n = item >> 1, s = item & 1;
    int l = threadIdx.x;
    int i = l >> 2, k = l & 3;
    int r0 = offsets[n], r1 = offsets[n+1];
    // head-k qd row for this item (uniform across the 16 slots of head k)
    float qf[32];
    const unsigned* qp = (const unsigned*)(qdb + (item*KK + k)*ZZ);
#pragma unroll
    for (int j = 0; j < 16; ++j) {
        unsigned u = qp[j];
        qf[2*j]   = __uint_as_float(u << 16);
        qf[2*j+1] = __uint_as_float(u & 0xffff0000u);
    }
    float E[8];
    float mx = -1e30f;
    int nit = 0;
    for (int idx = r0 + i; idx < r1; idx += 16, ++nit) {
        int sn = src_by_pos[idx];
        float e = edge_score((const unsigned*)(zGb + (sn*SS + s)*ZZ), qf);
        if (nit < 8) E[nit] = e;
        mx = fmaxf(mx, e);
    }
#pragma unroll
    for (int off = 4; off < 64; off <<= 1) mx = fmaxf(mx, __shfl_xor(mx, off));
    float sum = 0.f;
    nit = 0;
    for (int idx = r0 + i; idx < r1; idx += 16, ++nit) {
        float e = (nit < 8) ? E[nit]
                : edge_score((const unsigned*)(zGb + (src_by_pos[idx]*SS + s)*ZZ), qf);
        sum += __expf(e - mx);
    }
#pragma unroll
    for (int off = 4; off < 64; off <<= 1) sum += __shfl_xor(sum, off);
    int deg = r1 - r0;
    float dd = (float)(deg > 1 ? deg : 1);
    float inv = sum > 0.f ? 1.f/(sum*dd) : 0.f;
    nit = 0;
    for (int idx = r0 + i; idx < r1; idx += 16, ++nit) {
        float e = (nit < 8) ? E[nit]
                : edge_score((const unsigned*)(zGb + (src_by_pos[idx]*SS + s)*ZZ), qf);
        alpha[(idx*2 + s)*4 + k] = __expf(e - mx) * inv;
    }
}

// B2: fused xenc + edge layer-1 + aggregation. Per (n,s): p2 computed once
// from xt[item] (fp32); per edge one 16B wave-uniform xt[src] load + 4 FMAs.
// Edge loop unrolled x4 to keep 4 loads in flight.
__global__ __launch_bounds__(64) void k_agg2(
    const float* __restrict__ xt, const float* __restrict__ G1,
    const float* __restrict__ G2, const float* __restrict__ c1,
    const float* __restrict__ c2, const int* __restrict__ src_by_pos,
    const int* __restrict__ offsets, const float* __restrict__ alpha,
    unsigned short* __restrict__ agg_b)
{
    int item = blockIdx.x;
    int n = item >> 1, s = item & 1;
    int h = threadIdx.x;
    int r0 = offsets[n], r1 = offsets[n+1];
    const float4 g1 = *(const float4*)(G1 + h*4);
    const float4 g2 = *(const float4*)(G2 + h*4);
    const float4 xd = *(const float4*)(xt + item*4);
    float p2 = c2[h] + xd.x*g2.x + xd.y*g2.y + xd.z*g2.z + xd.w*g2.w;
    float c1h = c1[h];
    float a0 = 0.f, a1 = 0.f, a2 = 0.f, a3 = 0.f;
    int idx = r0;
    for (; idx + 4 <= r1; idx += 4) {
        int sn0 = src_by_pos[idx];
        int sn1 = src_by_pos[idx+1];
        int sn2 = src_by_pos[idx+2];
        int sn3 = src_by_pos[idx+3];
        float4 x0 = *(const float4*)(xt + (sn0*SS + s)*NIN);
        float4 x1 = *(const float4*)(xt + (sn1*SS + s)*NIN);
        float4 x2 = *(const float4*)(xt + (sn2*SS + s)*NIN);
        float4 x3 = *(const float4*)(xt + (sn3*SS + s)*NIN);
        float4 w0 = *(const float4*)(alpha + ((idx+0)*2 + s)*4);
        float4 w1 = *(const float4*)(alpha + ((idx+1)*2 + s)*4);
        float4 w2 = *(const float4*)(alpha + ((idx+2)*2 + s)*4);
        float4 w3 = *(const float4*)(alpha + ((idx+3)*2 + s)*4);
        float p, hd;
        p = c1h + x0.x*g1.x + x0.y*g1.y + x0.z*g1.z + x0.w*g1.w;
        hd = p + p2; hd = hd > 0.f ? hd : 0.f;
        a0 += w0.x*hd; a1 += w0.y*hd; a2 += w0.z*hd; a3 += w0.w*hd;
        p = c1h + x1.x*g1.x + x1.y*g1.y + x1.z*g1.z + x1.w*g1.w;
        hd = p + p2; hd = hd > 0.f ? hd : 0.f;
        a0 += w1.x*hd; a1 += w1.y*hd; a2 += w1.z*hd; a3 += w1.w*hd;
        p = c1h + x2.x*g1.x + x2.y*g1.y + x2.z*g1.z + x2.w*g1.w;
        hd = p + p2; hd = hd > 0.f ? hd : 0.f;
        a0 += w2.x*hd; a1 += w2.y*hd; a2 += w2.z*hd; a3 += w2.w*hd;
        p = c1h + x3.x*g1.x + x3.y*g1.y + x3.z*g1.z + x3.w*g1.w;
        hd = p + p2; hd = hd > 0.f ? hd : 0.f;
        a0 += w3.x*hd; a1 += w3.y*hd; a2 += w3.z*hd; a3 += w3.w*hd;
    }
    for (; idx < r1; ++idx) {
        int sn = src_by_pos[idx];
        float4 x0 = *(const float4*)(xt + (sn*SS + s)*NIN);
        float4 w0 = *(const float4*)(alpha + (idx*2 + s)*4);
        float p = c1h + x0.x*g1.x + x0.y*g1.y + x0.z*g1.z + x0.w*g1.w;
        float hd = p + p2; hd = hd > 0.f ? hd : 0.f;
        a0 += w0.x*hd; a1 += w0.y*hd; a2 += w0.z*hd; a3 += w0.w*hd;
    }
    agg_b[item*256 +       h] = f2b(a0);
    agg_b[item*256 + 64  + h] = f2b(a1);
    agg_b[item*256 + 128 + h] = f2b(a2);
    agg_b[item*256 + 192 + h] = f2b(a3);
}

// B3: GEMM0 (agg@W2^T block-diag per head) + chained node GEMMs.
// 4 waves/block, 16 items/wave. Per-wave LDS only, no barrier.
__global__ __launch_bounds__(256) void k_node_mfma(
    const unsigned short* __restrict__ agg_b, const unsigned short* __restrict__ zAb,
    const unsigned short* __restrict__ W2b,
    const unsigned short* __restrict__ F1w1b, const unsigned short* __restrict__ F1w2b,
    const unsigned short* __restrict__ ow1b, const unsigned short* __restrict__ ow2b,
    const float* __restrict__ ob1, const float* __restrict__ ob2,
    float* __restrict__ xt, float* __restrict__ out, int tstep)
{
    __shared__ unsigned short res_s[4][16*264];
    __shared__ unsigned short hid_s[4][16*72];
    __shared__ unsigned short hcat_s[4][16*104];
    int tid = threadIdx.x;
    int w = tid >> 6, l = tid & 63, l15 = l & 15, qq = l >> 4;

    bf16x8 w2f[2][4], b2f[2][4], o1f[3][4], bo2[2];
#pragma unroll
    for (int nb = 0; nb < 4; ++nb) {
        int n = nb*16 + l15;
#pragma unroll
        for (int kb = 0; kb < 2; ++kb) {
            w2f[kb][nb] = *(const bf16x8*)(W2b  + n*64 + kb*32 + qq*8);
            b2f[kb][nb] = *(const bf16x8*)(F1w2b + n*64 + kb*32 + qq*8);
        }
#pragma unroll
        for (int kb = 0; kb < 3; ++kb)
            o1f[kb][nb] = *(const bf16x8*)(ow1b + n*96 + kb*32 + qq*8);
    }
#pragma unroll
    for (int kb = 0; kb < 2; ++kb) {
        if (l15 < 4) bo2[kb] = *(const bf16x8*)(ow2b + l15*64 + kb*32 + qq*8);
        else {
            bf16x8 z;
#pragma unroll
            for (int j = 0; j < 8; ++j) z[j] = 0;
            bo2[kb] = z;
        }
    }
    float b1v[4];
#pragma unroll
    for (int nb = 0; nb < 4; ++nb) b1v[nb] = ob1[nb*16 + l15];
    float b2v = (l15 < 4) ? ob2[l15] : 0.0f;

    int itemBase = blockIdx.x*64 + w*16;
    if (itemBase >= NN*SS) return;

    *(uint4*)(&hcat_s[w][l15*104 + 64 + qq*8]) =
        *(const uint4*)(zAb + (itemBase + l15)*ZZ + qq*8);

    // GEMM0: res[item, k*64+h'] = sum_h agg[item,k*64+h] * W2[h'][h]
#pragma unroll
    for (int k = 0; k < 4; ++k) {
        f32x4 acc0[4];
#pragma unroll
        for (int nb = 0; nb < 4; ++nb) acc0[nb] = (f32x4)(0.0f);
#pragma unroll
        for (int kb = 0; kb < 2; ++kb) {
            bf16x8 af = *(const bf16x8*)(agg_b + (itemBase + l15)*256 + k*64 + kb*32 + qq*8);
#pragma unroll
            for (int nb = 0; nb < 4; ++nb)
                acc0[nb] = __builtin_amdgcn_mfma_f32_16x16x32_bf16(af, w2f[kb][nb], acc0[nb], 0, 0, 0);
        }
#pragma unroll
        for (int nb = 0; nb < 4; ++nb)
#pragma unroll
            for (int r = 0; r < 4; ++r)
                res_s[w][(qq*4 + r)*264 + k*64 + nb*16 + l15] = f2b(acc0[nb][r]);
    }

    // GEMM1: res[16x256] @ F1w1^T[256x64], relu
    f32x4 acc[4];
#pragma unroll
    for (int nb = 0; nb < 4; ++nb) acc[nb] = (f32x4)(0.0f);
#pragma unroll
    for (int kb = 0; kb < 8; ++kb) {
        bf16x8 af = *(const bf16x8*)(&res_s[w][l15*264 + kb*32 + qq*8]);
#pragma unroll
        for (int nb = 0; nb < 4; ++nb) {
            bf16x8 bf = *(const bf16x8*)(F1w1b + (nb*16 + l15)*256 + kb*32 + qq*8);
            acc[nb] = __builtin_amdgcn_mfma_f32_16x16x32_bf16(af, bf, acc[nb], 0, 0, 0);
        }
    }
#pragma unroll
    for (int nb = 0; nb < 4; ++nb)
#pragma unroll
        for (int r = 0; r < 4; ++r) {
            float v = acc[nb][r];
            hid_s[w][(qq*4 + r)*72 + nb*16 + l15] = f2b(v > 0.0f ? v : 0.0f);
        }

    // GEMM2: hid[16x64] @ F1w2^T[64x64] -> deltax -> hcat cols 0..63
    f32x4 acc2[4];
#pragma unroll
    for (int nb = 0; nb < 4; ++nb) acc2[nb] = (f32x4)(0.0f);
#pragma unroll
    for (int kb = 0; kb < 2; ++kb) {
        bf16x8 af = *(const bf16x8*)(&hid_s[w][l15*72 + kb*32 + qq*8]);
#pragma unroll
        for (int nb = 0; nb < 4; ++nb)
            acc2[nb] = __builtin_amdgcn_mfma_f32_16x16x32_bf16(af, b2f[kb][nb], acc2[nb], 0, 0, 0);
    }
#pragma unroll
    for (int nb = 0; nb < 4; ++nb)
#pragma unroll
        for (int r = 0; r < 4; ++r)
            hcat_s[w][(qq*4 + r)*104 + nb*16 + l15] = f2b(acc2[nb][r]);

    // GEMM3: hcat[16x96] @ ow1^T[96x64] + b1, relu -> hid_s
    f32x4 acc3[4];
#pragma unroll
    for (int nb = 0; nb < 4; ++nb) acc3[nb] = (f32x4)(0.0f);
#pragma unroll
    for (int kb = 0; kb < 3; ++kb) {
        bf16x8 af = *(const bf16x8*)(&hcat_s[w][l15*104 + kb*32 + qq*8]);
#pragma unroll
        for (int nb = 0; nb < 4; ++nb)
            acc3[nb] = __builtin_amdgcn_mfma_f32_16x16x32_bf16(af, o1f[kb][nb], acc3[nb], 0, 0, 0);
    }
#pragma unroll
    for (int nb = 0; nb < 4; ++nb)
#pragma unroll
        for (int r = 0; r < 4; ++r) {
            float v = acc3[nb][r] + b1v[nb];
            hid_s[w][(qq*4 + r)*72 + nb*16 + l15] = f2b(v > 0.0f ? v : 0.0f);
        }

    // GEMM4: hid[16x64] @ ow2^T[64x4(pad16)] + b2
    f32x4 acc4 = (f32x4)(0.0f);
#pragma unroll
    for (int kb = 0; kb < 2; ++kb) {
        bf16x8 af = *(const bf16x8*)(&hid_s[w][l15*72 + kb*32 + qq*8]);
        acc4 = __builtin_amdgcn_mfma_f32_16x16x32_bf16(af, bo2[kb], acc4, 0, 0, 0);
    }
    if (l15 < 4) {
#pragma unroll
        for (int r = 0; r < 4; ++r) {
            int item = itemBase + qq*4 + r;
            float nx = xt[item*4 + l15] + acc4[r] + b2v;
            xt[item*4 + l15] = nx;
            int n = item >> 1, s = item & 1;
            out[((n*TT + tstep)*SS + s)*4 + l15] = nx;
        }
    }
}

extern "C" void kernel_launch(void* const* d_in, const int* in_sizes, int n_in,
                              void* d_out, int out_size, void* d_ws, size_t ws_size,
                              hipStream_t stream) {
    const float* inputs = (const float*)d_in[0];
    const float* zA     = (const float*)d_in[1];
    const float* zG     = (const float*)d_in[2];
    const int*   src    = (const int*)d_in[3];
    const int*   dst    = (const int*)d_in[4];
    const float* Ws     = (const float*)d_in[5];
    const float* Wd     = (const float*)d_in[6];
    const float* F2w1   = (const float*)d_in[7];
    const float* F2w2   = (const float*)d_in[8];
    const float* F1w1   = (const float*)d_in[9];
    const float* F1w2   = (const float*)d_in[10];
    const float* xw     = (const float*)d_in[11];
    const float* xb     = (const float*)d_in[12];
    const float* ow1    = (const float*)d_in[13];
    const float* ob1    = (const float*)d_in[14];
    const float* ow2    = (const float*)d_in[15];
    const float* ob2    = (const float*)d_in[16];
    float* out = (float*)d_out;

    // ---- workspace carve (units: floats) ----
    float*          base        = (float*)d_ws;
    float*          MT          = base;                              // 4,096
    float*          alpha       = base + 4096;                       // 1,280,000
    int*            deg_i       = (int*)(base + 1284096);            // 10,000 (zeroed)
    int*            offsets     = (int*)(base + 1294096);            // 10,016
    int*            cursor      = (int*)(base + 1304112);            // 10,000
    int*            src_by_pos  = (int*)(base + 1314112);            // 160,000
    float*          xt          = base + 1474112;                    // 80,000
    float*          G1f         = base + 1554112;                    // 256
    float*          G2f         = base + 1554368;                    // 256
    float*          c1f         = base + 1554624;                    // 64
    float*          c2f         = base + 1554688;                    // 64 (pad to 1,554,816)
    unsigned short* W2b         = (unsigned short*)(base + 1554816); // 4,096 ush
    unsigned short* F1w1b       = (unsigned short*)(base + 1556864); // 16,384 ush
    unsigned short* F1w2b       = (unsigned short*)(base + 1565056); // 4,096 ush
    unsigned short* ow1b        = (unsigned short*)(base + 1567104); // 6,144 ush
    unsigned short* ow2b        = (unsigned short*)(base + 1570176); // 256 ush
    unsigned short* zAb         = (unsigned short*)(base + 1570304); // 640,000 ush
    unsigned short* zGb         = (unsigned short*)(base + 1890304); // 640,000 ush
    unsigned short* agg_b       = (unsigned short*)(base + 2210304); // 5,120,000 ush
    unsigned short* qdb         = (unsigned short*)(base + 4770304); // 2,560,000 ush
    // total 6,050,304 floats = 24.2 MB

    hipMemsetAsync(deg_i, 0, 10000u * 4u, stream);

    // ---- attention phase (once) ----
    const int CONVB = (NN*SS*ZZ + 255)/256;   // 2500
    k_prep<<<17 + CONVB, 256, 0, stream>>>(Ws, Wd, F2w1, xw, xb, F2w2, F1w1, F1w2,
                                           ow1, ow2, zA, zG, inputs, dst,
                                           MT, G1f, G2f, c1f, c2f,
                                           W2b, F1w1b, F1w2b, ow1b, ow2b,
                                           zAb, zGb, xt, deg_i);
    k_qd<<<(NN*SS*KK*ZZ + 255)/256, 256, 0, stream>>>(zG, MT, qdb);
    k_scan<<<1, 1024, 0, stream>>>(deg_i, offsets, cursor);
    k_scatter<<<(NE + 255)/256, 256, 0, stream>>>(src, dst, cursor, src_by_pos);
    k_attn_alpha<<<NN*SS, 64, 0, stream>>>(qdb, zGb, src_by_pos, offsets, alpha);

    // ---- time stepping ----
    for (int t = 0; t < 2; ++t) {
        k_agg2<<<NN*SS, 64, 0, stream>>>(xt, G1f, G2f, c1f, c2f,
                                         src_by_pos, offsets, alpha, agg_b);
        k_node_mfma<<<(NN*SS + 63)/64, 256, 0, stream>>>(agg_b, zAb, W2b, F1w1b, F1w2b,
                                                         ow1b, ow2b, ob1, ob2, xt, out, t);
    }
}

// Round 14
// 226.939 us; speedup vs baseline: 2.1255x; 1.1066x over previous
//
#include <hip/hip_runtime.h>

#define NN 10000
#define NE 160000
#define TT 2
#define SS 2
#define HH 64
#define ZZ 32
#define KK 4
#define NIN 4

typedef short bf16x8 __attribute__((ext_vector_type(8)));
typedef float f32x4 __attribute__((ext_vector_type(4)));

// fp32 -> bf16 (RNE)
__device__ __forceinline__ unsigned short f2b(float x) {
    unsigned u = __float_as_uint(x);
    u += 0x7fffu + ((u >> 16) & 1u);
    return (unsigned short)(u >> 16);
}
__device__ __forceinline__ float bf2f(unsigned short u) {
    return __uint_as_float(((unsigned)u) << 16);
}

// leaky(dot(zG_row(bf16 pairs), qf[32]))
__device__ __forceinline__ float edge_score(const unsigned* __restrict__ zp,
                                            const float* __restrict__ qf) {
    float a = 0.f;
#pragma unroll
    for (int j = 0; j < 16; ++j) {
        unsigned u = zp[j];
        a += __uint_as_float(u << 16) * qf[2*j]
           + __uint_as_float(u & 0xffff0000u) * qf[2*j+1];
    }
    return a > 0.f ? a : 0.01f*a;
}

// P0: merged prep. blocks 0..15: attnM (MT[k][j][i], transposed). block 16: fold.
// blocks 17+: bf16 conversions + xt init + deg count.
__global__ __launch_bounds__(256) void k_prep(
    const float* __restrict__ Ws, const float* __restrict__ Wd,
    const float* __restrict__ F2w1, const float* __restrict__ xw,
    const float* __restrict__ xb, const float* __restrict__ F2w2,
    const float* __restrict__ F1w1, const float* __restrict__ F1w2,
    const float* __restrict__ ow1, const float* __restrict__ ow2,
    const float* __restrict__ zA, const float* __restrict__ zG,
    const float* __restrict__ inputs, const int* __restrict__ dst,
    float* __restrict__ MT, float* __restrict__ G1, float* __restrict__ G2,
    float* __restrict__ c1, float* __restrict__ c2,
    unsigned short* __restrict__ W2b, unsigned short* __restrict__ F1w1b,
    unsigned short* __restrict__ F1w2b, unsigned short* __restrict__ ow1b,
    unsigned short* __restrict__ ow2b, unsigned short* __restrict__ zAb,
    unsigned short* __restrict__ zGb, float* __restrict__ xt,
    int* __restrict__ deg_i)
{
    int b = blockIdx.x;
    int tid = threadIdx.x;
    if (b < 16) {
        int o = b*256 + tid;              // 4096 outputs
        int j = o & 31, i = (o >> 5) & 31, k = o >> 10;
        float acc = 0.0f;
        for (int h = 0; h < HH; ++h)
            acc += Ws[(k*HH + h)*ZZ + i] * Wd[(k*HH + h)*ZZ + j];
        MT[(k*ZZ + j)*ZZ + i] = acc;
    } else if (b == 16) {
        int h = tid >> 2, i = tid & 3;
        float a1 = 0.f, a2 = 0.f;
        for (int j = 0; j < HH; ++j) {
            float x = xw[j*NIN + i];
            a1 += F2w1[h*128 + j] * x;
            a2 += F2w1[h*128 + 64 + j] * x;
        }
        G1[h*4 + i] = a1;
        G2[h*4 + i] = a2;
        if (i == 0) {
            float b1 = 0.f, b2 = 0.f;
            for (int j = 0; j < HH; ++j) {
                float bb = xb[j];
                b1 += F2w1[h*128 + j] * bb;
                b2 += F2w1[h*128 + 64 + j] * bb;
            }
            c1[h] = b1; c2[h] = b2;
        }
    } else {
        int t = (b - 17)*256 + tid;
        if (t < NN*SS*ZZ) { zAb[t] = f2b(zA[t]); zGb[t] = f2b(zG[t]); }
        if (t < HH*HH)    { W2b[t] = f2b(F2w2[t]); F1w2b[t] = f2b(F1w2[t]); }
        if (t < HH*KK*HH) F1w1b[t] = f2b(F1w1[t]);
        if (t < HH*(HH+ZZ)) ow1b[t] = f2b(ow1[t]);
        if (t < 4*HH)     ow2b[t] = f2b(ow2[t]);
        if (t < NN*SS*NIN) {
            int i = t & 3;
            int n = t >> 3;
            xt[t] = inputs[n*(TT*NIN) + i];
        }
        if (t < NE) atomicAdd(deg_i + dst[t], 1);
    }
}

// C2: exclusive scan of deg_i -> offsets[0..NN], cursor copy (1 block, Hillis-Steele)
__global__ void k_scan(const int* __restrict__ deg_i, int* __restrict__ offsets,
                       int* __restrict__ cursor) {
    __shared__ int buf0[1024], buf1[1024];
    int tidx = threadIdx.x;
    const int CH = (NN + 1023) / 1024;   // 10
    int b0 = tidx * CH;
    int sum = 0;
    for (int i = 0; i < CH; ++i) { int idx = b0 + i; if (idx < NN) sum += deg_i[idx]; }
    buf0[tidx] = sum;
    __syncthreads();
    int* s = buf0; int* d = buf1;
    for (int off = 1; off < 1024; off <<= 1) {
        d[tidx] = s[tidx] + (tidx >= off ? s[tidx - off] : 0);
        __syncthreads();
        int* tmp = s; s = d; d = tmp;
    }
    int run = s[tidx] - sum;
    for (int i = 0; i < CH; ++i) {
        int idx = b0 + i;
        if (idx < NN) { offsets[idx] = run; cursor[idx] = run; run += deg_i[idx]; }
    }
    if (tidx == 0) offsets[NN] = NE;
}

// C3: scatter src node ids into dst-sorted position order
__global__ void k_scatter(const int* __restrict__ src, const int* __restrict__ dst,
                          int* __restrict__ cursor, int* __restrict__ src_by_pos) {
    int e = blockIdx.x * blockDim.x + threadIdx.x;
    if (e >= NE) return;
    int pos = atomicAdd(cursor + dst[e], 1);
    src_by_pos[pos] = src[e];
}

// Fused attention + step-0 aggregation. One wave per (n,s) item.
// Phase 0: qd[k][i] computed in-block from MT + fp32 zG (LDS share).
// Phase 1: scores -> softmax stats -> alpha (global, for t=1) + LDS cache.
// Phase 2: k_agg2 body (lane = h) using LDS alpha (global fallback deg>64).
__global__ __launch_bounds__(64) void k_attn_agg0(
    const float* __restrict__ MT, const float* __restrict__ zG,
    const unsigned short* __restrict__ zGb, const int* __restrict__ src_by_pos,
    const int* __restrict__ offsets, const float* __restrict__ xt,
    const float* __restrict__ G1, const float* __restrict__ G2,
    const float* __restrict__ c1, const float* __restrict__ c2,
    float* alpha, unsigned short* __restrict__ agg_b)
{
    __shared__ float sq[128];          // qd flat [k*32+i]
    __shared__ float alpha_s[64][4];   // alpha cache, first 64 edges
    int item = blockIdx.x;
    int n = item >> 1, s = item & 1;
    int l = threadIdx.x;
    int i = l >> 2, k = l & 3;
    int r0 = offsets[n], r1 = offsets[n+1];

    // ---- phase 0: qd in-block (2 entries per lane) ----
    {
        int i0 = l & 31;
        int k0 = l >> 5;         // 0..1
        int k1 = k0 + 2;         // 2..3
        const float* zg = zG + item*ZZ;
        float acc0 = 0.f, acc1 = 0.f;
#pragma unroll
        for (int j = 0; j < ZZ; ++j) {
            float z = zg[j];
            acc0 += MT[(k0*ZZ + j)*ZZ + i0] * z;
            acc1 += MT[(k1*ZZ + j)*ZZ + i0] * z;
        }
        sq[k0*ZZ + i0] = acc0;
        sq[k1*ZZ + i0] = acc1;
    }
    __syncthreads();
    float qf[32];
#pragma unroll
    for (int j = 0; j < 32; ++j) qf[j] = sq[k*ZZ + j];

    // ---- phase 1: scores -> alpha ----
    float E[8];
    float mx = -1e30f;
    int nit = 0;
    for (int idx = r0 + i; idx < r1; idx += 16, ++nit) {
        int sn = src_by_pos[idx];
        float e = edge_score((const unsigned*)(zGb + (sn*SS + s)*ZZ), qf);
        if (nit < 8) E[nit] = e;
        mx = fmaxf(mx, e);
    }
#pragma unroll
    for (int off = 4; off < 64; off <<= 1) mx = fmaxf(mx, __shfl_xor(mx, off));
    float sum = 0.f;
    nit = 0;
    for (int idx = r0 + i; idx < r1; idx += 16, ++nit) {
        float e = (nit < 8) ? E[nit]
                : edge_score((const unsigned*)(zGb + (src_by_pos[idx]*SS + s)*ZZ), qf);
        sum += __expf(e - mx);
    }
#pragma unroll
    for (int off = 4; off < 64; off <<= 1) sum += __shfl_xor(sum, off);
    int deg = r1 - r0;
    float dd = (float)(deg > 1 ? deg : 1);
    float inv = sum > 0.f ? 1.f/(sum*dd) : 0.f;
    nit = 0;
    for (int idx = r0 + i; idx < r1; idx += 16, ++nit) {
        float e = (nit < 8) ? E[nit]
                : edge_score((const unsigned*)(zGb + (src_by_pos[idx]*SS + s)*ZZ), qf);
        float a = __expf(e - mx) * inv;
        alpha[(idx*2 + s)*4 + k] = a;
        int jo = idx - r0;
        if (jo < 64) alpha_s[jo][k] = a;
    }
    __threadfence_block();
    __syncthreads();

    // ---- phase 2: step-0 aggregation (lane = h) ----
    int h = l;
    const float4 g1 = *(const float4*)(G1 + h*4);
    const float4 g2 = *(const float4*)(G2 + h*4);
    const float4 xd = *(const float4*)(xt + item*4);
    float p2 = c2[h] + xd.x*g2.x + xd.y*g2.y + xd.z*g2.z + xd.w*g2.w;
    float c1h = c1[h];
    float a0 = 0.f, a1 = 0.f, a2 = 0.f, a3 = 0.f;
    for (int jo = 0; jo < deg; ++jo) {
        int idx = r0 + jo;
        int sn = src_by_pos[idx];
        float4 x0 = *(const float4*)(xt + (sn*SS + s)*NIN);
        float4 w4 = (jo < 64) ? *(const float4*)(&alpha_s[jo][0])
                              : *(const float4*)(alpha + (idx*2 + s)*4);
        float p = c1h + x0.x*g1.x + x0.y*g1.y + x0.z*g1.z + x0.w*g1.w;
        float hd = p + p2; hd = hd > 0.f ? hd : 0.f;
        a0 += w4.x*hd; a1 += w4.y*hd; a2 += w4.z*hd; a3 += w4.w*hd;
    }
    agg_b[item*256 +       h] = f2b(a0);
    agg_b[item*256 + 64  + h] = f2b(a1);
    agg_b[item*256 + 128 + h] = f2b(a2);
    agg_b[item*256 + 192 + h] = f2b(a3);
}

// B2: fused xenc + edge layer-1 + aggregation (step 1). Edge loop unrolled x4.
__global__ __launch_bounds__(64) void k_agg2(
    const float* __restrict__ xt, const float* __restrict__ G1,
    const float* __restrict__ G2, const float* __restrict__ c1,
    const float* __restrict__ c2, const int* __restrict__ src_by_pos,
    const int* __restrict__ offsets, const float* __restrict__ alpha,
    unsigned short* __restrict__ agg_b)
{
    int item = blockIdx.x;
    int n = item >> 1, s = item & 1;
    int h = threadIdx.x;
    int r0 = offsets[n], r1 = offsets[n+1];
    const float4 g1 = *(const float4*)(G1 + h*4);
    const float4 g2 = *(const float4*)(G2 + h*4);
    const float4 xd = *(const float4*)(xt + item*4);
    float p2 = c2[h] + xd.x*g2.x + xd.y*g2.y + xd.z*g2.z + xd.w*g2.w;
    float c1h = c1[h];
    float a0 = 0.f, a1 = 0.f, a2 = 0.f, a3 = 0.f;
    int idx = r0;
    for (; idx + 4 <= r1; idx += 4) {
        int sn0 = src_by_pos[idx];
        int sn1 = src_by_pos[idx+1];
        int sn2 = src_by_pos[idx+2];
        int sn3 = src_by_pos[idx+3];
        float4 x0 = *(const float4*)(xt + (sn0*SS + s)*NIN);
        float4 x1 = *(const float4*)(xt + (sn1*SS + s)*NIN);
        float4 x2 = *(const float4*)(xt + (sn2*SS + s)*NIN);
        float4 x3 = *(const float4*)(xt + (sn3*SS + s)*NIN);
        float4 w0 = *(const float4*)(alpha + ((idx+0)*2 + s)*4);
        float4 w1 = *(const float4*)(alpha + ((idx+1)*2 + s)*4);
        float4 w2 = *(const float4*)(alpha + ((idx+2)*2 + s)*4);
        float4 w3 = *(const float4*)(alpha + ((idx+3)*2 + s)*4);
        float p, hd;
        p = c1h + x0.x*g1.x + x0.y*g1.y + x0.z*g1.z + x0.w*g1.w;
        hd = p + p2; hd = hd > 0.f ? hd : 0.f;
        a0 += w0.x*hd; a1 += w0.y*hd; a2 += w0.z*hd; a3 += w0.w*hd;
        p = c1h + x1.x*g1.x + x1.y*g1.y + x1.z*g1.z + x1.w*g1.w;
        hd = p + p2; hd = hd > 0.f ? hd : 0.f;
        a0 += w1.x*hd; a1 += w1.y*hd; a2 += w1.z*hd; a3 += w1.w*hd;
        p = c1h + x2.x*g1.x + x2.y*g1.y + x2.z*g1.z + x2.w*g1.w;
        hd = p + p2; hd = hd > 0.f ? hd : 0.f;
        a0 += w2.x*hd; a1 += w2.y*hd; a2 += w2.z*hd; a3 += w2.w*hd;
        p = c1h + x3.x*g1.x + x3.y*g1.y + x3.z*g1.z + x3.w*g1.w;
        hd = p + p2; hd = hd > 0.f ? hd : 0.f;
        a0 += w3.x*hd; a1 += w3.y*hd; a2 += w3.z*hd; a3 += w3.w*hd;
    }
    for (; idx < r1; ++idx) {
        int sn = src_by_pos[idx];
        float4 x0 = *(const float4*)(xt + (sn*SS + s)*NIN);
        float4 w0 = *(const float4*)(alpha + (idx*2 + s)*4);
        float p = c1h + x0.x*g1.x + x0.y*g1.y + x0.z*g1.z + x0.w*g1.w;
        float hd = p + p2; hd = hd > 0.f ? hd : 0.f;
        a0 += w0.x*hd; a1 += w0.y*hd; a2 += w0.z*hd; a3 += w0.w*hd;
    }
    agg_b[item*256 +       h] = f2b(a0);
    agg_b[item*256 + 64  + h] = f2b(a1);
    agg_b[item*256 + 128 + h] = f2b(a2);
    agg_b[item*256 + 192 + h] = f2b(a3);
}

// B3: GEMM0 (agg@W2^T block-diag per head) + chained node GEMMs.
// 4 waves/block, 16 items/wave. Per-wave LDS only, no barrier.
__global__ __launch_bounds__(256) void k_node_mfma(
    const unsigned short* __restrict__ agg_b, const unsigned short* __restrict__ zAb,
    const unsigned short* __restrict__ W2b,
    const unsigned short* __restrict__ F1w1b, const unsigned short* __restrict__ F1w2b,
    const unsigned short* __restrict__ ow1b, const unsigned short* __restrict__ ow2b,
    const float* __restrict__ ob1, const float* __restrict__ ob2,
    float* __restrict__ xt, float* __restrict__ out, int tstep)
{
    __shared__ unsigned short res_s[4][16*264];
    __shared__ unsigned short hid_s[4][16*72];
    __shared__ unsigned short hcat_s[4][16*104];
    int tid = threadIdx.x;
    int w = tid >> 6, l = tid & 63, l15 = l & 15, qq = l >> 4;

    bf16x8 w2f[2][4], b2f[2][4], o1f[3][4], bo2[2];
#pragma unroll
    for (int nb = 0; nb < 4; ++nb) {
        int n = nb*16 + l15;
#pragma unroll
        for (int kb = 0; kb < 2; ++kb) {
            w2f[kb][nb] = *(const bf16x8*)(W2b  + n*64 + kb*32 + qq*8);
            b2f[kb][nb] = *(const bf16x8*)(F1w2b + n*64 + kb*32 + qq*8);
        }
#pragma unroll
        for (int kb = 0; kb < 3; ++kb)
            o1f[kb][nb] = *(const bf16x8*)(ow1b + n*96 + kb*32 + qq*8);
    }
#pragma unroll
    for (int kb = 0; kb < 2; ++kb) {
        if (l15 < 4) bo2[kb] = *(const bf16x8*)(ow2b + l15*64 + kb*32 + qq*8);
        else {
            bf16x8 z;
#pragma unroll
            for (int j = 0; j < 8; ++j) z[j] = 0;
            bo2[kb] = z;
        }
    }
    float b1v[4];
#pragma unroll
    for (int nb = 0; nb < 4; ++nb) b1v[nb] = ob1[nb*16 + l15];
    float b2v = (l15 < 4) ? ob2[l15] : 0.0f;

    int itemBase = blockIdx.x*64 + w*16;
    if (itemBase >= NN*SS) return;

    *(uint4*)(&hcat_s[w][l15*104 + 64 + qq*8]) =
        *(const uint4*)(zAb + (itemBase + l15)*ZZ + qq*8);

    // GEMM0: res[item, k*64+h'] = sum_h agg[item,k*64+h] * W2[h'][h]
#pragma unroll
    for (int k = 0; k < 4; ++k) {
        f32x4 acc0[4];
#pragma unroll
        for (int nb = 0; nb < 4; ++nb) acc0[nb] = (f32x4)(0.0f);
#pragma unroll
        for (int kb = 0; kb < 2; ++kb) {
            bf16x8 af = *(const bf16x8*)(agg_b + (itemBase + l15)*256 + k*64 + kb*32 + qq*8);
#pragma unroll
            for (int nb = 0; nb < 4; ++nb)
                acc0[nb] = __builtin_amdgcn_mfma_f32_16x16x32_bf16(af, w2f[kb][nb], acc0[nb], 0, 0, 0);
        }
#pragma unroll
        for (int nb = 0; nb < 4; ++nb)
#pragma unroll
            for (int r = 0; r < 4; ++r)
                res_s[w][(qq*4 + r)*264 + k*64 + nb*16 + l15] = f2b(acc0[nb][r]);
    }

    // GEMM1: res[16x256] @ F1w1^T[256x64], relu
    f32x4 acc[4];
#pragma unroll
    for (int nb = 0; nb < 4; ++nb) acc[nb] = (f32x4)(0.0f);
#pragma unroll
    for (int kb = 0; kb < 8; ++kb) {
        bf16x8 af = *(const bf16x8*)(&res_s[w][l15*264 + kb*32 + qq*8]);
#pragma unroll
        for (int nb = 0; nb < 4; ++nb) {
            bf16x8 bf = *(const bf16x8*)(F1w1b + (nb*16 + l15)*256 + kb*32 + qq*8);
            acc[nb] = __builtin_amdgcn_mfma_f32_16x16x32_bf16(af, bf, acc[nb], 0, 0, 0);
        }
    }
#pragma unroll
    for (int nb = 0; nb < 4; ++nb)
#pragma unroll
        for (int r = 0; r < 4; ++r) {
            float v = acc[nb][r];
            hid_s[w][(qq*4 + r)*72 + nb*16 + l15] = f2b(v > 0.0f ? v : 0.0f);
        }

    // GEMM2: hid[16x64] @ F1w2^T[64x64] -> deltax -> hcat cols 0..63
    f32x4 acc2[4];
#pragma unroll
    for (int nb = 0; nb < 4; ++nb) acc2[nb] = (f32x4)(0.0f);
#pragma unroll
    for (int kb = 0; kb < 2; ++kb) {
        bf16x8 af = *(const bf16x8*)(&hid_s[w][l15*72 + kb*32 + qq*8]);
#pragma unroll
        for (int nb = 0; nb < 4; ++nb)
            acc2[nb] = __builtin_amdgcn_mfma_f32_16x16x32_bf16(af, b2f[kb][nb], acc2[nb], 0, 0, 0);
    }
#pragma unroll
    for (int nb = 0; nb < 4; ++nb)
#pragma unroll
        for (int r = 0; r < 4; ++r)
            hcat_s[w][(qq*4 + r)*104 + nb*16 + l15] = f2b(acc2[nb][r]);

    // GEMM3: hcat[16x96] @ ow1^T[96x64] + b1, relu -> hid_s
    f32x4 acc3[4];
#pragma unroll
    for (int nb = 0; nb < 4; ++nb) acc3[nb] = (f32x4)(0.0f);
#pragma unroll
    for (int kb = 0; kb < 3; ++kb) {
        bf16x8 af = *(const bf16x8*)(&hcat_s[w][l15*104 + kb*32 + qq*8]);
#pragma unroll
        for (int nb = 0; nb < 4; ++nb)
            acc3[nb] = __builtin_amdgcn_mfma_f32_16x16x32_bf16(af, o1f[kb][nb], acc3[nb], 0, 0, 0);
    }
#pragma unroll
    for (int nb = 0; nb < 4; ++nb)
#pragma unroll
        for (int r = 0; r < 4; ++r) {
            float v = acc3[nb][r] + b1v[nb];
            hid_s[w][(qq*4 + r)*72 + nb*16 + l15] = f2b(v > 0.0f ? v : 0.0f);
        }

    // GEMM4: hid[16x64] @ ow2^T[64x4(pad16)] + b2
    f32x4 acc4 = (f32x4)(0.0f);
#pragma unroll
    for (int kb = 0; kb < 2; ++kb) {
        bf16x8 af = *(const bf16x8*)(&hid_s[w][l15*72 + kb*32 + qq*8]);
        acc4 = __builtin_amdgcn_mfma_f32_16x16x32_bf16(af, bo2[kb], acc4, 0, 0, 0);
    }
    if (l15 < 4) {
#pragma unroll
        for (int r = 0; r < 4; ++r) {
            int item = itemBase + qq*4 + r;
            float nx = xt[item*4 + l15] + acc4[r] + b2v;
            xt[item*4 + l15] = nx;
            int n = item >> 1, s = item & 1;
            out[((n*TT + tstep)*SS + s)*4 + l15] = nx;
        }
    }
}

extern "C" void kernel_launch(void* const* d_in, const int* in_sizes, int n_in,
                              void* d_out, int out_size, void* d_ws, size_t ws_size,
                              hipStream_t stream) {
    const float* inputs = (const float*)d_in[0];
    const float* zA     = (const float*)d_in[1];
    const float* zG     = (const float*)d_in[2];
    const int*   src    = (const int*)d_in[3];
    const int*   dst    = (const int*)d_in[4];
    const float* Ws     = (const float*)d_in[5];
    const float* Wd     = (const float*)d_in[6];
    const float* F2w1   = (const float*)d_in[7];
    const float* F2w2   = (const float*)d_in[8];
    const float* F1w1   = (const float*)d_in[9];
    const float* F1w2   = (const float*)d_in[10];
    const float* xw     = (const float*)d_in[11];
    const float* xb     = (const float*)d_in[12];
    const float* ow1    = (const float*)d_in[13];
    const float* ob1    = (const float*)d_in[14];
    const float* ow2    = (const float*)d_in[15];
    const float* ob2    = (const float*)d_in[16];
    float* out = (float*)d_out;

    // ---- workspace carve (units: floats) ----
    float*          base        = (float*)d_ws;
    float*          MT          = base;                              // 4,096
    float*          alpha       = base + 4096;                       // 1,280,000
    int*            deg_i       = (int*)(base + 1284096);            // 10,000 (zeroed)
    int*            offsets     = (int*)(base + 1294096);            // 10,016
    int*            cursor      = (int*)(base + 1304112);            // 10,000
    int*            src_by_pos  = (int*)(base + 1314112);            // 160,000
    float*          xt          = base + 1474112;                    // 80,000
    float*          G1f         = base + 1554112;                    // 256
    float*          G2f         = base + 1554368;                    // 256
    float*          c1f         = base + 1554624;                    // 64
    float*          c2f         = base + 1554688;                    // 64 (pad to 1,554,816)
    unsigned short* W2b         = (unsigned short*)(base + 1554816); // 4,096 ush
    unsigned short* F1w1b       = (unsigned short*)(base + 1556864); // 16,384 ush
    unsigned short* F1w2b       = (unsigned short*)(base + 1565056); // 4,096 ush
    unsigned short* ow1b        = (unsigned short*)(base + 1567104); // 6,144 ush
    unsigned short* ow2b        = (unsigned short*)(base + 1570176); // 256 ush
    unsigned short* zAb         = (unsigned short*)(base + 1570304); // 640,000 ush
    unsigned short* zGb         = (unsigned short*)(base + 1890304); // 640,000 ush
    unsigned short* agg_b       = (unsigned short*)(base + 2210304); // 5,120,000 ush
    // total 4,770,304 floats = 19.1 MB

    hipMemsetAsync(deg_i, 0, 10000u * 4u, stream);

    // ---- attention phase (once) ----
    const int CONVB = (NN*SS*ZZ + 255)/256;   // 2500
    k_prep<<<17 + CONVB, 256, 0, stream>>>(Ws, Wd, F2w1, xw, xb, F2w2, F1w1, F1w2,
                                           ow1, ow2, zA, zG, inputs, dst,
                                           MT, G1f, G2f, c1f, c2f,
                                           W2b, F1w1b, F1w2b, ow1b, ow2b,
                                           zAb, zGb, xt, deg_i);
    k_scan<<<1, 1024, 0, stream>>>(deg_i, offsets, cursor);
    k_scatter<<<(NE + 255)/256, 256, 0, stream>>>(src, dst, cursor, src_by_pos);

    // ---- step 0 (attention fused with aggregation) ----
    k_attn_agg0<<<NN*SS, 64, 0, stream>>>(MT, zG, zGb, src_by_pos, offsets, xt,
                                          G1f, G2f, c1f, c2f, alpha, agg_b);
    k_node_mfma<<<(NN*SS + 63)/64, 256, 0, stream>>>(agg_b, zAb, W2b, F1w1b, F1w2b,
                                                     ow1b, ow2b, ob1, ob2, xt, out, 0);
    // ---- step 1 ----
    k_agg2<<<NN*SS, 64, 0, stream>>>(xt, G1f, G2f, c1f, c2f,
                                     src_by_pos, offsets, alpha, agg_b);
    k_node_mfma<<<(NN*SS + 63)/64, 256, 0, stream>>>(agg_b, zAb, W2b, F1w1b, F1w2b,
                                                     ow1b, ow2b, ob1, ob2, xt, out, 1);
}